// Round 3
// baseline (1916.518 us; speedup 1.0000x reference)
//
#include <hip/hip_runtime.h>
#include <hip/hip_bf16.h>
#include <math.h>

typedef __hip_bfloat16 bf16;
typedef __bf16 bhalf;
typedef bhalf bhalf8 __attribute__((ext_vector_type(8)));
typedef float f32x4 __attribute__((ext_vector_type(4)));

#define D_MODEL   1024
#define D_STATE   64
#define HEADDIM   64
#define D_INNER   2048
#define NHEADS    32
#define CONV_DIM  2176
#define D_IN_PROJ 4256
#define FFN_DIM   4096
#define BSZ       2
#define SEQ       2048
#define NROWS     (BSZ*SEQ)

// ---------------------------------------------------------------------------
// Input dtype detection: bf16 N(0,1) data has max|v| ~ 4; fp32 data read as
// bf16 halfwords has random exponents -> |v| > 1e6 or NaN with certainty.
// flag = 1 means inputs are fp32.
// ---------------------------------------------------------------------------
__global__ __launch_bounds__(64)
void detect_kernel(const unsigned short* __restrict__ x, int* __restrict__ flagp)
{
  int bad = 0;
  for (int i = threadIdx.x; i < 4096; i += 64) {
    unsigned u = ((unsigned)x[i]) << 16;
    float v = __uint_as_float(u);
    if (!(fabsf(v) <= 1e6f)) bad = 1;   // catches NaN too
  }
  unsigned long long any = __ballot(bad);
  if (threadIdx.x == 0) *flagp = (any != 0ULL) ? 1 : 0;
}

// ---------------------------------------------------------------------------
// Normalize all inputs to bf16 workspace copies (copy if bf16, cvt if fp32).
// One block per 2048-element chunk of one tensor.
// ---------------------------------------------------------------------------
#define NT 19
struct CvtArgs {
  const void* src[NT];
  void*       dst[NT];
  int ccum[NT + 1];   // cumulative chunk counts
  int nel[NT];        // element counts
};

__global__ __launch_bounds__(256)
void cvt_kernel(CvtArgs a, const int* __restrict__ flagp)
{
  int c = blockIdx.x;
  int ti = 0;
  while (c >= a.ccum[ti + 1]) ti++;          // block-uniform, <=19 iters
  int base = (c - a.ccum[ti]) * 2048;
  int n = a.nel[ti];
  if (*flagp) {
    const float* s = (const float*)a.src[ti];
    bf16* d = (bf16*)a.dst[ti];
    for (int i = threadIdx.x; i < 2048; i += 256) {
      int j = base + i;
      if (j < n) d[j] = __float2bfloat16(s[j]);
    }
  } else {
    const unsigned short* s = (const unsigned short*)a.src[ti];
    unsigned short* d = (unsigned short*)a.dst[ti];
    for (int i = threadIdx.x; i < 2048; i += 256) {
      int j = base + i;
      if (j < n) d[j] = s[j];
    }
  }
}

// ---------------------------------------------------------------------------
// GEMM: C[M,N] = A[M,K] @ W[N,K]^T, bf16 inputs, fp32 accum, fused epilogues.
// 128x128 tile, BK=32, 256 threads (4 waves in 2x2), mfma_f32_16x16x32_bf16.
// EPI 0: store bf16                    EPI 1: outF = acc + bf16(resB)
// EPI 2: store bf16(gelu(acc+bias))    EPI 3: acc+bias+resF -> d_out (dtype per flag)
// ---------------------------------------------------------------------------
template<int EPI>
__global__ __launch_bounds__(256, 2)
void gemm_bt(const bf16* __restrict__ A, const bf16* __restrict__ W,
             int M, int N, int K,
             bf16* __restrict__ outB, float* __restrict__ outF,
             const bf16* __restrict__ bias,
             const bf16* __restrict__ resB,
             const float* __restrict__ resF,
             const int* __restrict__ flagp)
{
  __shared__ __align__(16) bhalf sA[128 * 32];
  __shared__ __align__(16) bhalf sW[128 * 32];
  const int t    = threadIdx.x;
  const int n0   = blockIdx.x * 128;
  const int m0   = blockIdx.y * 128;
  const int w    = t >> 6;
  const int lane = t & 63;
  const int wm   = (w >> 1) * 64;
  const int wn   = (w & 1) * 64;
  const int lr   = lane & 15;
  const int lq   = lane >> 4;
  const int srow = t >> 2;          // 0..63
  const int scol = (t & 3) * 8;     // 0,8,16,24

  const bool f32o = (EPI == 3) && (flagp != nullptr) && (*flagp != 0);

  f32x4 acc[4][4];
  #pragma unroll
  for (int i = 0; i < 4; i++)
    #pragma unroll
    for (int j = 0; j < 4; j++)
      acc[i][j] = (f32x4){0.f, 0.f, 0.f, 0.f};

  for (int k0 = 0; k0 < K; k0 += 32) {
    bhalf8 ta[2], tw[2];
    #pragma unroll
    for (int hh = 0; hh < 2; hh++) {
      int row = hh * 64 + srow;
      ta[hh] = *(const bhalf8*)(A + (size_t)(m0 + row) * K + k0 + scol);
      int wr = n0 + row; wr = wr < N ? wr : N - 1;   // clamp tail rows (in_proj)
      tw[hh] = *(const bhalf8*)(W + (size_t)wr * K + k0 + scol);
    }
    #pragma unroll
    for (int hh = 0; hh < 2; hh++) {
      int row = hh * 64 + srow;
      *(bhalf8*)(sA + row * 32 + scol) = ta[hh];
      *(bhalf8*)(sW + row * 32 + scol) = tw[hh];
    }
    __syncthreads();
    bhalf8 af[4], bfr[4];
    #pragma unroll
    for (int i = 0; i < 4; i++)
      af[i] = *(const bhalf8*)(sA + (wm + i * 16 + lr) * 32 + lq * 8);
    #pragma unroll
    for (int j = 0; j < 4; j++)
      bfr[j] = *(const bhalf8*)(sW + (wn + j * 16 + lr) * 32 + lq * 8);
    #pragma unroll
    for (int i = 0; i < 4; i++)
      #pragma unroll
      for (int j = 0; j < 4; j++)
        acc[i][j] = __builtin_amdgcn_mfma_f32_16x16x32_bf16(af[i], bfr[j], acc[i][j], 0, 0, 0);
    __syncthreads();
  }

  #pragma unroll
  for (int i = 0; i < 4; i++) {
    #pragma unroll
    for (int j = 0; j < 4; j++) {
      #pragma unroll
      for (int r = 0; r < 4; r++) {
        int m = m0 + wm + i * 16 + lq * 4 + r;   // D row = quad*4 + reg  (m89/m91)
        int n = n0 + wn + j * 16 + lr;           // D col = lane&15
        if (n < N) {
          float v = acc[i][j][r];
          size_t idx = (size_t)m * N + n;
          if (EPI == 0) {
            outB[idx] = __float2bfloat16(v);
          } else if (EPI == 1) {
            outF[idx] = v + __bfloat162float(resB[idx]);
          } else if (EPI == 2) {
            v += __bfloat162float(bias[n]);
            outB[idx] = __float2bfloat16(0.5f * v * (1.0f + erff(v * 0.70710678118654752f)));
          } else {
            v += __bfloat162float(bias[n]) + resF[idx];
            if (f32o) outF[idx] = v;
            else      outB[idx] = __float2bfloat16(v);
          }
        }
      }
    }
  }
}

// ---------------------------------------------------------------------------
// Fused ln0 + ln1 (one block per row of 1024).
// ---------------------------------------------------------------------------
__global__ __launch_bounds__(256)
void ln01_kernel(const bf16* __restrict__ x,
                 const bf16* __restrict__ w0, const bf16* __restrict__ b0,
                 const bf16* __restrict__ w1, const bf16* __restrict__ b1,
                 bf16* __restrict__ x0o, bf16* __restrict__ x1o)
{
  int row = blockIdx.x, t = threadIdx.x;
  const bf16* xr = x + (size_t)row * D_MODEL;
  __shared__ float rs[4], rq[4];
  float v[4], s = 0.f, ss = 0.f;
  #pragma unroll
  for (int i = 0; i < 4; i++) {
    v[i] = __bfloat162float(xr[t + 256 * i]);
    s += v[i]; ss += v[i] * v[i];
  }
  #pragma unroll
  for (int o = 32; o; o >>= 1) { s += __shfl_down(s, o); ss += __shfl_down(ss, o); }
  if ((t & 63) == 0) { rs[t >> 6] = s; rq[t >> 6] = ss; }
  __syncthreads();
  float S = rs[0] + rs[1] + rs[2] + rs[3];
  float Q = rq[0] + rq[1] + rq[2] + rq[3];
  float mean = S * (1.f / D_MODEL);
  float rstd = rsqrtf(Q * (1.f / D_MODEL) - mean * mean + 1e-5f);
  float u[4]; s = 0.f; ss = 0.f;
  #pragma unroll
  for (int i = 0; i < 4; i++) {
    int c = t + 256 * i;
    u[i] = (v[i] - mean) * rstd * __bfloat162float(w0[c]) + __bfloat162float(b0[c]);
    s += u[i]; ss += u[i] * u[i];
    x0o[(size_t)row * D_MODEL + c] = __float2bfloat16(u[i]);
  }
  __syncthreads();
  #pragma unroll
  for (int o = 32; o; o >>= 1) { s += __shfl_down(s, o); ss += __shfl_down(ss, o); }
  if ((t & 63) == 0) { rs[t >> 6] = s; rq[t >> 6] = ss; }
  __syncthreads();
  S = rs[0] + rs[1] + rs[2] + rs[3];
  Q = rq[0] + rq[1] + rq[2] + rq[3];
  mean = S * (1.f / D_MODEL);
  rstd = rsqrtf(Q * (1.f / D_MODEL) - mean * mean + 1e-5f);
  #pragma unroll
  for (int i = 0; i < 4; i++) {
    int c = t + 256 * i;
    x1o[(size_t)row * D_MODEL + c] =
        __float2bfloat16((u[i] - mean) * rstd * __bfloat162float(w1[c]) + __bfloat162float(b1[c]));
  }
}

// ---------------------------------------------------------------------------
// Causal depthwise conv (k=4) + SiLU over the xBC slice of zxbcdt.
// ---------------------------------------------------------------------------
__global__ __launch_bounds__(256)
void conv_silu_kernel(const bf16* __restrict__ zxb, const bf16* __restrict__ cw,
                      const bf16* __restrict__ cb, float* __restrict__ xact)
{
  int c = blockIdx.x * 256 + threadIdx.x;
  int row = blockIdx.y;
  if (c >= CONV_DIM) return;
  int l = row & (SEQ - 1);
  float acc = __bfloat162float(cb[c]);
  #pragma unroll
  for (int k = 0; k < 4; k++) {
    int lt = l - 3 + k;
    if (lt >= 0)
      acc += __bfloat162float(zxb[(size_t)(row - 3 + k) * D_IN_PROJ + D_INNER + c]) *
             __bfloat162float(cw[c * 4 + k]);
  }
  xact[(size_t)row * CONV_DIM + c] = acc / (1.f + expf(-acc));
}

// ---------------------------------------------------------------------------
// dt = softplus(raw + dt_bias); dA = exp(dt * -exp(A_log))
// ---------------------------------------------------------------------------
__global__ __launch_bounds__(256)
void dt_kernel(const bf16* __restrict__ zxb, const bf16* __restrict__ dt_bias,
               const bf16* __restrict__ A_log, float* __restrict__ dts,
               float* __restrict__ dab)
{
  int i = blockIdx.x * 256 + threadIdx.x;     // NROWS*NHEADS threads exactly
  int row = i >> 5, h = i & 31;
  float v = __bfloat162float(zxb[(size_t)row * D_IN_PROJ + (D_INNER + CONV_DIM) + h]) +
            __bfloat162float(dt_bias[h]);
  float sp = (v > 20.f) ? v : log1pf(expf(v));
  dts[i] = sp;
  dab[i] = expf(-sp * expf(__bfloat162float(A_log[h])));
}

// ---------------------------------------------------------------------------
// Sequential scan. Block per (b,h), 2 waves; wave g owns n in [32g, 32g+32),
// lane = p. Partial y per group -> global (no barriers). 1-step prefetch.
// ---------------------------------------------------------------------------
__global__ __launch_bounds__(128)
void scan_kernel(const float* __restrict__ xact, const float* __restrict__ dts,
                 const float* __restrict__ dab, bf16* __restrict__ ypart)
{
  const int bh = blockIdx.x;
  const int b = bh >> 5, h = bh & 31;
  const int g = threadIdx.x >> 6, p = threadIdx.x & 63;
  const float* base  = xact + (size_t)b * SEQ * CONV_DIM;
  const float* Bbase = base + D_INNER + g * 32;
  const float* Cbase = base + D_INNER + D_STATE + g * 32;
  const float* xbase = base + h * 64 + p;
  const float* dtp = dts + (size_t)b * SEQ * NHEADS + h;
  const float* dap = dab + (size_t)b * SEQ * NHEADS + h;
  bf16* yo = ypart + (size_t)(g * BSZ + b) * SEQ * D_INNER + h * 64 + p;

  float hs[32];
  #pragma unroll
  for (int n = 0; n < 32; n++) hs[n] = 0.f;

  f32x4 Bv[8], Cv[8], Bn[8], Cn[8];
  float xv, dtv, dav;
  float xn = 0.f, dtn = 0.f, dan = 0.f;
  #pragma unroll
  for (int q = 0; q < 8; q++) { Bn[q] = (f32x4){0,0,0,0}; Cn[q] = (f32x4){0,0,0,0}; }

  {
    const f32x4* Bp = (const f32x4*)Bbase;
    const f32x4* Cp = (const f32x4*)Cbase;
    #pragma unroll
    for (int q = 0; q < 8; q++) { Bv[q] = Bp[q]; Cv[q] = Cp[q]; }
    xv = xbase[0]; dtv = dtp[0]; dav = dap[0];
  }

  for (int t = 0; t < SEQ; t++) {
    if (t + 1 < SEQ) {
      const f32x4* Bp = (const f32x4*)(Bbase + (size_t)(t + 1) * CONV_DIM);
      const f32x4* Cp = (const f32x4*)(Cbase + (size_t)(t + 1) * CONV_DIM);
      #pragma unroll
      for (int q = 0; q < 8; q++) { Bn[q] = Bp[q]; Cn[q] = Cp[q]; }
      xn  = xbase[(size_t)(t + 1) * CONV_DIM];
      dtn = dtp[(size_t)(t + 1) * NHEADS];
      dan = dap[(size_t)(t + 1) * NHEADS];
    }
    float a = dtv * xv;
    f32x4 acc4 = (f32x4){0.f, 0.f, 0.f, 0.f};
    #pragma unroll
    for (int q = 0; q < 8; q++) {
      #pragma unroll
      for (int j = 0; j < 4; j++) {
        hs[q * 4 + j] = fmaf(hs[q * 4 + j], dav, a * Bv[q][j]);
        acc4[j] = fmaf(hs[q * 4 + j], Cv[q][j], acc4[j]);
      }
    }
    yo[(size_t)t * D_INNER] = __float2bfloat16((acc4[0] + acc4[1]) + (acc4[2] + acc4[3]));
    #pragma unroll
    for (int q = 0; q < 8; q++) { Bv[q] = Bn[q]; Cv[q] = Cn[q]; }
    xv = xn; dtv = dtn; dav = dan;
  }
}

// ---------------------------------------------------------------------------
// y = ypart0 + ypart1 + D*x;  y *= silu(z);  RMSNorm * norm_w -> bf16
// ---------------------------------------------------------------------------
__global__ __launch_bounds__(256)
void gate_rms_kernel(const bf16* __restrict__ ypart, const float* __restrict__ xact,
                     const bf16* __restrict__ zxb, const bf16* __restrict__ Dp,
                     const bf16* __restrict__ nw, bf16* __restrict__ yn)
{
  int row = blockIdx.x, t = threadIdx.x;
  __shared__ float rq[4];
  float yv[8]; float ss = 0.f;
  #pragma unroll
  for (int i = 0; i < 8; i++) {
    int c = t + 256 * i;
    float y = __bfloat162float(ypart[(size_t)row * D_INNER + c]) +
              __bfloat162float(ypart[((size_t)NROWS + row) * D_INNER + c]) +
              __bfloat162float(Dp[c >> 6]) * xact[(size_t)row * CONV_DIM + c];
    float z = __bfloat162float(zxb[(size_t)row * D_IN_PROJ + c]);
    yv[i] = y * (z / (1.f + expf(-z)));
    ss += yv[i] * yv[i];
  }
  #pragma unroll
  for (int o = 32; o; o >>= 1) ss += __shfl_down(ss, o);
  if ((t & 63) == 0) rq[t >> 6] = ss;
  __syncthreads();
  float tot = rq[0] + rq[1] + rq[2] + rq[3];
  float rr = rsqrtf(tot * (1.f / D_INNER) + 1e-5f);
  #pragma unroll
  for (int i = 0; i < 8; i++) {
    int c = t + 256 * i;
    yn[(size_t)row * D_INNER + c] =
        __float2bfloat16(yv[i] * rr * __bfloat162float(nw[c]));
  }
}

// ---------------------------------------------------------------------------
// ln2 on fp32 x2 -> bf16
// ---------------------------------------------------------------------------
__global__ __launch_bounds__(256)
void ln2_kernel(const float* __restrict__ xin, const bf16* __restrict__ w,
                const bf16* __restrict__ b, bf16* __restrict__ out)
{
  int row = blockIdx.x, t = threadIdx.x;
  const float* xr = xin + (size_t)row * D_MODEL;
  __shared__ float rs[4], rq[4];
  float v[4], s = 0.f, ss = 0.f;
  #pragma unroll
  for (int i = 0; i < 4; i++) {
    v[i] = xr[t + 256 * i];
    s += v[i]; ss += v[i] * v[i];
  }
  #pragma unroll
  for (int o = 32; o; o >>= 1) { s += __shfl_down(s, o); ss += __shfl_down(ss, o); }
  if ((t & 63) == 0) { rs[t >> 6] = s; rq[t >> 6] = ss; }
  __syncthreads();
  float S = rs[0] + rs[1] + rs[2] + rs[3];
  float Q = rq[0] + rq[1] + rq[2] + rq[3];
  float mean = S * (1.f / D_MODEL);
  float rstd = rsqrtf(Q * (1.f / D_MODEL) - mean * mean + 1e-5f);
  #pragma unroll
  for (int i = 0; i < 4; i++) {
    int c = t + 256 * i;
    out[(size_t)row * D_MODEL + c] =
        __float2bfloat16((v[i] - mean) * rstd * __bfloat162float(w[c]) + __bfloat162float(b[c]));
  }
}

// ---------------------------------------------------------------------------
extern "C" void kernel_launch(void* const* d_in, const int* in_sizes, int n_in,
                              void* d_out, int out_size, void* d_ws, size_t ws_size,
                              hipStream_t stream)
{
  char* ws = (char*)d_ws;
  // pipeline buffers (aliases safe per kernel timeline):
  bf16*  x0b   = (bf16*) (ws + 0);           //  8,388,608  (residual, dies @ out_proj)
  bf16*  x1b   = (bf16*) (ws + 8388608);     //  8,388,608  (dies @ in_proj)
  bf16*  zxb   = (bf16*) (ws + 16777216);    // 34,865,152  (dies @ gate_rms)
  float* x2f   = (float*)(ws + 16777216);    // 16,777,216  ALIAS zxb (born @ out_proj)
  float* xact  = (float*)(ws + 51642368);    // 35,651,584  (dies @ gate_rms)
  bf16*  gbuf  = (bf16*) (ws + 51642368);    // 33,554,432  ALIAS xact (born @ ffn1)
  float* dtsb  = (float*)(ws + 87293952);    //    524,288
  float* dab   = (float*)(ws + 87818240);    //    524,288
  bf16*  ypart = (bf16*) (ws + 88342528);    // 33,554,432  (born @ scan, dies @ gate_rms)
  bf16*  hln   = (bf16*) (ws + 88342528);    //  8,388,608  ALIAS ypart (born @ ln2)
  bf16*  ynb   = (bf16*) (ws + 121896960);   // 16,777,216
  // normalized bf16 input copies:
  bf16*  xcvt  = (bf16*) (ws + 88342528);    //  8,388,608  ALIAS ypart (dies @ ln01, ypart born @ scan)
  bf16*  wproj = (bf16*) (ws + 96731136);    //  8,716,288  ALIAS ypart (dies @ in_proj)
  bf16*  wout  = (bf16*) (ws + 138674176);   //  4,194,304
  bf16*  w1c   = (bf16*) (ws + 142868480);   //  8,388,608
  bf16*  w2c   = (bf16*) (ws + 151257088);   //  8,388,608
  bf16*  ln0w  = (bf16*) (ws + 159645696);
  bf16*  ln0b  = (bf16*) (ws + 159647744);
  bf16*  ln1w  = (bf16*) (ws + 159649792);
  bf16*  ln1b  = (bf16*) (ws + 159651840);
  bf16*  ln2w  = (bf16*) (ws + 159653888);
  bf16*  ln2b  = (bf16*) (ws + 159655936);
  bf16*  convw = (bf16*) (ws + 159657984);
  bf16*  convb = (bf16*) (ws + 159675392);
  bf16*  dtb   = (bf16*) (ws + 159679744);
  bf16*  alog  = (bf16*) (ws + 159679808);
  bf16*  Dp    = (bf16*) (ws + 159679872);
  bf16*  normw = (bf16*) (ws + 159679936);
  bf16*  b1c   = (bf16*) (ws + 159684032);
  bf16*  b2c   = (bf16*) (ws + 159692224);
  int*   flag  = (int*)  (ws + 159694272);

  detect_kernel<<<1, 64, 0, stream>>>((const unsigned short*)d_in[0], flag);

  CvtArgs ca;
  void* dsts[NT] = { xcvt, ln0w, ln0b, ln1w, ln1b, ln2w, ln2b, wproj, convw, convb,
                     dtb, alog, Dp, normw, wout, w1c, b1c, w2c, b2c };
  int cc = 0;
  ca.ccum[0] = 0;
  for (int i = 0; i < NT; i++) {
    ca.src[i] = d_in[i];
    ca.dst[i] = dsts[i];
    ca.nel[i] = in_sizes[i];
    cc += (in_sizes[i] + 2047) / 2048;
    ca.ccum[i + 1] = cc;
  }
  cvt_kernel<<<cc, 256, 0, stream>>>(ca, flag);

  ln01_kernel<<<NROWS, 256, 0, stream>>>(xcvt, ln0w, ln0b, ln1w, ln1b, x0b, x1b);

  gemm_bt<0><<<dim3(34, 32), 256, 0, stream>>>(x1b, wproj, NROWS, D_IN_PROJ, D_MODEL,
                                               zxb, nullptr, nullptr, nullptr, nullptr, nullptr);

  conv_silu_kernel<<<dim3(9, NROWS), 256, 0, stream>>>(zxb, convw, convb, xact);
  dt_kernel<<<(NROWS * NHEADS) / 256, 256, 0, stream>>>(zxb, dtb, alog, dtsb, dab);

  scan_kernel<<<BSZ * NHEADS, 128, 0, stream>>>(xact, dtsb, dab, ypart);

  gate_rms_kernel<<<NROWS, 256, 0, stream>>>(ypart, xact, zxb, Dp, normw, ynb);

  gemm_bt<1><<<dim3(8, 32), 256, 0, stream>>>(ynb, wout, NROWS, D_MODEL, D_INNER,
                                              nullptr, x2f, nullptr, x0b, nullptr, nullptr);

  ln2_kernel<<<NROWS, 256, 0, stream>>>(x2f, ln2w, ln2b, hln);

  gemm_bt<2><<<dim3(32, 32), 256, 0, stream>>>(hln, w1c, NROWS, FFN_DIM, D_MODEL,
                                               gbuf, nullptr, b1c, nullptr, nullptr, nullptr);

  gemm_bt<3><<<dim3(8, 32), 256, 0, stream>>>(gbuf, w2c, NROWS, D_MODEL, FFN_DIM,
                                              (bf16*)d_out, (float*)d_out, b2c, nullptr, x2f, flag);
}

// Round 4
// 702.175 us; speedup vs baseline: 2.7294x; 2.7294x over previous
//
#include <hip/hip_runtime.h>
#include <hip/hip_bf16.h>
#include <math.h>

typedef __hip_bfloat16 bf16;
typedef __bf16 bhalf;
typedef bhalf bhalf8 __attribute__((ext_vector_type(8)));
typedef float f32x4 __attribute__((ext_vector_type(4)));

#define D_MODEL   1024
#define D_STATE   64
#define HEADDIM   64
#define D_INNER   2048
#define NHEADS    32
#define CONV_DIM  2176
#define D_IN_PROJ 4256
#define FFN_DIM   4096
#define BSZ       2
#define SEQ       2048
#define NROWS     (BSZ*SEQ)
#define TC        64                // scan chunk length
#define NCH       (SEQ/TC)          // 32 chunks

// ---------------------------------------------------------------------------
// Input dtype detection (kept from round 3; inputs are fp32 => flag=1).
// ---------------------------------------------------------------------------
__global__ __launch_bounds__(64)
void detect_kernel(const unsigned short* __restrict__ x, int* __restrict__ flagp)
{
  int bad = 0;
  for (int i = threadIdx.x; i < 4096; i += 64) {
    unsigned u = ((unsigned)x[i]) << 16;
    float v = __uint_as_float(u);
    if (!(fabsf(v) <= 1e6f)) bad = 1;   // catches NaN too
  }
  unsigned long long any = __ballot(bad);
  if (threadIdx.x == 0) *flagp = (any != 0ULL) ? 1 : 0;
}

// ---------------------------------------------------------------------------
// Normalize all inputs to bf16 workspace copies (cvt if fp32, copy if bf16).
// ---------------------------------------------------------------------------
#define NT 19
struct CvtArgs {
  const void* src[NT];
  void*       dst[NT];
  int ccum[NT + 1];
  int nel[NT];
};

__global__ __launch_bounds__(256)
void cvt_kernel(CvtArgs a, const int* __restrict__ flagp)
{
  int c = blockIdx.x;
  int ti = 0;
  while (c >= a.ccum[ti + 1]) ti++;          // block-uniform, <=19 iters
  int base = (c - a.ccum[ti]) * 2048;
  int n = a.nel[ti];
  if (*flagp) {
    const float* s = (const float*)a.src[ti];
    bf16* d = (bf16*)a.dst[ti];
    for (int i = threadIdx.x; i < 2048; i += 256) {
      int j = base + i;
      if (j < n) d[j] = __float2bfloat16(s[j]);
    }
  } else {
    const unsigned short* s = (const unsigned short*)a.src[ti];
    unsigned short* d = (unsigned short*)a.dst[ti];
    for (int i = threadIdx.x; i < 2048; i += 256) {
      int j = base + i;
      if (j < n) d[j] = s[j];
    }
  }
}

// ---------------------------------------------------------------------------
// GEMM: C[M,N] = A[M,K] @ W[N,K]^T, bf16 inputs, fp32 accum, fused epilogues.
// ---------------------------------------------------------------------------
template<int EPI>
__global__ __launch_bounds__(256, 2)
void gemm_bt(const bf16* __restrict__ A, const bf16* __restrict__ W,
             int M, int N, int K,
             bf16* __restrict__ outB, float* __restrict__ outF,
             const bf16* __restrict__ bias,
             const bf16* __restrict__ resB,
             const float* __restrict__ resF,
             const int* __restrict__ flagp)
{
  __shared__ __align__(16) bhalf sA[128 * 32];
  __shared__ __align__(16) bhalf sW[128 * 32];
  const int t    = threadIdx.x;
  const int n0   = blockIdx.x * 128;
  const int m0   = blockIdx.y * 128;
  const int w    = t >> 6;
  const int lane = t & 63;
  const int wm   = (w >> 1) * 64;
  const int wn   = (w & 1) * 64;
  const int lr   = lane & 15;
  const int lq   = lane >> 4;
  const int srow = t >> 2;
  const int scol = (t & 3) * 8;

  const bool f32o = (EPI == 3) && (flagp != nullptr) && (*flagp != 0);

  f32x4 acc[4][4];
  #pragma unroll
  for (int i = 0; i < 4; i++)
    #pragma unroll
    for (int j = 0; j < 4; j++)
      acc[i][j] = (f32x4){0.f, 0.f, 0.f, 0.f};

  for (int k0 = 0; k0 < K; k0 += 32) {
    bhalf8 ta[2], tw[2];
    #pragma unroll
    for (int hh = 0; hh < 2; hh++) {
      int row = hh * 64 + srow;
      ta[hh] = *(const bhalf8*)(A + (size_t)(m0 + row) * K + k0 + scol);
      int wr = n0 + row; wr = wr < N ? wr : N - 1;
      tw[hh] = *(const bhalf8*)(W + (size_t)wr * K + k0 + scol);
    }
    #pragma unroll
    for (int hh = 0; hh < 2; hh++) {
      int row = hh * 64 + srow;
      *(bhalf8*)(sA + row * 32 + scol) = ta[hh];
      *(bhalf8*)(sW + row * 32 + scol) = tw[hh];
    }
    __syncthreads();
    bhalf8 af[4], bfr[4];
    #pragma unroll
    for (int i = 0; i < 4; i++)
      af[i] = *(const bhalf8*)(sA + (wm + i * 16 + lr) * 32 + lq * 8);
    #pragma unroll
    for (int j = 0; j < 4; j++)
      bfr[j] = *(const bhalf8*)(sW + (wn + j * 16 + lr) * 32 + lq * 8);
    #pragma unroll
    for (int i = 0; i < 4; i++)
      #pragma unroll
      for (int j = 0; j < 4; j++)
        acc[i][j] = __builtin_amdgcn_mfma_f32_16x16x32_bf16(af[i], bfr[j], acc[i][j], 0, 0, 0);
    __syncthreads();
  }

  #pragma unroll
  for (int i = 0; i < 4; i++) {
    #pragma unroll
    for (int j = 0; j < 4; j++) {
      #pragma unroll
      for (int r = 0; r < 4; r++) {
        int m = m0 + wm + i * 16 + lq * 4 + r;
        int n = n0 + wn + j * 16 + lr;
        if (n < N) {
          float v = acc[i][j][r];
          size_t idx = (size_t)m * N + n;
          if (EPI == 0) {
            outB[idx] = __float2bfloat16(v);
          } else if (EPI == 1) {
            outF[idx] = v + __bfloat162float(resB[idx]);
          } else if (EPI == 2) {
            v += __bfloat162float(bias[n]);
            outB[idx] = __float2bfloat16(0.5f * v * (1.0f + erff(v * 0.70710678118654752f)));
          } else {
            v += __bfloat162float(bias[n]) + resF[idx];
            if (f32o) outF[idx] = v;
            else      outB[idx] = __float2bfloat16(v);
          }
        }
      }
    }
  }
}

// ---------------------------------------------------------------------------
// Fused ln0 + ln1.
// ---------------------------------------------------------------------------
__global__ __launch_bounds__(256)
void ln01_kernel(const bf16* __restrict__ x,
                 const bf16* __restrict__ w0, const bf16* __restrict__ b0,
                 const bf16* __restrict__ w1, const bf16* __restrict__ b1,
                 bf16* __restrict__ x0o, bf16* __restrict__ x1o)
{
  int row = blockIdx.x, t = threadIdx.x;
  const bf16* xr = x + (size_t)row * D_MODEL;
  __shared__ float rs[4], rq[4];
  float v[4], s = 0.f, ss = 0.f;
  #pragma unroll
  for (int i = 0; i < 4; i++) {
    v[i] = __bfloat162float(xr[t + 256 * i]);
    s += v[i]; ss += v[i] * v[i];
  }
  #pragma unroll
  for (int o = 32; o; o >>= 1) { s += __shfl_down(s, o); ss += __shfl_down(ss, o); }
  if ((t & 63) == 0) { rs[t >> 6] = s; rq[t >> 6] = ss; }
  __syncthreads();
  float S = rs[0] + rs[1] + rs[2] + rs[3];
  float Q = rq[0] + rq[1] + rq[2] + rq[3];
  float mean = S * (1.f / D_MODEL);
  float rstd = rsqrtf(Q * (1.f / D_MODEL) - mean * mean + 1e-5f);
  float u[4]; s = 0.f; ss = 0.f;
  #pragma unroll
  for (int i = 0; i < 4; i++) {
    int c = t + 256 * i;
    u[i] = (v[i] - mean) * rstd * __bfloat162float(w0[c]) + __bfloat162float(b0[c]);
    s += u[i]; ss += u[i] * u[i];
    x0o[(size_t)row * D_MODEL + c] = __float2bfloat16(u[i]);
  }
  __syncthreads();
  #pragma unroll
  for (int o = 32; o; o >>= 1) { s += __shfl_down(s, o); ss += __shfl_down(ss, o); }
  if ((t & 63) == 0) { rs[t >> 6] = s; rq[t >> 6] = ss; }
  __syncthreads();
  S = rs[0] + rs[1] + rs[2] + rs[3];
  Q = rq[0] + rq[1] + rq[2] + rq[3];
  mean = S * (1.f / D_MODEL);
  rstd = rsqrtf(Q * (1.f / D_MODEL) - mean * mean + 1e-5f);
  #pragma unroll
  for (int i = 0; i < 4; i++) {
    int c = t + 256 * i;
    x1o[(size_t)row * D_MODEL + c] =
        __float2bfloat16((u[i] - mean) * rstd * __bfloat162float(w1[c]) + __bfloat162float(b1[c]));
  }
}

// ---------------------------------------------------------------------------
// Causal depthwise conv (k=4) + SiLU.
// ---------------------------------------------------------------------------
__global__ __launch_bounds__(256)
void conv_silu_kernel(const bf16* __restrict__ zxb, const bf16* __restrict__ cw,
                      const bf16* __restrict__ cb, float* __restrict__ xact)
{
  int c = blockIdx.x * 256 + threadIdx.x;
  int row = blockIdx.y;
  if (c >= CONV_DIM) return;
  int l = row & (SEQ - 1);
  float acc = __bfloat162float(cb[c]);
  #pragma unroll
  for (int k = 0; k < 4; k++) {
    int lt = l - 3 + k;
    if (lt >= 0)
      acc += __bfloat162float(zxb[(size_t)(row - 3 + k) * D_IN_PROJ + D_INNER + c]) *
             __bfloat162float(cw[c * 4 + k]);
  }
  xact[(size_t)row * CONV_DIM + c] = acc / (1.f + expf(-acc));
}

// ---------------------------------------------------------------------------
// dt = softplus(raw + dt_bias); dA = exp(dt * -exp(A_log))
// ---------------------------------------------------------------------------
__global__ __launch_bounds__(256)
void dt_kernel(const bf16* __restrict__ zxb, const bf16* __restrict__ dt_bias,
               const bf16* __restrict__ A_log, float* __restrict__ dts,
               float* __restrict__ dab)
{
  int i = blockIdx.x * 256 + threadIdx.x;
  int row = i >> 5, h = i & 31;
  float v = __bfloat162float(zxb[(size_t)row * D_IN_PROJ + (D_INNER + CONV_DIM) + h]) +
            __bfloat162float(dt_bias[h]);
  float sp = (v > 20.f) ? v : log1pf(expf(v));
  dts[i] = sp;
  dab[i] = expf(-sp * expf(__bfloat162float(A_log[h])));
}

// ---------------------------------------------------------------------------
// Chunked scan, pass 1 (!EMIT) and pass 3 (EMIT).
// Grid = NCH*64 blocks: bid = c*64 + bh (64 blocks of one chunk share B/C in L2).
// 128 threads: wave g in {0,1} owns states n in [32g,32g+32), lane = p.
// !EMIT: from h=0, compute chunk state S_c -> Sbuf (bf16) and a_c = prod dA.
// EMIT: seed h from Sbuf (holds incoming state after pass 2), emit y partials.
// ---------------------------------------------------------------------------
template<bool EMIT>
__global__ __launch_bounds__(128)
void scan_chunk_kernel(const float* __restrict__ xact, const float* __restrict__ dts,
                       const float* __restrict__ dab, bf16* __restrict__ Sbuf,
                       float* __restrict__ acb, bf16* __restrict__ ypart)
{
  const int bid = blockIdx.x;
  const int bh = bid & 63, c = bid >> 6;
  const int b = bh >> 5, h = bh & 31;
  const int g = threadIdx.x >> 6, p = threadIdx.x & 63;
  const int t0 = c * TC;
  const float* base  = xact + (size_t)b * SEQ * CONV_DIM;
  const float* Bbase = base + D_INNER + g * 32;
  const float* Cbase = base + D_INNER + D_STATE + g * 32;
  const float* xbase = base + h * 64 + p;
  const float* dtp = dts + (size_t)b * SEQ * NHEADS + h;
  const float* dap = dab + (size_t)b * SEQ * NHEADS + h;
  bf16* sp = Sbuf + ((size_t)bh * NCH + c) * (HEADDIM * D_STATE) + p * 64 + g * 32;

  float hs[32];
  if constexpr (EMIT) {
    #pragma unroll
    for (int n = 0; n < 32; n++) hs[n] = __bfloat162float(sp[n]);
  } else {
    #pragma unroll
    for (int n = 0; n < 32; n++) hs[n] = 0.f;
  }
  float prod = 1.f;
  bf16* yo = ypart + (size_t)(g * BSZ + b) * SEQ * D_INNER + h * 64 + p;

  f32x4 Bv[8], Cv[8], Bn[8], Cn[8];
  float xv, dtv, dav;
  float xn = 0.f, dtn = 0.f, dan = 0.f;
  #pragma unroll
  for (int q = 0; q < 8; q++) { Bn[q] = (f32x4){0,0,0,0}; Cn[q] = (f32x4){0,0,0,0}; }

  {
    const f32x4* Bp = (const f32x4*)(Bbase + (size_t)t0 * CONV_DIM);
    #pragma unroll
    for (int q = 0; q < 8; q++) Bv[q] = Bp[q];
    if constexpr (EMIT) {
      const f32x4* Cp = (const f32x4*)(Cbase + (size_t)t0 * CONV_DIM);
      #pragma unroll
      for (int q = 0; q < 8; q++) Cv[q] = Cp[q];
    }
    xv = xbase[(size_t)t0 * CONV_DIM];
    dtv = dtp[(size_t)t0 * NHEADS];
    dav = dap[(size_t)t0 * NHEADS];
  }

  for (int u = 0; u < TC; u++) {
    const int t = t0 + u;
    if (u + 1 < TC) {
      const f32x4* Bp = (const f32x4*)(Bbase + (size_t)(t + 1) * CONV_DIM);
      #pragma unroll
      for (int q = 0; q < 8; q++) Bn[q] = Bp[q];
      if constexpr (EMIT) {
        const f32x4* Cp = (const f32x4*)(Cbase + (size_t)(t + 1) * CONV_DIM);
        #pragma unroll
        for (int q = 0; q < 8; q++) Cn[q] = Cp[q];
      }
      xn  = xbase[(size_t)(t + 1) * CONV_DIM];
      dtn = dtp[(size_t)(t + 1) * NHEADS];
      dan = dap[(size_t)(t + 1) * NHEADS];
    }
    float a = dtv * xv;
    if constexpr (!EMIT) prod *= dav;
    f32x4 acc4 = (f32x4){0.f, 0.f, 0.f, 0.f};
    #pragma unroll
    for (int q = 0; q < 8; q++) {
      #pragma unroll
      for (int j = 0; j < 4; j++) {
        hs[q * 4 + j] = fmaf(hs[q * 4 + j], dav, a * Bv[q][j]);
        if constexpr (EMIT)
          acc4[j] = fmaf(hs[q * 4 + j], Cv[q][j], acc4[j]);
      }
    }
    if constexpr (EMIT)
      yo[(size_t)t * D_INNER] = __float2bfloat16((acc4[0] + acc4[1]) + (acc4[2] + acc4[3]));
    #pragma unroll
    for (int q = 0; q < 8; q++) { Bv[q] = Bn[q]; if constexpr (EMIT) Cv[q] = Cn[q]; }
    xv = xn; dtv = dtn; dav = dan;
  }

  if constexpr (!EMIT) {
    #pragma unroll
    for (int n = 0; n < 32; n++) sp[n] = __float2bfloat16(hs[n]);
    if (threadIdx.x == 0) acb[bh * NCH + c] = prod;
  }
}

// ---------------------------------------------------------------------------
// Pass 2: per (b,h), per state element (p,n): H_{c+1} = a_c*H_c + S_c,
// in-place so slot c ends holding the INCOMING state of chunk c.
// Grid = 64 bh x 4 quarters; thread owns 4 elements.
// ---------------------------------------------------------------------------
__global__ __launch_bounds__(256)
void state_prop_kernel(bf16* __restrict__ Sbuf, const float* __restrict__ acb)
{
  const int bh = blockIdx.x >> 2, q = blockIdx.x & 3;
  const int t = threadIdx.x;
  bf16* sp = Sbuf + (size_t)bh * NCH * (HEADDIM * D_STATE) + q * 1024 + t;
  const float* ap = acb + bh * NCH;
  float h0 = 0.f, h1 = 0.f, h2 = 0.f, h3 = 0.f;
  for (int c = 0; c < NCH; c++) {
    bf16* pc = sp + (size_t)c * (HEADDIM * D_STATE);
    float s0 = __bfloat162float(pc[0]);
    float s1 = __bfloat162float(pc[256]);
    float s2 = __bfloat162float(pc[512]);
    float s3 = __bfloat162float(pc[768]);
    float a = ap[c];
    pc[0]   = __float2bfloat16(h0);
    pc[256] = __float2bfloat16(h1);
    pc[512] = __float2bfloat16(h2);
    pc[768] = __float2bfloat16(h3);
    h0 = fmaf(h0, a, s0); h1 = fmaf(h1, a, s1);
    h2 = fmaf(h2, a, s2); h3 = fmaf(h3, a, s3);
  }
}

// ---------------------------------------------------------------------------
// y = ypart0 + ypart1 + D*x;  y *= silu(z);  RMSNorm * norm_w -> bf16
// ---------------------------------------------------------------------------
__global__ __launch_bounds__(256)
void gate_rms_kernel(const bf16* __restrict__ ypart, const float* __restrict__ xact,
                     const bf16* __restrict__ zxb, const bf16* __restrict__ Dp,
                     const bf16* __restrict__ nw, bf16* __restrict__ yn)
{
  int row = blockIdx.x, t = threadIdx.x;
  __shared__ float rq[4];
  float yv[8]; float ss = 0.f;
  #pragma unroll
  for (int i = 0; i < 8; i++) {
    int c = t + 256 * i;
    float y = __bfloat162float(ypart[(size_t)row * D_INNER + c]) +
              __bfloat162float(ypart[((size_t)NROWS + row) * D_INNER + c]) +
              __bfloat162float(Dp[c >> 6]) * xact[(size_t)row * CONV_DIM + c];
    float z = __bfloat162float(zxb[(size_t)row * D_IN_PROJ + c]);
    yv[i] = y * (z / (1.f + expf(-z)));
    ss += yv[i] * yv[i];
  }
  #pragma unroll
  for (int o = 32; o; o >>= 1) ss += __shfl_down(ss, o);
  if ((t & 63) == 0) rq[t >> 6] = ss;
  __syncthreads();
  float tot = rq[0] + rq[1] + rq[2] + rq[3];
  float rr = rsqrtf(tot * (1.f / D_INNER) + 1e-5f);
  #pragma unroll
  for (int i = 0; i < 8; i++) {
    int c = t + 256 * i;
    yn[(size_t)row * D_INNER + c] =
        __float2bfloat16(yv[i] * rr * __bfloat162float(nw[c]));
  }
}

// ---------------------------------------------------------------------------
// ln2 on fp32 x2 -> bf16
// ---------------------------------------------------------------------------
__global__ __launch_bounds__(256)
void ln2_kernel(const float* __restrict__ xin, const bf16* __restrict__ w,
                const bf16* __restrict__ b, bf16* __restrict__ out)
{
  int row = blockIdx.x, t = threadIdx.x;
  const float* xr = xin + (size_t)row * D_MODEL;
  __shared__ float rs[4], rq[4];
  float v[4], s = 0.f, ss = 0.f;
  #pragma unroll
  for (int i = 0; i < 4; i++) {
    v[i] = xr[t + 256 * i];
    s += v[i]; ss += v[i] * v[i];
  }
  #pragma unroll
  for (int o = 32; o; o >>= 1) { s += __shfl_down(s, o); ss += __shfl_down(ss, o); }
  if ((t & 63) == 0) { rs[t >> 6] = s; rq[t >> 6] = ss; }
  __syncthreads();
  float S = rs[0] + rs[1] + rs[2] + rs[3];
  float Q = rq[0] + rq[1] + rq[2] + rq[3];
  float mean = S * (1.f / D_MODEL);
  float rstd = rsqrtf(Q * (1.f / D_MODEL) - mean * mean + 1e-5f);
  #pragma unroll
  for (int i = 0; i < 4; i++) {
    int c = t + 256 * i;
    out[(size_t)row * D_MODEL + c] =
        __float2bfloat16((v[i] - mean) * rstd * __bfloat162float(w[c]) + __bfloat162float(b[c]));
  }
}

// ---------------------------------------------------------------------------
extern "C" void kernel_launch(void* const* d_in, const int* in_sizes, int n_in,
                              void* d_out, int out_size, void* d_ws, size_t ws_size,
                              hipStream_t stream)
{
  char* ws = (char*)d_ws;
  // Workspace layout, lifetime-audited (kernels numbered: 1 detect, 2 cvt,
  // 3 ln01, 4 in_proj, 5 conv, 6 dt, 7 scanP1, 8 stateProp, 9 scanP3,
  // 10 gate_rms, 11 out_proj, 12 ln2, 13 ffn1, 14 ffn2). Peak 158,973,952 B.
  bf16*  xcvt  = (bf16*) (ws + 0);           //  8,388,608  [2->3]
  bf16*  x1b   = (bf16*) (ws + 8388608);     //  8,388,608  [3->4]
  bf16*  Sbuf  = (bf16*) (ws + 0);           // 16,777,216  [7->9]  alias xcvt+x1b
  bf16*  ynb   = (bf16*) (ws + 0);           // 16,777,216  [10->11] alias Sbuf
  bf16*  wproj = (bf16*) (ws + 16777216);    //  8,716,288  [2->4]
  float* acb   = (float*)(ws + 16777216);    //      8,192  [7->8]  alias wproj
  float* dtsb  = (float*)(ws + 16785408);    //    524,288  [6->9]  alias wproj
  float* dab   = (float*)(ws + 17309696);    //    524,288  [6->9]  alias wproj
  bf16*  wout  = (bf16*) (ws + 25493504);    //  4,194,304  [2->11]
  bf16*  w1c   = (bf16*) (ws + 29687808);    //  8,388,608  [2->13]
  bf16*  w2c   = (bf16*) (ws + 38076416);    //  8,388,608  [2->14]
  bf16*  ln0w  = (bf16*) (ws + 46465024);
  bf16*  ln0b  = (bf16*) (ws + 46467072);
  bf16*  ln1w  = (bf16*) (ws + 46469120);
  bf16*  ln1b  = (bf16*) (ws + 46471168);
  bf16*  ln2w  = (bf16*) (ws + 46473216);
  bf16*  ln2b  = (bf16*) (ws + 46475264);
  bf16*  convw = (bf16*) (ws + 46477312);    //     17,408
  bf16*  convb = (bf16*) (ws + 46494720);    //      4,352
  bf16*  dtb   = (bf16*) (ws + 46499072);
  bf16*  alog  = (bf16*) (ws + 46499136);
  bf16*  Dp    = (bf16*) (ws + 46499200);
  bf16*  normw = (bf16*) (ws + 46499264);    //      4,096
  bf16*  b1c   = (bf16*) (ws + 46503360);    //      8,192
  bf16*  b2c   = (bf16*) (ws + 46511552);    //      2,048
  int*   flag  = (int*)  (ws + 46513600);
  bf16*  x0b   = (bf16*) (ws + 46514176);    //  8,388,608  [3->11]
  bf16*  zxb   = (bf16*) (ws + 54902784);    // 34,865,152  [4->10]
  float* x2f   = (float*)(ws + 54902784);    // 16,777,216  [11->14] alias zxb
  float* xact  = (float*)(ws + 89767936);    // 35,651,584  [5->10]
  bf16*  gbuf  = (bf16*) (ws + 89767936);    // 33,554,432  [13->14] alias xact
  bf16*  ypart = (bf16*) (ws + 125419520);   // 33,554,432  [9->10]  ends 158,973,952
  bf16*  hln   = (bf16*) (ws + 125419520);   //  8,388,608  [12->13] alias ypart

  detect_kernel<<<1, 64, 0, stream>>>((const unsigned short*)d_in[0], flag);

  CvtArgs ca;
  void* dsts[NT] = { xcvt, ln0w, ln0b, ln1w, ln1b, ln2w, ln2b, wproj, convw, convb,
                     dtb, alog, Dp, normw, wout, w1c, b1c, w2c, b2c };
  int cc = 0;
  ca.ccum[0] = 0;
  for (int i = 0; i < NT; i++) {
    ca.src[i] = d_in[i];
    ca.dst[i] = dsts[i];
    ca.nel[i] = in_sizes[i];
    cc += (in_sizes[i] + 2047) / 2048;
    ca.ccum[i + 1] = cc;
  }
  cvt_kernel<<<cc, 256, 0, stream>>>(ca, flag);

  ln01_kernel<<<NROWS, 256, 0, stream>>>(xcvt, ln0w, ln0b, ln1w, ln1b, x0b, x1b);

  gemm_bt<0><<<dim3(34, 32), 256, 0, stream>>>(x1b, wproj, NROWS, D_IN_PROJ, D_MODEL,
                                               zxb, nullptr, nullptr, nullptr, nullptr, nullptr);

  conv_silu_kernel<<<dim3(9, NROWS), 256, 0, stream>>>(zxb, convw, convb, xact);
  dt_kernel<<<(NROWS * NHEADS) / 256, 256, 0, stream>>>(zxb, dtb, alog, dtsb, dab);

  scan_chunk_kernel<false><<<NCH * 64, 128, 0, stream>>>(xact, dtsb, dab, Sbuf, acb, nullptr);
  state_prop_kernel<<<64 * 4, 256, 0, stream>>>(Sbuf, acb);
  scan_chunk_kernel<true><<<NCH * 64, 128, 0, stream>>>(xact, dtsb, dab, Sbuf, nullptr, ypart);

  gate_rms_kernel<<<NROWS, 256, 0, stream>>>(ypart, xact, zxb, Dp, normw, ynb);

  gemm_bt<1><<<dim3(8, 32), 256, 0, stream>>>(ynb, wout, NROWS, D_MODEL, D_INNER,
                                              nullptr, x2f, nullptr, x0b, nullptr, nullptr);

  ln2_kernel<<<NROWS, 256, 0, stream>>>(x2f, ln2w, ln2b, hln);

  gemm_bt<2><<<dim3(32, 32), 256, 0, stream>>>(hln, w1c, NROWS, FFN_DIM, D_MODEL,
                                               gbuf, nullptr, b1c, nullptr, nullptr, nullptr);

  gemm_bt<3><<<dim3(8, 32), 256, 0, stream>>>(gbuf, w2c, NROWS, D_MODEL, FFN_DIM,
                                              (bf16*)d_out, (float*)d_out, b2c, nullptr, x2f, flag);
}

// Round 5
// 540.359 us; speedup vs baseline: 3.5468x; 1.2995x over previous
//
#include <hip/hip_runtime.h>
#include <hip/hip_bf16.h>
#include <math.h>

typedef __hip_bfloat16 bf16;
typedef __bf16 bhalf;
typedef bhalf bhalf8 __attribute__((ext_vector_type(8)));
typedef float f32x4 __attribute__((ext_vector_type(4)));

#define D_MODEL   1024
#define D_STATE   64
#define HEADDIM   64
#define D_INNER   2048
#define NHEADS    32
#define CONV_DIM  2176
#define D_IN_PROJ 4256
#define FFN_DIM   4096
#define BSZ       2
#define SEQ       2048
#define NROWS     (BSZ*SEQ)
#define TC        64                // scan chunk length
#define NCH       (SEQ/TC)          // 32 chunks

#define AS1 __attribute__((address_space(1)))
#define AS3 __attribute__((address_space(3)))
__device__ __forceinline__ void load_lds16(const void* g, void* l) {
  __builtin_amdgcn_global_load_lds((AS1 void*)g, (AS3 void*)l, 16, 0, 0);
}

// ---------------------------------------------------------------------------
// Input dtype detection (inputs proven fp32 => flag=1; kept for robustness).
// ---------------------------------------------------------------------------
__global__ __launch_bounds__(64)
void detect_kernel(const unsigned short* __restrict__ x, int* __restrict__ flagp)
{
  int bad = 0;
  for (int i = threadIdx.x; i < 4096; i += 64) {
    unsigned u = ((unsigned)x[i]) << 16;
    float v = __uint_as_float(u);
    if (!(fabsf(v) <= 1e6f)) bad = 1;
  }
  unsigned long long any = __ballot(bad);
  if (threadIdx.x == 0) *flagp = (any != 0ULL) ? 1 : 0;
}

// ---------------------------------------------------------------------------
// Normalize all inputs to bf16 workspace copies.
// ---------------------------------------------------------------------------
#define NT 19
struct CvtArgs {
  const void* src[NT];
  void*       dst[NT];
  int ccum[NT + 1];
  int nel[NT];
};

__global__ __launch_bounds__(256)
void cvt_kernel(CvtArgs a, const int* __restrict__ flagp)
{
  int c = blockIdx.x;
  int ti = 0;
  while (c >= a.ccum[ti + 1]) ti++;
  int base = (c - a.ccum[ti]) * 2048;
  int n = a.nel[ti];
  if (*flagp) {
    const float* s = (const float*)a.src[ti];
    bf16* d = (bf16*)a.dst[ti];
    for (int i = threadIdx.x; i < 2048; i += 256) {
      int j = base + i;
      if (j < n) d[j] = __float2bfloat16(s[j]);
    }
  } else {
    const unsigned short* s = (const unsigned short*)a.src[ti];
    unsigned short* d = (unsigned short*)a.dst[ti];
    for (int i = threadIdx.x; i < 2048; i += 256) {
      int j = base + i;
      if (j < n) d[j] = s[j];
    }
  }
}

// ---------------------------------------------------------------------------
// GEMM: C[M,N] = A[M,K] @ W[N,K]^T, bf16, fp32 accum, fused epilogues.
// m97 pattern: global_load_lds width=16 staging (proven executable in round 0).
// ---------------------------------------------------------------------------
template<int EPI>
__global__ __launch_bounds__(256, 2)
void gemm_bt(const bf16* __restrict__ A, const bf16* __restrict__ W,
             int M, int N, int K,
             bf16* __restrict__ outB, float* __restrict__ outF,
             const bf16* __restrict__ bias,
             const bf16* __restrict__ resB,
             const float* __restrict__ resF,
             const int* __restrict__ flagp)
{
  __shared__ __align__(16) bhalf sA[128 * 32];
  __shared__ __align__(16) bhalf sW[128 * 32];
  const int t    = threadIdx.x;
  const int n0   = blockIdx.x * 128;
  const int m0   = blockIdx.y * 128;
  const int w    = t >> 6;
  const int lane = t & 63;
  const int wm   = (w >> 1) * 64;
  const int wn   = (w & 1) * 64;
  const int lr   = lane & 15;
  const int lq   = lane >> 4;
  const int srow = t >> 2;
  const int scol = (t & 3) * 8;

  const bool f32o = (EPI == 3) && (flagp != nullptr) && (*flagp != 0);

  f32x4 acc[4][4];
  #pragma unroll
  for (int i = 0; i < 4; i++)
    #pragma unroll
    for (int j = 0; j < 4; j++)
      acc[i][j] = (f32x4){0.f, 0.f, 0.f, 0.f};

  for (int k0 = 0; k0 < K; k0 += 32) {
    #pragma unroll
    for (int hh = 0; hh < 2; hh++) {
      int row = hh * 64 + srow;
      load_lds16(A + (size_t)(m0 + row) * K + k0 + scol, sA + hh * 2048 + t * 8);
      int wr = n0 + row; wr = wr < N ? wr : N - 1;
      load_lds16(W + (size_t)wr * K + k0 + scol, sW + hh * 2048 + t * 8);
    }
    __syncthreads();
    bhalf8 af[4], bfr[4];
    #pragma unroll
    for (int i = 0; i < 4; i++)
      af[i] = *(const bhalf8*)(sA + (wm + i * 16 + lr) * 32 + lq * 8);
    #pragma unroll
    for (int j = 0; j < 4; j++)
      bfr[j] = *(const bhalf8*)(sW + (wn + j * 16 + lr) * 32 + lq * 8);
    #pragma unroll
    for (int i = 0; i < 4; i++)
      #pragma unroll
      for (int j = 0; j < 4; j++)
        acc[i][j] = __builtin_amdgcn_mfma_f32_16x16x32_bf16(af[i], bfr[j], acc[i][j], 0, 0, 0);
    __syncthreads();
  }

  #pragma unroll
  for (int i = 0; i < 4; i++) {
    #pragma unroll
    for (int j = 0; j < 4; j++) {
      #pragma unroll
      for (int r = 0; r < 4; r++) {
        int m = m0 + wm + i * 16 + lq * 4 + r;
        int n = n0 + wn + j * 16 + lr;
        if (n < N) {
          float v = acc[i][j][r];
          size_t idx = (size_t)m * N + n;
          if (EPI == 0) {
            outB[idx] = __float2bfloat16(v);
          } else if (EPI == 1) {
            outF[idx] = v + __bfloat162float(resB[idx]);
          } else if (EPI == 2) {
            v += __bfloat162float(bias[n]);
            outB[idx] = __float2bfloat16(0.5f * v * (1.0f + erff(v * 0.70710678118654752f)));
          } else {
            v += __bfloat162float(bias[n]) + resF[idx];
            if (f32o) outF[idx] = v;
            else      outB[idx] = __float2bfloat16(v);
          }
        }
      }
    }
  }
}

// ---------------------------------------------------------------------------
// Fused ln0 + ln1.
// ---------------------------------------------------------------------------
__global__ __launch_bounds__(256)
void ln01_kernel(const bf16* __restrict__ x,
                 const bf16* __restrict__ w0, const bf16* __restrict__ b0,
                 const bf16* __restrict__ w1, const bf16* __restrict__ b1,
                 bf16* __restrict__ x0o, bf16* __restrict__ x1o)
{
  int row = blockIdx.x, t = threadIdx.x;
  const bf16* xr = x + (size_t)row * D_MODEL;
  __shared__ float rs[4], rq[4];
  float v[4], s = 0.f, ss = 0.f;
  #pragma unroll
  for (int i = 0; i < 4; i++) {
    v[i] = __bfloat162float(xr[t + 256 * i]);
    s += v[i]; ss += v[i] * v[i];
  }
  #pragma unroll
  for (int o = 32; o; o >>= 1) { s += __shfl_down(s, o); ss += __shfl_down(ss, o); }
  if ((t & 63) == 0) { rs[t >> 6] = s; rq[t >> 6] = ss; }
  __syncthreads();
  float S = rs[0] + rs[1] + rs[2] + rs[3];
  float Q = rq[0] + rq[1] + rq[2] + rq[3];
  float mean = S * (1.f / D_MODEL);
  float rstd = rsqrtf(Q * (1.f / D_MODEL) - mean * mean + 1e-5f);
  float u[4]; s = 0.f; ss = 0.f;
  #pragma unroll
  for (int i = 0; i < 4; i++) {
    int c = t + 256 * i;
    u[i] = (v[i] - mean) * rstd * __bfloat162float(w0[c]) + __bfloat162float(b0[c]);
    s += u[i]; ss += u[i] * u[i];
    x0o[(size_t)row * D_MODEL + c] = __float2bfloat16(u[i]);
  }
  __syncthreads();
  #pragma unroll
  for (int o = 32; o; o >>= 1) { s += __shfl_down(s, o); ss += __shfl_down(ss, o); }
  if ((t & 63) == 0) { rs[t >> 6] = s; rq[t >> 6] = ss; }
  __syncthreads();
  S = rs[0] + rs[1] + rs[2] + rs[3];
  Q = rq[0] + rq[1] + rq[2] + rq[3];
  mean = S * (1.f / D_MODEL);
  rstd = rsqrtf(Q * (1.f / D_MODEL) - mean * mean + 1e-5f);
  #pragma unroll
  for (int i = 0; i < 4; i++) {
    int c = t + 256 * i;
    x1o[(size_t)row * D_MODEL + c] =
        __float2bfloat16((u[i] - mean) * rstd * __bfloat162float(w1[c]) + __bfloat162float(b1[c]));
  }
}

// ---------------------------------------------------------------------------
// Causal depthwise conv (k=4) + SiLU.
// ---------------------------------------------------------------------------
__global__ __launch_bounds__(256)
void conv_silu_kernel(const bf16* __restrict__ zxb, const bf16* __restrict__ cw,
                      const bf16* __restrict__ cb, float* __restrict__ xact)
{
  int c = blockIdx.x * 256 + threadIdx.x;
  int row = blockIdx.y;
  if (c >= CONV_DIM) return;
  int l = row & (SEQ - 1);
  float acc = __bfloat162float(cb[c]);
  #pragma unroll
  for (int k = 0; k < 4; k++) {
    int lt = l - 3 + k;
    if (lt >= 0)
      acc += __bfloat162float(zxb[(size_t)(row - 3 + k) * D_IN_PROJ + D_INNER + c]) *
             __bfloat162float(cw[c * 4 + k]);
  }
  xact[(size_t)row * CONV_DIM + c] = acc / (1.f + expf(-acc));
}

// ---------------------------------------------------------------------------
// dt = softplus(raw + dt_bias); lda = dt * A  (log of per-step decay)
// ---------------------------------------------------------------------------
__global__ __launch_bounds__(256)
void dt_kernel(const bf16* __restrict__ zxb, const bf16* __restrict__ dt_bias,
               const bf16* __restrict__ A_log, float* __restrict__ dts,
               float* __restrict__ ldab)
{
  int i = blockIdx.x * 256 + threadIdx.x;
  int row = i >> 5, h = i & 31;
  float v = __bfloat162float(zxb[(size_t)row * D_IN_PROJ + (D_INNER + CONV_DIM) + h]) +
            __bfloat162float(dt_bias[h]);
  float sp = (v > 20.f) ? v : log1pf(expf(v));
  dts[i] = sp;
  ldab[i] = -sp * expf(__bfloat162float(A_log[h]));
}

// ---------------------------------------------------------------------------
// MFMA chunk scan, pass 1: per (b,h,chunk) compute chunk state
//   H_c[n,p] = sum_u exp(ls_T - ls_u) dt_u B[u,n] X[u,p]
// via 64x64x64 matmul. Stored to Sbuf as [p*64+n]. Also a_c = exp(ls_T).
// Grid NCH*64 blocks, 256 threads (4 waves; wave w owns n-strip 16w..16w+15).
// ---------------------------------------------------------------------------
__global__ __launch_bounds__(256)
void scan_state_kernel(const float* __restrict__ xact, const float* __restrict__ dts,
                       const float* __restrict__ ldab, bf16* __restrict__ Sbuf,
                       float* __restrict__ acb)
{
  __shared__ __align__(16) bf16 wBT[64][72];   // wBT[n][u] = B[u,n]*w_u
  __shared__ __align__(16) bf16 XT[64][72];    // XT[p][u]  = X[u,p]
  __shared__ float lsS[64], dtS[64];
  const int bid = blockIdx.x;
  const int bh = bid & 63, c = bid >> 6;
  const int b = bh >> 5, h = bh & 31;
  const int t0 = c * TC;
  const int tid = threadIdx.x;
  const int w = tid >> 6, lane = tid & 63;
  const int lr = lane & 15, lq = lane >> 4;

  if (w == 0) {   // inclusive prefix sum of log-decay
    float v = ldab[(size_t)(b * SEQ + t0 + lane) * NHEADS + h];
    #pragma unroll
    for (int o = 1; o < 64; o <<= 1) {
      float up = __shfl_up(v, o);
      if (lane >= o) v += up;
    }
    lsS[lane] = v;
    dtS[lane] = dts[(size_t)(b * SEQ + t0 + lane) * NHEADS + h];
  }
  __syncthreads();
  const float lsT = lsS[63];
  {
    int nn = tid & 63, u0 = (tid >> 6) * 16;
    for (int i = 0; i < 16; i++) {
      int u = u0 + i;
      const float* rowp = xact + (size_t)(b * SEQ + t0 + u) * CONV_DIM;
      float wgt = dtS[u] * __expf(lsT - lsS[u]);
      wBT[nn][u] = __float2bfloat16(rowp[D_INNER + nn] * wgt);
      XT[nn][u]  = __float2bfloat16(rowp[h * 64 + nn]);
    }
  }
  __syncthreads();

  bhalf8 af0 = *(const bhalf8*)&wBT[16 * w + lr][lq * 8];
  bhalf8 af1 = *(const bhalf8*)&wBT[16 * w + lr][32 + lq * 8];
  bf16* sb = Sbuf + ((size_t)bh * NCH + c) * 4096;
  #pragma unroll
  for (int jt = 0; jt < 4; jt++) {
    bhalf8 xf0 = *(const bhalf8*)&XT[16 * jt + lr][lq * 8];
    bhalf8 xf1 = *(const bhalf8*)&XT[16 * jt + lr][32 + lq * 8];
    f32x4 acc = (f32x4){0.f, 0.f, 0.f, 0.f};
    acc = __builtin_amdgcn_mfma_f32_16x16x32_bf16(af0, xf0, acc, 0, 0, 0);
    acc = __builtin_amdgcn_mfma_f32_16x16x32_bf16(af1, xf1, acc, 0, 0, 0);
    #pragma unroll
    for (int r = 0; r < 4; r++) {
      int n = 16 * w + lq * 4 + r;            // D row = quad*4 + reg
      int p = 16 * jt + lr;                   // D col = lane&15
      sb[p * 64 + n] = __float2bfloat16(acc[r]);
    }
  }
  if (tid == 0) acb[bh * NCH + c] = __expf(lsT);
}

// ---------------------------------------------------------------------------
// Pass 2: H_{c+1} = a_c*H_c + S_c in-place; slot c ends = incoming state.
// ---------------------------------------------------------------------------
__global__ __launch_bounds__(256)
void state_prop_kernel(bf16* __restrict__ Sbuf, const float* __restrict__ acb)
{
  const int bh = blockIdx.x >> 2, q = blockIdx.x & 3;
  const int t = threadIdx.x;
  bf16* sp = Sbuf + (size_t)bh * NCH * 4096 + q * 1024 + t;
  const float* ap = acb + bh * NCH;
  float h0 = 0.f, h1 = 0.f, h2 = 0.f, h3 = 0.f;
  for (int c = 0; c < NCH; c++) {
    bf16* pc = sp + (size_t)c * 4096;
    float s0 = __bfloat162float(pc[0]);
    float s1 = __bfloat162float(pc[256]);
    float s2 = __bfloat162float(pc[512]);
    float s3 = __bfloat162float(pc[768]);
    float a = ap[c];
    pc[0]   = __float2bfloat16(h0);
    pc[256] = __float2bfloat16(h1);
    pc[512] = __float2bfloat16(h2);
    pc[768] = __float2bfloat16(h3);
    h0 = fmaf(h0, a, s0); h1 = fmaf(h1, a, s1);
    h2 = fmaf(h2, a, s2); h3 = fmaf(h3, a, s3);
  }
}

// ---------------------------------------------------------------------------
// MFMA chunk scan, pass 3:
//   G = C@B^T ; M[t,u] = G*exp(ls_t-ls_u)*dt_u (u<=t) ;
//   Y = M@X + diag(exp(ls_t)) * (C @ H_in)
// M round-trips D-layout -> LDS -> A-layout (flash-attn pattern, m120).
// ---------------------------------------------------------------------------
__global__ __launch_bounds__(256)
void scan_y_kernel(const float* __restrict__ xact, const float* __restrict__ dts,
                   const float* __restrict__ ldab, const bf16* __restrict__ Sbuf,
                   bf16* __restrict__ yfull)
{
  __shared__ __align__(16) bf16 Cs[64][72];    // C[t][n]
  __shared__ __align__(16) bf16 Bs[64][72];    // B[u][n]
  __shared__ __align__(16) bf16 XT[64][72];    // X^T: [p][u]
  __shared__ __align__(16) bf16 HT[64][72];    // H_in^T: [p][n]
  __shared__ __align__(16) bf16 Ms[64][72];    // M[t][u]
  __shared__ float lsS[64], dtS[64];
  const int bid = blockIdx.x;
  const int bh = bid & 63, c = bid >> 6;
  const int b = bh >> 5, h = bh & 31;
  const int t0 = c * TC;
  const int tid = threadIdx.x;
  const int w = tid >> 6, lane = tid & 63;
  const int lr = lane & 15, lq = lane >> 4;

  if (w == 0) {
    float v = ldab[(size_t)(b * SEQ + t0 + lane) * NHEADS + h];
    #pragma unroll
    for (int o = 1; o < 64; o <<= 1) {
      float up = __shfl_up(v, o);
      if (lane >= o) v += up;
    }
    lsS[lane] = v;
    dtS[lane] = dts[(size_t)(b * SEQ + t0 + lane) * NHEADS + h];
  }
  {
    int nn = tid & 63, u0 = (tid >> 6) * 16;
    for (int i = 0; i < 16; i++) {
      int u = u0 + i;
      const float* rowp = xact + (size_t)(b * SEQ + t0 + u) * CONV_DIM;
      Bs[u][nn] = __float2bfloat16(rowp[D_INNER + nn]);
      Cs[u][nn] = __float2bfloat16(rowp[D_INNER + 64 + nn]);
      XT[nn][u] = __float2bfloat16(rowp[h * 64 + nn]);
    }
    const bf16* sb = Sbuf + ((size_t)bh * NCH + c) * 4096;
    for (int i = 0; i < 16; i++) {
      int e = tid + 256 * i;
      HT[e >> 6][e & 63] = sb[e];
    }
  }
  __syncthreads();

  // A-frags of C (wave's t-strip), reused for G and C@H_in
  bhalf8 cf0 = *(const bhalf8*)&Cs[16 * w + lr][lq * 8];
  bhalf8 cf1 = *(const bhalf8*)&Cs[16 * w + lr][32 + lq * 8];
  f32x4 accH[4];
  #pragma unroll
  for (int jt = 0; jt < 4; jt++) {
    bhalf8 bf0 = *(const bhalf8*)&Bs[16 * jt + lr][lq * 8];
    bhalf8 bf1 = *(const bhalf8*)&Bs[16 * jt + lr][32 + lq * 8];
    f32x4 g = (f32x4){0.f, 0.f, 0.f, 0.f};
    g = __builtin_amdgcn_mfma_f32_16x16x32_bf16(cf0, bf0, g, 0, 0, 0);
    g = __builtin_amdgcn_mfma_f32_16x16x32_bf16(cf1, bf1, g, 0, 0, 0);
    bhalf8 hf0 = *(const bhalf8*)&HT[16 * jt + lr][lq * 8];
    bhalf8 hf1 = *(const bhalf8*)&HT[16 * jt + lr][32 + lq * 8];
    f32x4 ah = (f32x4){0.f, 0.f, 0.f, 0.f};
    ah = __builtin_amdgcn_mfma_f32_16x16x32_bf16(cf0, hf0, ah, 0, 0, 0);
    ah = __builtin_amdgcn_mfma_f32_16x16x32_bf16(cf1, hf1, ah, 0, 0, 0);
    accH[jt] = ah;
    // mask G -> M (D-layout: row t = 16w + lq*4 + r, col u = 16jt + lr)
    #pragma unroll
    for (int r = 0; r < 4; r++) {
      int t = 16 * w + lq * 4 + r;
      int u = 16 * jt + lr;
      float m = 0.f;
      if (u <= t) m = g[r] * __expf(lsS[t] - lsS[u]) * dtS[u];
      Ms[t][u] = __float2bfloat16(m);
    }
  }
  __syncthreads();

  bhalf8 mf0 = *(const bhalf8*)&Ms[16 * w + lr][lq * 8];
  bhalf8 mf1 = *(const bhalf8*)&Ms[16 * w + lr][32 + lq * 8];
  #pragma unroll
  for (int jt = 0; jt < 4; jt++) {
    bhalf8 xf0 = *(const bhalf8*)&XT[16 * jt + lr][lq * 8];
    bhalf8 xf1 = *(const bhalf8*)&XT[16 * jt + lr][32 + lq * 8];
    f32x4 acc = (f32x4){0.f, 0.f, 0.f, 0.f};
    acc = __builtin_amdgcn_mfma_f32_16x16x32_bf16(mf0, xf0, acc, 0, 0, 0);
    acc = __builtin_amdgcn_mfma_f32_16x16x32_bf16(mf1, xf1, acc, 0, 0, 0);
    #pragma unroll
    for (int r = 0; r < 4; r++) {
      int t = 16 * w + lq * 4 + r;
      int p = 16 * jt + lr;
      float y = acc[r] + __expf(lsS[t]) * accH[jt][r];
      yfull[(size_t)(b * SEQ + t0 + t) * D_INNER + h * 64 + p] = __float2bfloat16(y);
    }
  }
}

// ---------------------------------------------------------------------------
// y = yfull + D*x;  y *= silu(z);  RMSNorm * norm_w -> bf16
// ---------------------------------------------------------------------------
__global__ __launch_bounds__(256)
void gate_rms_kernel(const bf16* __restrict__ yfull, const float* __restrict__ xact,
                     const bf16* __restrict__ zxb, const bf16* __restrict__ Dp,
                     const bf16* __restrict__ nw, bf16* __restrict__ yn)
{
  int row = blockIdx.x, t = threadIdx.x;
  __shared__ float rq[4];
  float yv[8]; float ss = 0.f;
  #pragma unroll
  for (int i = 0; i < 8; i++) {
    int c = t + 256 * i;
    float y = __bfloat162float(yfull[(size_t)row * D_INNER + c]) +
              __bfloat162float(Dp[c >> 6]) * xact[(size_t)row * CONV_DIM + c];
    float z = __bfloat162float(zxb[(size_t)row * D_IN_PROJ + c]);
    yv[i] = y * (z / (1.f + expf(-z)));
    ss += yv[i] * yv[i];
  }
  #pragma unroll
  for (int o = 32; o; o >>= 1) ss += __shfl_down(ss, o);
  if ((t & 63) == 0) rq[t >> 6] = ss;
  __syncthreads();
  float tot = rq[0] + rq[1] + rq[2] + rq[3];
  float rr = rsqrtf(tot * (1.f / D_INNER) + 1e-5f);
  #pragma unroll
  for (int i = 0; i < 8; i++) {
    int c = t + 256 * i;
    yn[(size_t)row * D_INNER + c] =
        __float2bfloat16(yv[i] * rr * __bfloat162float(nw[c]));
  }
}

// ---------------------------------------------------------------------------
// ln2 on fp32 x2 -> bf16
// ---------------------------------------------------------------------------
__global__ __launch_bounds__(256)
void ln2_kernel(const float* __restrict__ xin, const bf16* __restrict__ w,
                const bf16* __restrict__ b, bf16* __restrict__ out)
{
  int row = blockIdx.x, t = threadIdx.x;
  const float* xr = xin + (size_t)row * D_MODEL;
  __shared__ float rs[4], rq[4];
  float v[4], s = 0.f, ss = 0.f;
  #pragma unroll
  for (int i = 0; i < 4; i++) {
    v[i] = xr[t + 256 * i];
    s += v[i]; ss += v[i] * v[i];
  }
  #pragma unroll
  for (int o = 32; o; o >>= 1) { s += __shfl_down(s, o); ss += __shfl_down(ss, o); }
  if ((t & 63) == 0) { rs[t >> 6] = s; rq[t >> 6] = ss; }
  __syncthreads();
  float S = rs[0] + rs[1] + rs[2] + rs[3];
  float Q = rq[0] + rq[1] + rq[2] + rq[3];
  float mean = S * (1.f / D_MODEL);
  float rstd = rsqrtf(Q * (1.f / D_MODEL) - mean * mean + 1e-5f);
  #pragma unroll
  for (int i = 0; i < 4; i++) {
    int c = t + 256 * i;
    out[(size_t)row * D_MODEL + c] =
        __float2bfloat16((v[i] - mean) * rstd * __bfloat162float(w[c]) + __bfloat162float(b[c]));
  }
}

// ---------------------------------------------------------------------------
extern "C" void kernel_launch(void* const* d_in, const int* in_sizes, int n_in,
                              void* d_out, int out_size, void* d_ws, size_t ws_size,
                              hipStream_t stream)
{
  char* ws = (char*)d_ws;
  // layout identical to round 4 (lifetimes unchanged); yfull lives in the
  // old ypart slot (now only 16.7 MB used).
  bf16*  xcvt  = (bf16*) (ws + 0);           //  [2->3]
  bf16*  x1b   = (bf16*) (ws + 8388608);     //  [3->4]
  bf16*  Sbuf  = (bf16*) (ws + 0);           //  [7->9]  alias xcvt+x1b (16.7MB)
  bf16*  ynb   = (bf16*) (ws + 0);           //  [10->11] alias Sbuf
  bf16*  wproj = (bf16*) (ws + 16777216);    //  [2->4]
  float* acb   = (float*)(ws + 16777216);    //  [7->8]  alias wproj
  float* dtsb  = (float*)(ws + 16785408);    //  [6->9]  alias wproj
  float* ldab  = (float*)(ws + 17309696);    //  [6->9]  alias wproj
  bf16*  wout  = (bf16*) (ws + 25493504);    //  [2->11]
  bf16*  w1c   = (bf16*) (ws + 29687808);    //  [2->13]
  bf16*  w2c   = (bf16*) (ws + 38076416);    //  [2->14]
  bf16*  ln0w  = (bf16*) (ws + 46465024);
  bf16*  ln0b  = (bf16*) (ws + 46467072);
  bf16*  ln1w  = (bf16*) (ws + 46469120);
  bf16*  ln1b  = (bf16*) (ws + 46471168);
  bf16*  ln2w  = (bf16*) (ws + 46473216);
  bf16*  ln2b  = (bf16*) (ws + 46475264);
  bf16*  convw = (bf16*) (ws + 46477312);
  bf16*  convb = (bf16*) (ws + 46494720);
  bf16*  dtb   = (bf16*) (ws + 46499072);
  bf16*  alog  = (bf16*) (ws + 46499136);
  bf16*  Dp    = (bf16*) (ws + 46499200);
  bf16*  normw = (bf16*) (ws + 46499264);
  bf16*  b1c   = (bf16*) (ws + 46503360);
  bf16*  b2c   = (bf16*) (ws + 46511552);
  int*   flag  = (int*)  (ws + 46513600);
  bf16*  x0b   = (bf16*) (ws + 46514176);    //  [3->11]
  bf16*  zxb   = (bf16*) (ws + 54902784);    //  [4->10]
  float* x2f   = (float*)(ws + 54902784);    //  [11->14] alias zxb
  float* xact  = (float*)(ws + 89767936);    //  [5->10]
  bf16*  gbuf  = (bf16*) (ws + 89767936);    //  [13->14] alias xact
  bf16*  yfull = (bf16*) (ws + 125419520);   //  [9->10]  16,777,216
  bf16*  hln   = (bf16*) (ws + 125419520);   //  [12->13] alias yfull

  detect_kernel<<<1, 64, 0, stream>>>((const unsigned short*)d_in[0], flag);

  CvtArgs ca;
  void* dsts[NT] = { xcvt, ln0w, ln0b, ln1w, ln1b, ln2w, ln2b, wproj, convw, convb,
                     dtb, alog, Dp, normw, wout, w1c, b1c, w2c, b2c };
  int cc = 0;
  ca.ccum[0] = 0;
  for (int i = 0; i < NT; i++) {
    ca.src[i] = d_in[i];
    ca.dst[i] = dsts[i];
    ca.nel[i] = in_sizes[i];
    cc += (in_sizes[i] + 2047) / 2048;
    ca.ccum[i + 1] = cc;
  }
  cvt_kernel<<<cc, 256, 0, stream>>>(ca, flag);

  ln01_kernel<<<NROWS, 256, 0, stream>>>(xcvt, ln0w, ln0b, ln1w, ln1b, x0b, x1b);

  gemm_bt<0><<<dim3(34, 32), 256, 0, stream>>>(x1b, wproj, NROWS, D_IN_PROJ, D_MODEL,
                                               zxb, nullptr, nullptr, nullptr, nullptr, nullptr);

  conv_silu_kernel<<<dim3(9, NROWS), 256, 0, stream>>>(zxb, convw, convb, xact);
  dt_kernel<<<(NROWS * NHEADS) / 256, 256, 0, stream>>>(zxb, dtb, alog, dtsb, ldab);

  scan_state_kernel<<<NCH * 64, 256, 0, stream>>>(xact, dtsb, ldab, Sbuf, acb);
  state_prop_kernel<<<64 * 4, 256, 0, stream>>>(Sbuf, acb);
  scan_y_kernel<<<NCH * 64, 256, 0, stream>>>(xact, dtsb, ldab, Sbuf, yfull);

  gate_rms_kernel<<<NROWS, 256, 0, stream>>>(yfull, xact, zxb, Dp, normw, ynb);

  gemm_bt<1><<<dim3(8, 32), 256, 0, stream>>>(ynb, wout, NROWS, D_MODEL, D_INNER,
                                              nullptr, x2f, nullptr, x0b, nullptr, nullptr);

  ln2_kernel<<<NROWS, 256, 0, stream>>>(x2f, ln2w, ln2b, hln);

  gemm_bt<2><<<dim3(32, 32), 256, 0, stream>>>(hln, w1c, NROWS, FFN_DIM, D_MODEL,
                                               gbuf, nullptr, b1c, nullptr, nullptr, nullptr);

  gemm_bt<3><<<dim3(8, 32), 256, 0, stream>>>(gbuf, w2c, NROWS, D_MODEL, FFN_DIM,
                                              (bf16*)d_out, (float*)d_out, b2c, nullptr, x2f, flag);
}

// Round 6
// 510.889 us; speedup vs baseline: 3.7513x; 1.0577x over previous
//
#include <hip/hip_runtime.h>
#include <hip/hip_bf16.h>
#include <math.h>

typedef __hip_bfloat16 bf16;
typedef __bf16 bhalf;
typedef bhalf bhalf8 __attribute__((ext_vector_type(8)));
typedef float f32x4 __attribute__((ext_vector_type(4)));
typedef unsigned short u16;
typedef u16 u16x4 __attribute__((ext_vector_type(4)));

#define D_MODEL   1024
#define D_STATE   64
#define HEADDIM   64
#define D_INNER   2048
#define NHEADS    32
#define CONV_DIM  2176
#define D_IN_PROJ 4256
#define FFN_DIM   4096
#define BSZ       2
#define SEQ       2048
#define NROWS     (BSZ*SEQ)
#define TC        64
#define NCH       (SEQ/TC)

#define AS1 __attribute__((address_space(1)))
#define AS3 __attribute__((address_space(3)))
__device__ __forceinline__ void load_lds16(const void* g, void* l) {
  __builtin_amdgcn_global_load_lds((AS1 void*)g, (AS3 void*)l, 16, 0, 0);
}

// ---------------------------------------------------------------------------
// Input dtype detection (inputs proven fp32 => flag=1; kept for robustness).
// ---------------------------------------------------------------------------
__global__ __launch_bounds__(64)
void detect_kernel(const unsigned short* __restrict__ x, int* __restrict__ flagp)
{
  int bad = 0;
  for (int i = threadIdx.x; i < 4096; i += 64) {
    unsigned u = ((unsigned)x[i]) << 16;
    float v = __uint_as_float(u);
    if (!(fabsf(v) <= 1e6f)) bad = 1;
  }
  unsigned long long any = __ballot(bad);
  if (threadIdx.x == 0) *flagp = (any != 0ULL) ? 1 : 0;
}

// ---------------------------------------------------------------------------
// Normalize all inputs to bf16 workspace copies.
// ---------------------------------------------------------------------------
#define NT 19
struct CvtArgs {
  const void* src[NT];
  void*       dst[NT];
  int ccum[NT + 1];
  int nel[NT];
};

__global__ __launch_bounds__(256)
void cvt_kernel(CvtArgs a, const int* __restrict__ flagp)
{
  int c = blockIdx.x;
  int ti = 0;
  while (c >= a.ccum[ti + 1]) ti++;
  int base = (c - a.ccum[ti]) * 2048;
  int n = a.nel[ti];
  if (*flagp) {
    const float* s = (const float*)a.src[ti];
    bf16* d = (bf16*)a.dst[ti];
    for (int i = threadIdx.x; i < 2048; i += 256) {
      int j = base + i;
      if (j < n) d[j] = __float2bfloat16(s[j]);
    }
  } else {
    const unsigned short* s = (const unsigned short*)a.src[ti];
    unsigned short* d = (unsigned short*)a.dst[ti];
    for (int i = threadIdx.x; i < 2048; i += 256) {
      int j = base + i;
      if (j < n) d[j] = s[j];
    }
  }
}

// ---------------------------------------------------------------------------
// GEMM: C[M,N] = A[M,K] @ W[N,K]^T, bf16, fp32 accum, fused epilogues.
// m97 pattern: global_load_lds width=16 staging.
// EPI 0: store bf16   EPI 2: store bf16(gelu(acc+bias))
// ---------------------------------------------------------------------------
template<int EPI>
__global__ __launch_bounds__(256, 2)
void gemm_bt(const bf16* __restrict__ A, const bf16* __restrict__ W,
             int M, int N, int K,
             bf16* __restrict__ outB,
             const bf16* __restrict__ bias)
{
  __shared__ __align__(16) bhalf sA[128 * 32];
  __shared__ __align__(16) bhalf sW[128 * 32];
  const int t    = threadIdx.x;
  const int n0   = blockIdx.x * 128;
  const int m0   = blockIdx.y * 128;
  const int w    = t >> 6;
  const int lane = t & 63;
  const int wm   = (w >> 1) * 64;
  const int wn   = (w & 1) * 64;
  const int lr   = lane & 15;
  const int lq   = lane >> 4;
  const int srow = t >> 2;
  const int scol = (t & 3) * 8;

  f32x4 acc[4][4];
  #pragma unroll
  for (int i = 0; i < 4; i++)
    #pragma unroll
    for (int j = 0; j < 4; j++)
      acc[i][j] = (f32x4){0.f, 0.f, 0.f, 0.f};

  for (int k0 = 0; k0 < K; k0 += 32) {
    #pragma unroll
    for (int hh = 0; hh < 2; hh++) {
      int row = hh * 64 + srow;
      load_lds16(A + (size_t)(m0 + row) * K + k0 + scol, sA + hh * 2048 + t * 8);
      int wr = n0 + row; wr = wr < N ? wr : N - 1;
      load_lds16(W + (size_t)wr * K + k0 + scol, sW + hh * 2048 + t * 8);
    }
    __syncthreads();
    bhalf8 af[4], bfr[4];
    #pragma unroll
    for (int i = 0; i < 4; i++)
      af[i] = *(const bhalf8*)(sA + (wm + i * 16 + lr) * 32 + lq * 8);
    #pragma unroll
    for (int j = 0; j < 4; j++)
      bfr[j] = *(const bhalf8*)(sW + (wn + j * 16 + lr) * 32 + lq * 8);
    #pragma unroll
    for (int i = 0; i < 4; i++)
      #pragma unroll
      for (int j = 0; j < 4; j++)
        acc[i][j] = __builtin_amdgcn_mfma_f32_16x16x32_bf16(af[i], bfr[j], acc[i][j], 0, 0, 0);
    __syncthreads();
  }

  #pragma unroll
  for (int i = 0; i < 4; i++) {
    #pragma unroll
    for (int j = 0; j < 4; j++) {
      #pragma unroll
      for (int r = 0; r < 4; r++) {
        int m = m0 + wm + i * 16 + lq * 4 + r;
        int n = n0 + wn + j * 16 + lr;
        if (n < N) {
          float v = acc[i][j][r];
          size_t idx = (size_t)m * N + n;
          if (EPI == 0) {
            outB[idx] = __float2bfloat16(v);
          } else {
            v += __bfloat162float(bias[n]);
            outB[idx] = __float2bfloat16(0.5f * v * (1.0f + erff(v * 0.70710678118654752f)));
          }
        }
      }
    }
  }
}

// ---------------------------------------------------------------------------
// Split-K GEMM for skinny-N shapes (N=1024): blockIdx.z = split index,
// each split covers K-range [z*ks, (z+1)*ks), plain fp32 partial store.
// ---------------------------------------------------------------------------
struct SkParts { float* p0; float* p1; float* p2; float* p3; };

__global__ __launch_bounds__(256, 2)
void gemm_sk(const bf16* __restrict__ A, const bf16* __restrict__ W,
             int M, int N, int K, int ks, SkParts parts)
{
  __shared__ __align__(16) bhalf sA[128 * 32];
  __shared__ __align__(16) bhalf sW[128 * 32];
  const int t    = threadIdx.x;
  const int n0   = blockIdx.x * 128;
  const int m0   = blockIdx.y * 128;
  const int z    = blockIdx.z;
  const int w    = t >> 6;
  const int lane = t & 63;
  const int wm   = (w >> 1) * 64;
  const int wn   = (w & 1) * 64;
  const int lr   = lane & 15;
  const int lq   = lane >> 4;
  const int srow = t >> 2;
  const int scol = (t & 3) * 8;

  f32x4 acc[4][4];
  #pragma unroll
  for (int i = 0; i < 4; i++)
    #pragma unroll
    for (int j = 0; j < 4; j++)
      acc[i][j] = (f32x4){0.f, 0.f, 0.f, 0.f};

  const int kend = z * ks + ks;
  for (int k0 = z * ks; k0 < kend; k0 += 32) {
    #pragma unroll
    for (int hh = 0; hh < 2; hh++) {
      int row = hh * 64 + srow;
      load_lds16(A + (size_t)(m0 + row) * K + k0 + scol, sA + hh * 2048 + t * 8);
      load_lds16(W + (size_t)(n0 + row) * K + k0 + scol, sW + hh * 2048 + t * 8);
    }
    __syncthreads();
    bhalf8 af[4], bfr[4];
    #pragma unroll
    for (int i = 0; i < 4; i++)
      af[i] = *(const bhalf8*)(sA + (wm + i * 16 + lr) * 32 + lq * 8);
    #pragma unroll
    for (int j = 0; j < 4; j++)
      bfr[j] = *(const bhalf8*)(sW + (wn + j * 16 + lr) * 32 + lq * 8);
    #pragma unroll
    for (int i = 0; i < 4; i++)
      #pragma unroll
      for (int j = 0; j < 4; j++)
        acc[i][j] = __builtin_amdgcn_mfma_f32_16x16x32_bf16(af[i], bfr[j], acc[i][j], 0, 0, 0);
    __syncthreads();
  }

  float* out = (z == 0) ? parts.p0 : (z == 1) ? parts.p1 : (z == 2) ? parts.p2 : parts.p3;
  #pragma unroll
  for (int i = 0; i < 4; i++)
    #pragma unroll
    for (int j = 0; j < 4; j++)
      #pragma unroll
      for (int r = 0; r < 4; r++) {
        int m = m0 + wm + i * 16 + lq * 4 + r;
        int n = n0 + wn + j * 16 + lr;
        out[(size_t)m * N + n] = acc[i][j][r];
      }
}

// ---------------------------------------------------------------------------
// Split-K reduce, out_proj: x2f = p0 + p1 + resB(bf16)
// ---------------------------------------------------------------------------
__global__ __launch_bounds__(256)
void reduce_out_kernel(const float* __restrict__ p0, const float* __restrict__ p1,
                       const bf16* __restrict__ resB, float* __restrict__ out)
{
  int i = blockIdx.x * 256 + threadIdx.x;   // f32x4 group
  f32x4 a = ((const f32x4*)p0)[i];
  f32x4 b = ((const f32x4*)p1)[i];
  u16x4 r = ((const u16x4*)resB)[i];
  f32x4 o;
  #pragma unroll
  for (int j = 0; j < 4; j++)
    o[j] = a[j] + b[j] + __uint_as_float(((unsigned)r[j]) << 16);
  ((f32x4*)out)[i] = o;
}

// ---------------------------------------------------------------------------
// Split-K reduce, ffn2: d_out = p0+p1+p2+p3 + bias + resF (dtype per flag)
// ---------------------------------------------------------------------------
__global__ __launch_bounds__(256)
void reduce_ffn_kernel(const float* __restrict__ p0, const float* __restrict__ p1,
                       const float* __restrict__ p2, const float* __restrict__ p3,
                       const bf16* __restrict__ bias, const float* __restrict__ resF,
                       void* __restrict__ outp, const int* __restrict__ flagp)
{
  int i = blockIdx.x * 256 + threadIdx.x;   // f32x4 group
  int n4 = i & (D_MODEL / 4 - 1);
  f32x4 v0 = ((const f32x4*)p0)[i];
  f32x4 v1 = ((const f32x4*)p1)[i];
  f32x4 v2 = ((const f32x4*)p2)[i];
  f32x4 v3 = ((const f32x4*)p3)[i];
  f32x4 rf = ((const f32x4*)resF)[i];
  u16x4 bb = ((const u16x4*)bias)[n4];
  f32x4 o;
  #pragma unroll
  for (int j = 0; j < 4; j++)
    o[j] = ((v0[j] + v1[j]) + (v2[j] + v3[j])) + rf[j] +
           __uint_as_float(((unsigned)bb[j]) << 16);
  if (*flagp) {
    ((f32x4*)outp)[i] = o;
  } else {
    bf16* ob = (bf16*)outp;
    #pragma unroll
    for (int j = 0; j < 4; j++) ob[i * 4 + j] = __float2bfloat16(o[j]);
  }
}

// ---------------------------------------------------------------------------
// Fused ln0 + ln1.
// ---------------------------------------------------------------------------
__global__ __launch_bounds__(256)
void ln01_kernel(const bf16* __restrict__ x,
                 const bf16* __restrict__ w0, const bf16* __restrict__ b0,
                 const bf16* __restrict__ w1, const bf16* __restrict__ b1,
                 bf16* __restrict__ x0o, bf16* __restrict__ x1o)
{
  int row = blockIdx.x, t = threadIdx.x;
  const bf16* xr = x + (size_t)row * D_MODEL;
  __shared__ float rs[4], rq[4];
  float v[4], s = 0.f, ss = 0.f;
  #pragma unroll
  for (int i = 0; i < 4; i++) {
    v[i] = __bfloat162float(xr[t + 256 * i]);
    s += v[i]; ss += v[i] * v[i];
  }
  #pragma unroll
  for (int o = 32; o; o >>= 1) { s += __shfl_down(s, o); ss += __shfl_down(ss, o); }
  if ((t & 63) == 0) { rs[t >> 6] = s; rq[t >> 6] = ss; }
  __syncthreads();
  float S = rs[0] + rs[1] + rs[2] + rs[3];
  float Q = rq[0] + rq[1] + rq[2] + rq[3];
  float mean = S * (1.f / D_MODEL);
  float rstd = rsqrtf(Q * (1.f / D_MODEL) - mean * mean + 1e-5f);
  float u[4]; s = 0.f; ss = 0.f;
  #pragma unroll
  for (int i = 0; i < 4; i++) {
    int c = t + 256 * i;
    u[i] = (v[i] - mean) * rstd * __bfloat162float(w0[c]) + __bfloat162float(b0[c]);
    s += u[i]; ss += u[i] * u[i];
    x0o[(size_t)row * D_MODEL + c] = __float2bfloat16(u[i]);
  }
  __syncthreads();
  #pragma unroll
  for (int o = 32; o; o >>= 1) { s += __shfl_down(s, o); ss += __shfl_down(ss, o); }
  if ((t & 63) == 0) { rs[t >> 6] = s; rq[t >> 6] = ss; }
  __syncthreads();
  S = rs[0] + rs[1] + rs[2] + rs[3];
  Q = rq[0] + rq[1] + rq[2] + rq[3];
  mean = S * (1.f / D_MODEL);
  rstd = rsqrtf(Q * (1.f / D_MODEL) - mean * mean + 1e-5f);
  #pragma unroll
  for (int i = 0; i < 4; i++) {
    int c = t + 256 * i;
    x1o[(size_t)row * D_MODEL + c] =
        __float2bfloat16((u[i] - mean) * rstd * __bfloat162float(w1[c]) + __bfloat162float(b1[c]));
  }
}

// ---------------------------------------------------------------------------
// Causal depthwise conv (k=4) + SiLU.
// ---------------------------------------------------------------------------
__global__ __launch_bounds__(256)
void conv_silu_kernel(const bf16* __restrict__ zxb, const bf16* __restrict__ cw,
                      const bf16* __restrict__ cb, float* __restrict__ xact)
{
  int c = blockIdx.x * 256 + threadIdx.x;
  int row = blockIdx.y;
  if (c >= CONV_DIM) return;
  int l = row & (SEQ - 1);
  float acc = __bfloat162float(cb[c]);
  #pragma unroll
  for (int k = 0; k < 4; k++) {
    int lt = l - 3 + k;
    if (lt >= 0)
      acc += __bfloat162float(zxb[(size_t)(row - 3 + k) * D_IN_PROJ + D_INNER + c]) *
             __bfloat162float(cw[c * 4 + k]);
  }
  xact[(size_t)row * CONV_DIM + c] = acc / (1.f + expf(-acc));
}

// ---------------------------------------------------------------------------
// dt = softplus(raw + dt_bias); lda = dt * A
// ---------------------------------------------------------------------------
__global__ __launch_bounds__(256)
void dt_kernel(const bf16* __restrict__ zxb, const bf16* __restrict__ dt_bias,
               const bf16* __restrict__ A_log, float* __restrict__ dts,
               float* __restrict__ ldab)
{
  int i = blockIdx.x * 256 + threadIdx.x;
  int row = i >> 5, h = i & 31;
  float v = __bfloat162float(zxb[(size_t)row * D_IN_PROJ + (D_INNER + CONV_DIM) + h]) +
            __bfloat162float(dt_bias[h]);
  float sp = (v > 20.f) ? v : log1pf(expf(v));
  dts[i] = sp;
  ldab[i] = -sp * expf(__bfloat162float(A_log[h]));
}

// ---------------------------------------------------------------------------
// MFMA chunk scan, pass 1 (chunk states).
// ---------------------------------------------------------------------------
__global__ __launch_bounds__(256)
void scan_state_kernel(const float* __restrict__ xact, const float* __restrict__ dts,
                       const float* __restrict__ ldab, bf16* __restrict__ Sbuf,
                       float* __restrict__ acb)
{
  __shared__ __align__(16) bf16 wBT[64][72];
  __shared__ __align__(16) bf16 XT[64][72];
  __shared__ float lsS[64], dtS[64];
  const int bid = blockIdx.x;
  const int bh = bid & 63, c = bid >> 6;
  const int b = bh >> 5, h = bh & 31;
  const int t0 = c * TC;
  const int tid = threadIdx.x;
  const int w = tid >> 6, lane = tid & 63;
  const int lr = lane & 15, lq = lane >> 4;

  if (w == 0) {
    float v = ldab[(size_t)(b * SEQ + t0 + lane) * NHEADS + h];
    #pragma unroll
    for (int o = 1; o < 64; o <<= 1) {
      float up = __shfl_up(v, o);
      if (lane >= o) v += up;
    }
    lsS[lane] = v;
    dtS[lane] = dts[(size_t)(b * SEQ + t0 + lane) * NHEADS + h];
  }
  __syncthreads();
  const float lsT = lsS[63];
  {
    int nn = tid & 63, u0 = (tid >> 6) * 16;
    for (int i = 0; i < 16; i++) {
      int u = u0 + i;
      const float* rowp = xact + (size_t)(b * SEQ + t0 + u) * CONV_DIM;
      float wgt = dtS[u] * __expf(lsT - lsS[u]);
      wBT[nn][u] = __float2bfloat16(rowp[D_INNER + nn] * wgt);
      XT[nn][u]  = __float2bfloat16(rowp[h * 64 + nn]);
    }
  }
  __syncthreads();

  bhalf8 af0 = *(const bhalf8*)&wBT[16 * w + lr][lq * 8];
  bhalf8 af1 = *(const bhalf8*)&wBT[16 * w + lr][32 + lq * 8];
  bf16* sb = Sbuf + ((size_t)bh * NCH + c) * 4096;
  #pragma unroll
  for (int jt = 0; jt < 4; jt++) {
    bhalf8 xf0 = *(const bhalf8*)&XT[16 * jt + lr][lq * 8];
    bhalf8 xf1 = *(const bhalf8*)&XT[16 * jt + lr][32 + lq * 8];
    f32x4 acc = (f32x4){0.f, 0.f, 0.f, 0.f};
    acc = __builtin_amdgcn_mfma_f32_16x16x32_bf16(af0, xf0, acc, 0, 0, 0);
    acc = __builtin_amdgcn_mfma_f32_16x16x32_bf16(af1, xf1, acc, 0, 0, 0);
    #pragma unroll
    for (int r = 0; r < 4; r++) {
      int n = 16 * w + lq * 4 + r;
      int p = 16 * jt + lr;
      sb[p * 64 + n] = __float2bfloat16(acc[r]);
    }
  }
  if (tid == 0) acb[bh * NCH + c] = __expf(lsT);
}

// ---------------------------------------------------------------------------
// Pass 2: serial inter-chunk propagation (in-place).
// ---------------------------------------------------------------------------
__global__ __launch_bounds__(256)
void state_prop_kernel(bf16* __restrict__ Sbuf, const float* __restrict__ acb)
{
  const int bh = blockIdx.x >> 2, q = blockIdx.x & 3;
  const int t = threadIdx.x;
  bf16* sp = Sbuf + (size_t)bh * NCH * 4096 + q * 1024 + t;
  const float* ap = acb + bh * NCH;
  float h0 = 0.f, h1 = 0.f, h2 = 0.f, h3 = 0.f;
  for (int c = 0; c < NCH; c++) {
    bf16* pc = sp + (size_t)c * 4096;
    float s0 = __bfloat162float(pc[0]);
    float s1 = __bfloat162float(pc[256]);
    float s2 = __bfloat162float(pc[512]);
    float s3 = __bfloat162float(pc[768]);
    float a = ap[c];
    pc[0]   = __float2bfloat16(h0);
    pc[256] = __float2bfloat16(h1);
    pc[512] = __float2bfloat16(h2);
    pc[768] = __float2bfloat16(h3);
    h0 = fmaf(h0, a, s0); h1 = fmaf(h1, a, s1);
    h2 = fmaf(h2, a, s2); h3 = fmaf(h3, a, s3);
  }
}

// ---------------------------------------------------------------------------
// MFMA chunk scan, pass 3 (intra-chunk attention + inbound-state term).
// ---------------------------------------------------------------------------
__global__ __launch_bounds__(256)
void scan_y_kernel(const float* __restrict__ xact, const float* __restrict__ dts,
                   const float* __restrict__ ldab, const bf16* __restrict__ Sbuf,
                   bf16* __restrict__ yfull)
{
  __shared__ __align__(16) bf16 Cs[64][72];
  __shared__ __align__(16) bf16 Bs[64][72];
  __shared__ __align__(16) bf16 XT[64][72];
  __shared__ __align__(16) bf16 HT[64][72];
  __shared__ __align__(16) bf16 Ms[64][72];
  __shared__ float lsS[64], dtS[64];
  const int bid = blockIdx.x;
  const int bh = bid & 63, c = bid >> 6;
  const int b = bh >> 5, h = bh & 31;
  const int t0 = c * TC;
  const int tid = threadIdx.x;
  const int w = tid >> 6, lane = tid & 63;
  const int lr = lane & 15, lq = lane >> 4;

  if (w == 0) {
    float v = ldab[(size_t)(b * SEQ + t0 + lane) * NHEADS + h];
    #pragma unroll
    for (int o = 1; o < 64; o <<= 1) {
      float up = __shfl_up(v, o);
      if (lane >= o) v += up;
    }
    lsS[lane] = v;
    dtS[lane] = dts[(size_t)(b * SEQ + t0 + lane) * NHEADS + h];
  }
  {
    int nn = tid & 63, u0 = (tid >> 6) * 16;
    for (int i = 0; i < 16; i++) {
      int u = u0 + i;
      const float* rowp = xact + (size_t)(b * SEQ + t0 + u) * CONV_DIM;
      Bs[u][nn] = __float2bfloat16(rowp[D_INNER + nn]);
      Cs[u][nn] = __float2bfloat16(rowp[D_INNER + 64 + nn]);
      XT[nn][u] = __float2bfloat16(rowp[h * 64 + nn]);
    }
    const bf16* sb = Sbuf + ((size_t)bh * NCH + c) * 4096;
    for (int i = 0; i < 16; i++) {
      int e = tid + 256 * i;
      HT[e >> 6][e & 63] = sb[e];
    }
  }
  __syncthreads();

  bhalf8 cf0 = *(const bhalf8*)&Cs[16 * w + lr][lq * 8];
  bhalf8 cf1 = *(const bhalf8*)&Cs[16 * w + lr][32 + lq * 8];
  f32x4 accH[4];
  #pragma unroll
  for (int jt = 0; jt < 4; jt++) {
    bhalf8 bf0 = *(const bhalf8*)&Bs[16 * jt + lr][lq * 8];
    bhalf8 bf1 = *(const bhalf8*)&Bs[16 * jt + lr][32 + lq * 8];
    f32x4 g = (f32x4){0.f, 0.f, 0.f, 0.f};
    g = __builtin_amdgcn_mfma_f32_16x16x32_bf16(cf0, bf0, g, 0, 0, 0);
    g = __builtin_amdgcn_mfma_f32_16x16x32_bf16(cf1, bf1, g, 0, 0, 0);
    bhalf8 hf0 = *(const bhalf8*)&HT[16 * jt + lr][lq * 8];
    bhalf8 hf1 = *(const bhalf8*)&HT[16 * jt + lr][32 + lq * 8];
    f32x4 ah = (f32x4){0.f, 0.f, 0.f, 0.f};
    ah = __builtin_amdgcn_mfma_f32_16x16x32_bf16(cf0, hf0, ah, 0, 0, 0);
    ah = __builtin_amdgcn_mfma_f32_16x16x32_bf16(cf1, hf1, ah, 0, 0, 0);
    accH[jt] = ah;
    #pragma unroll
    for (int r = 0; r < 4; r++) {
      int t = 16 * w + lq * 4 + r;
      int u = 16 * jt + lr;
      float m = 0.f;
      if (u <= t) m = g[r] * __expf(lsS[t] - lsS[u]) * dtS[u];
      Ms[t][u] = __float2bfloat16(m);
    }
  }
  __syncthreads();

  bhalf8 mf0 = *(const bhalf8*)&Ms[16 * w + lr][lq * 8];
  bhalf8 mf1 = *(const bhalf8*)&Ms[16 * w + lr][32 + lq * 8];
  #pragma unroll
  for (int jt = 0; jt < 4; jt++) {
    bhalf8 xf0 = *(const bhalf8*)&XT[16 * jt + lr][lq * 8];
    bhalf8 xf1 = *(const bhalf8*)&XT[16 * jt + lr][32 + lq * 8];
    f32x4 acc = (f32x4){0.f, 0.f, 0.f, 0.f};
    acc = __builtin_amdgcn_mfma_f32_16x16x32_bf16(mf0, xf0, acc, 0, 0, 0);
    acc = __builtin_amdgcn_mfma_f32_16x16x32_bf16(mf1, xf1, acc, 0, 0, 0);
    #pragma unroll
    for (int r = 0; r < 4; r++) {
      int t = 16 * w + lq * 4 + r;
      int p = 16 * jt + lr;
      float y = acc[r] + __expf(lsS[t]) * accH[jt][r];
      yfull[(size_t)(b * SEQ + t0 + t) * D_INNER + h * 64 + p] = __float2bfloat16(y);
    }
  }
}

// ---------------------------------------------------------------------------
// y = yfull + D*x;  y *= silu(z);  RMSNorm * norm_w -> bf16
// ---------------------------------------------------------------------------
__global__ __launch_bounds__(256)
void gate_rms_kernel(const bf16* __restrict__ yfull, const float* __restrict__ xact,
                     const bf16* __restrict__ zxb, const bf16* __restrict__ Dp,
                     const bf16* __restrict__ nw, bf16* __restrict__ yn)
{
  int row = blockIdx.x, t = threadIdx.x;
  __shared__ float rq[4];
  float yv[8]; float ss = 0.f;
  #pragma unroll
  for (int i = 0; i < 8; i++) {
    int c = t + 256 * i;
    float y = __bfloat162float(yfull[(size_t)row * D_INNER + c]) +
              __bfloat162float(Dp[c >> 6]) * xact[(size_t)row * CONV_DIM + c];
    float z = __bfloat162float(zxb[(size_t)row * D_IN_PROJ + c]);
    yv[i] = y * (z / (1.f + expf(-z)));
    ss += yv[i] * yv[i];
  }
  #pragma unroll
  for (int o = 32; o; o >>= 1) ss += __shfl_down(ss, o);
  if ((t & 63) == 0) rq[t >> 6] = ss;
  __syncthreads();
  float tot = rq[0] + rq[1] + rq[2] + rq[3];
  float rr = rsqrtf(tot * (1.f / D_INNER) + 1e-5f);
  #pragma unroll
  for (int i = 0; i < 8; i++) {
    int c = t + 256 * i;
    yn[(size_t)row * D_INNER + c] =
        __float2bfloat16(yv[i] * rr * __bfloat162float(nw[c]));
  }
}

// ---------------------------------------------------------------------------
// ln2 on fp32 x2 -> bf16
// ---------------------------------------------------------------------------
__global__ __launch_bounds__(256)
void ln2_kernel(const float* __restrict__ xin, const bf16* __restrict__ w,
                const bf16* __restrict__ b, bf16* __restrict__ out)
{
  int row = blockIdx.x, t = threadIdx.x;
  const float* xr = xin + (size_t)row * D_MODEL;
  __shared__ float rs[4], rq[4];
  float v[4], s = 0.f, ss = 0.f;
  #pragma unroll
  for (int i = 0; i < 4; i++) {
    v[i] = xr[t + 256 * i];
    s += v[i]; ss += v[i] * v[i];
  }
  #pragma unroll
  for (int o = 32; o; o >>= 1) { s += __shfl_down(s, o); ss += __shfl_down(ss, o); }
  if ((t & 63) == 0) { rs[t >> 6] = s; rq[t >> 6] = ss; }
  __syncthreads();
  float S = rs[0] + rs[1] + rs[2] + rs[3];
  float Q = rq[0] + rq[1] + rq[2] + rq[3];
  float mean = S * (1.f / D_MODEL);
  float rstd = rsqrtf(Q * (1.f / D_MODEL) - mean * mean + 1e-5f);
  #pragma unroll
  for (int i = 0; i < 4; i++) {
    int c = t + 256 * i;
    out[(size_t)row * D_MODEL + c] =
        __float2bfloat16((v[i] - mean) * rstd * __bfloat162float(w[c]) + __bfloat162float(b[c]));
  }
}

// ---------------------------------------------------------------------------
extern "C" void kernel_launch(void* const* d_in, const int* in_sizes, int n_in,
                              void* d_out, int out_size, void* d_ws, size_t ws_size,
                              hipStream_t stream)
{
  char* ws = (char*)d_ws;
  // Workspace layout (kernels: 1 detect, 2 cvt, 3 ln01, 4 in_proj, 5 conv,
  // 6 dt, 7 scanP1, 8 prop, 9 scanP3, 10 gate_rms, 11 out_proj_sk,
  // 11b reduce_out, 12 ln2, 13 ffn1, 14 ffn2_sk, 14b reduce_ffn).
  bf16*  xcvt  = (bf16*) (ws + 0);           //  [2->3]
  bf16*  x1b   = (bf16*) (ws + 8388608);     //  [3->4]
  bf16*  Sbuf  = (bf16*) (ws + 0);           //  [7->9]   alias xcvt+x1b
  bf16*  ynb   = (bf16*) (ws + 0);           //  [10->11] alias Sbuf
  float* pf0   = (float*)(ws + 0);           //  [14->14b] alias ynb (16.7MB)
  bf16*  wproj = (bf16*) (ws + 16777216);    //  [2->4]
  float* acb   = (float*)(ws + 16777216);    //  [7->8]   alias wproj
  float* dtsb  = (float*)(ws + 16785408);    //  [6->9]   alias wproj
  float* ldab  = (float*)(ws + 17309696);    //  [6->9]   alias wproj
  float* pf1   = (float*)(ws + 16777216);    //  [14->14b] alias wproj region (16.7MB, ends 33.5M)
  bf16*  wout  = (bf16*) (ws + 25493504);    //  [2->11]  (inside pf1 span; dead by 14)
  bf16*  w1c   = (bf16*) (ws + 29687808);    //  [2->13]
  bf16*  w2c   = (bf16*) (ws + 38076416);    //  [2->14]  LIVE in 14 (above pf1 end 33.5M+? no: pf1 ends 33,554,432 < 38,076,416 OK)
  bf16*  ln0w  = (bf16*) (ws + 46465024);
  bf16*  ln0b  = (bf16*) (ws + 46467072);
  bf16*  ln1w  = (bf16*) (ws + 46469120);
  bf16*  ln1b  = (bf16*) (ws + 46471168);
  bf16*  ln2w  = (bf16*) (ws + 46473216);
  bf16*  ln2b  = (bf16*) (ws + 46475264);
  bf16*  convw = (bf16*) (ws + 46477312);
  bf16*  convb = (bf16*) (ws + 46494720);
  bf16*  dtb   = (bf16*) (ws + 46499072);
  bf16*  alog  = (bf16*) (ws + 46499136);
  bf16*  Dp    = (bf16*) (ws + 46499200);
  bf16*  normw = (bf16*) (ws + 46499264);
  bf16*  b1c   = (bf16*) (ws + 46503360);
  bf16*  b2c   = (bf16*) (ws + 46511552);
  int*   flag  = (int*)  (ws + 46513600);
  bf16*  x0b   = (bf16*) (ws + 46514176);    //  [3->11b]
  bf16*  zxb   = (bf16*) (ws + 54902784);    //  [4->10]
  float* x2f   = (float*)(ws + 54902784);    //  [11b->14b] alias zxb (16.7MB)
  float* pf3   = (float*)(ws + 71680000);    //  [14->14b] tail of zxb region (dead @10), ends 88.46M
  float* xact  = (float*)(ws + 89767936);    //  [5->10]
  float* pout0 = (float*)(ws + 89767936);    //  [11->11b] alias xact (dead @10)
  float* pout1 = (float*)(ws + 106545152);   //  [11->11b] ends 123.3M (< gbuf end, gbuf born @13)
  bf16*  gbuf  = (bf16*) (ws + 89767936);    //  [13->14] alias xact region
  bf16*  yfull = (bf16*) (ws + 125419520);   //  [9->10]
  bf16*  hln   = (bf16*) (ws + 125419520);   //  [12->13] alias yfull
  float* pf2   = (float*)(ws + 125419520);   //  [14->14b] alias hln (dead @13), ends 142.2M

  detect_kernel<<<1, 64, 0, stream>>>((const unsigned short*)d_in[0], flag);

  CvtArgs ca;
  void* dsts[NT] = { xcvt, ln0w, ln0b, ln1w, ln1b, ln2w, ln2b, wproj, convw, convb,
                     dtb, alog, Dp, normw, wout, w1c, b1c, w2c, b2c };
  int cc = 0;
  ca.ccum[0] = 0;
  for (int i = 0; i < NT; i++) {
    ca.src[i] = d_in[i];
    ca.dst[i] = dsts[i];
    ca.nel[i] = in_sizes[i];
    cc += (in_sizes[i] + 2047) / 2048;
    ca.ccum[i + 1] = cc;
  }
  cvt_kernel<<<cc, 256, 0, stream>>>(ca, flag);

  ln01_kernel<<<NROWS, 256, 0, stream>>>(xcvt, ln0w, ln0b, ln1w, ln1b, x0b, x1b);

  gemm_bt<0><<<dim3(34, 32), 256, 0, stream>>>(x1b, wproj, NROWS, D_IN_PROJ, D_MODEL,
                                               zxb, nullptr);

  conv_silu_kernel<<<dim3(9, NROWS), 256, 0, stream>>>(zxb, convw, convb, xact);
  dt_kernel<<<(NROWS * NHEADS) / 256, 256, 0, stream>>>(zxb, dtb, alog, dtsb, ldab);

  scan_state_kernel<<<NCH * 64, 256, 0, stream>>>(xact, dtsb, ldab, Sbuf, acb);
  state_prop_kernel<<<64 * 4, 256, 0, stream>>>(Sbuf, acb);
  scan_y_kernel<<<NCH * 64, 256, 0, stream>>>(xact, dtsb, ldab, Sbuf, yfull);

  gate_rms_kernel<<<NROWS, 256, 0, stream>>>(yfull, xact, zxb, Dp, normw, ynb);

  // out_proj: split-K=2 (K=2048 -> 2x1024), partials then fused reduce(+res)
  SkParts po = { pout0, pout1, pout0, pout0 };
  gemm_sk<<<dim3(8, 32, 2), 256, 0, stream>>>(ynb, wout, NROWS, D_MODEL, D_INNER, 1024, po);
  reduce_out_kernel<<<(NROWS * D_MODEL) / 1024, 256, 0, stream>>>(pout0, pout1, x0b, x2f);

  ln2_kernel<<<NROWS, 256, 0, stream>>>(x2f, ln2w, ln2b, hln);

  gemm_bt<2><<<dim3(32, 32), 256, 0, stream>>>(hln, w1c, NROWS, FFN_DIM, D_MODEL,
                                               gbuf, b1c);

  // ffn2: split-K=4 (K=4096 -> 4x1024), partials then fused reduce(+bias+res)
  SkParts pfp = { pf0, pf1, pf2, pf3 };
  gemm_sk<<<dim3(8, 32, 4), 256, 0, stream>>>(gbuf, w2c, NROWS, D_MODEL, FFN_DIM, 1024, pfp);
  reduce_ffn_kernel<<<(NROWS * D_MODEL) / 1024, 256, 0, stream>>>(pf0, pf1, pf2, pf3,
                                                                  b2c, x2f, d_out, flag);
}

// Round 7
// 480.961 us; speedup vs baseline: 3.9848x; 1.0622x over previous
//
#include <hip/hip_runtime.h>
#include <hip/hip_bf16.h>
#include <math.h>

typedef __hip_bfloat16 bf16;
typedef __bf16 bhalf;
typedef bhalf bhalf8 __attribute__((ext_vector_type(8)));
typedef float f32x4 __attribute__((ext_vector_type(4)));
typedef unsigned short u16;
typedef u16 u16x4 __attribute__((ext_vector_type(4)));

#define D_MODEL   1024
#define D_STATE   64
#define HEADDIM   64
#define D_INNER   2048
#define NHEADS    32
#define CONV_DIM  2176
#define D_IN_PROJ 4256
#define FFN_DIM   4096
#define BSZ       2
#define SEQ       2048
#define NROWS     (BSZ*SEQ)
#define TC        64
#define NCH       (SEQ/TC)

#define AS1 __attribute__((address_space(1)))
#define AS3 __attribute__((address_space(3)))
__device__ __forceinline__ void load_lds16(const void* g, void* l) {
  __builtin_amdgcn_global_load_lds((AS1 void*)g, (AS3 void*)l, 16, 0, 0);
}

// ---------------------------------------------------------------------------
// Input dtype detection (inputs proven fp32 => flag=1; kept for robustness).
// ---------------------------------------------------------------------------
__global__ __launch_bounds__(64)
void detect_kernel(const unsigned short* __restrict__ x, int* __restrict__ flagp)
{
  int bad = 0;
  for (int i = threadIdx.x; i < 4096; i += 64) {
    unsigned u = ((unsigned)x[i]) << 16;
    float v = __uint_as_float(u);
    if (!(fabsf(v) <= 1e6f)) bad = 1;
  }
  unsigned long long any = __ballot(bad);
  if (threadIdx.x == 0) *flagp = (any != 0ULL) ? 1 : 0;
}

// ---------------------------------------------------------------------------
// Normalize all inputs to bf16 workspace copies.
// ---------------------------------------------------------------------------
#define NT 19
struct CvtArgs {
  const void* src[NT];
  void*       dst[NT];
  int ccum[NT + 1];
  int nel[NT];
};

__global__ __launch_bounds__(256)
void cvt_kernel(CvtArgs a, const int* __restrict__ flagp)
{
  int c = blockIdx.x;
  int ti = 0;
  while (c >= a.ccum[ti + 1]) ti++;
  int base = (c - a.ccum[ti]) * 2048;
  int n = a.nel[ti];
  if (*flagp) {
    const float* s = (const float*)a.src[ti];
    bf16* d = (bf16*)a.dst[ti];
    for (int i = threadIdx.x; i < 2048; i += 256) {
      int j = base + i;
      if (j < n) d[j] = __float2bfloat16(s[j]);
    }
  } else {
    const unsigned short* s = (const unsigned short*)a.src[ti];
    unsigned short* d = (unsigned short*)a.dst[ti];
    for (int i = threadIdx.x; i < 2048; i += 256) {
      int j = base + i;
      if (j < n) d[j] = s[j];
    }
  }
}

// ---------------------------------------------------------------------------
// GEMM: C[M,N] = A[M,K] @ W[N,K]^T, bf16, fp32 accum, fused epilogues.
// BK=64, XOR-swizzled LDS (row stride 128B = 32 banks; storing chunk (r,c)
// from global col c^(r&7) spreads fragment reads to 2-way max conflicts
// while keeping global_load_lds lane-contiguity).
// EPI 0: store bf16   EPI 2: store bf16(gelu(acc+bias))
// ---------------------------------------------------------------------------
template<int EPI>
__global__ __launch_bounds__(256, 2)
void gemm_bt(const bf16* __restrict__ A, const bf16* __restrict__ W,
             int M, int N, int K,
             bf16* __restrict__ outB,
             const bf16* __restrict__ bias)
{
  __shared__ __align__(16) bhalf sA[128 * 64];
  __shared__ __align__(16) bhalf sW[128 * 64];
  const int t    = threadIdx.x;
  const int n0   = blockIdx.x * 128;
  const int m0   = blockIdx.y * 128;
  const int w    = t >> 6;
  const int lane = t & 63;
  const int wm   = (w >> 1) * 64;
  const int wn   = (w & 1) * 64;
  const int lr   = lane & 15;
  const int lq   = lane >> 4;

  f32x4 acc[4][4];
  #pragma unroll
  for (int i = 0; i < 4; i++)
    #pragma unroll
    for (int j = 0; j < 4; j++)
      acc[i][j] = (f32x4){0.f, 0.f, 0.f, 0.f};

  for (int k0 = 0; k0 < K; k0 += 64) {
    #pragma unroll
    for (int j = 0; j < 4; j++) {
      int s  = t + 256 * j;            // LDS 16B-chunk slot, wave-contiguous
      int r  = s >> 3;                 // tile row 0..127
      int cs = (s & 7) ^ (r & 7);      // swizzled source col16
      load_lds16(A + (size_t)(m0 + r) * K + k0 + cs * 8, sA + s * 8);
      int wr = n0 + r; wr = wr < N ? wr : N - 1;
      load_lds16(W + (size_t)wr * K + k0 + cs * 8, sW + s * 8);
    }
    __syncthreads();
    #pragma unroll
    for (int kk = 0; kk < 2; kk++) {
      bhalf8 af[4], bfr[4];
      #pragma unroll
      for (int i = 0; i < 4; i++) {
        int r = wm + i * 16 + lr;
        int c = (kk * 4 + lq) ^ (r & 7);
        af[i] = *(const bhalf8*)(sA + r * 64 + c * 8);
      }
      #pragma unroll
      for (int j = 0; j < 4; j++) {
        int r = wn + j * 16 + lr;
        int c = (kk * 4 + lq) ^ (r & 7);
        bfr[j] = *(const bhalf8*)(sW + r * 64 + c * 8);
      }
      #pragma unroll
      for (int i = 0; i < 4; i++)
        #pragma unroll
        for (int j = 0; j < 4; j++)
          acc[i][j] = __builtin_amdgcn_mfma_f32_16x16x32_bf16(af[i], bfr[j], acc[i][j], 0, 0, 0);
    }
    __syncthreads();
  }

  #pragma unroll
  for (int i = 0; i < 4; i++) {
    #pragma unroll
    for (int j = 0; j < 4; j++) {
      #pragma unroll
      for (int r = 0; r < 4; r++) {
        int m = m0 + wm + i * 16 + lq * 4 + r;
        int n = n0 + wn + j * 16 + lr;
        if (n < N) {
          float v = acc[i][j][r];
          size_t idx = (size_t)m * N + n;
          if (EPI == 0) {
            outB[idx] = __float2bfloat16(v);
          } else {
            v += __bfloat162float(bias[n]);
            outB[idx] = __float2bfloat16(0.5f * v * (1.0f + erff(v * 0.70710678118654752f)));
          }
        }
      }
    }
  }
}

// ---------------------------------------------------------------------------
// Split-K GEMM (N=1024 skinny shapes); same BK=64 swizzled core.
// ---------------------------------------------------------------------------
struct SkParts { float* p0; float* p1; float* p2; float* p3; };

__global__ __launch_bounds__(256, 2)
void gemm_sk(const bf16* __restrict__ A, const bf16* __restrict__ W,
             int M, int N, int K, int ks, SkParts parts)
{
  __shared__ __align__(16) bhalf sA[128 * 64];
  __shared__ __align__(16) bhalf sW[128 * 64];
  const int t    = threadIdx.x;
  const int n0   = blockIdx.x * 128;
  const int m0   = blockIdx.y * 128;
  const int z    = blockIdx.z;
  const int w    = t >> 6;
  const int lane = t & 63;
  const int wm   = (w >> 1) * 64;
  const int wn   = (w & 1) * 64;
  const int lr   = lane & 15;
  const int lq   = lane >> 4;

  f32x4 acc[4][4];
  #pragma unroll
  for (int i = 0; i < 4; i++)
    #pragma unroll
    for (int j = 0; j < 4; j++)
      acc[i][j] = (f32x4){0.f, 0.f, 0.f, 0.f};

  const int kend = z * ks + ks;
  for (int k0 = z * ks; k0 < kend; k0 += 64) {
    #pragma unroll
    for (int j = 0; j < 4; j++) {
      int s  = t + 256 * j;
      int r  = s >> 3;
      int cs = (s & 7) ^ (r & 7);
      load_lds16(A + (size_t)(m0 + r) * K + k0 + cs * 8, sA + s * 8);
      load_lds16(W + (size_t)(n0 + r) * K + k0 + cs * 8, sW + s * 8);
    }
    __syncthreads();
    #pragma unroll
    for (int kk = 0; kk < 2; kk++) {
      bhalf8 af[4], bfr[4];
      #pragma unroll
      for (int i = 0; i < 4; i++) {
        int r = wm + i * 16 + lr;
        int c = (kk * 4 + lq) ^ (r & 7);
        af[i] = *(const bhalf8*)(sA + r * 64 + c * 8);
      }
      #pragma unroll
      for (int j = 0; j < 4; j++) {
        int r = wn + j * 16 + lr;
        int c = (kk * 4 + lq) ^ (r & 7);
        bfr[j] = *(const bhalf8*)(sW + r * 64 + c * 8);
      }
      #pragma unroll
      for (int i = 0; i < 4; i++)
        #pragma unroll
        for (int j = 0; j < 4; j++)
          acc[i][j] = __builtin_amdgcn_mfma_f32_16x16x32_bf16(af[i], bfr[j], acc[i][j], 0, 0, 0);
    }
    __syncthreads();
  }

  float* out = (z == 0) ? parts.p0 : (z == 1) ? parts.p1 : (z == 2) ? parts.p2 : parts.p3;
  #pragma unroll
  for (int i = 0; i < 4; i++)
    #pragma unroll
    for (int j = 0; j < 4; j++)
      #pragma unroll
      for (int r = 0; r < 4; r++) {
        int m = m0 + wm + i * 16 + lq * 4 + r;
        int n = n0 + wn + j * 16 + lr;
        out[(size_t)m * N + n] = acc[i][j][r];
      }
}

// ---------------------------------------------------------------------------
// Split-K reduce, out_proj: x2f = p0 + p1 + resB(bf16)
// ---------------------------------------------------------------------------
__global__ __launch_bounds__(256)
void reduce_out_kernel(const float* __restrict__ p0, const float* __restrict__ p1,
                       const bf16* __restrict__ resB, float* __restrict__ out)
{
  int i = blockIdx.x * 256 + threadIdx.x;
  f32x4 a = ((const f32x4*)p0)[i];
  f32x4 b = ((const f32x4*)p1)[i];
  u16x4 r = ((const u16x4*)resB)[i];
  f32x4 o;
  #pragma unroll
  for (int j = 0; j < 4; j++)
    o[j] = a[j] + b[j] + __uint_as_float(((unsigned)r[j]) << 16);
  ((f32x4*)out)[i] = o;
}

// ---------------------------------------------------------------------------
// Split-K reduce, ffn2: d_out = p0+p1+p2+p3 + bias + resF (dtype per flag)
// ---------------------------------------------------------------------------
__global__ __launch_bounds__(256)
void reduce_ffn_kernel(const float* __restrict__ p0, const float* __restrict__ p1,
                       const float* __restrict__ p2, const float* __restrict__ p3,
                       const bf16* __restrict__ bias, const float* __restrict__ resF,
                       void* __restrict__ outp, const int* __restrict__ flagp)
{
  int i = blockIdx.x * 256 + threadIdx.x;
  int n4 = i & (D_MODEL / 4 - 1);
  f32x4 v0 = ((const f32x4*)p0)[i];
  f32x4 v1 = ((const f32x4*)p1)[i];
  f32x4 v2 = ((const f32x4*)p2)[i];
  f32x4 v3 = ((const f32x4*)p3)[i];
  f32x4 rf = ((const f32x4*)resF)[i];
  u16x4 bb = ((const u16x4*)bias)[n4];
  f32x4 o;
  #pragma unroll
  for (int j = 0; j < 4; j++)
    o[j] = ((v0[j] + v1[j]) + (v2[j] + v3[j])) + rf[j] +
           __uint_as_float(((unsigned)bb[j]) << 16);
  if (*flagp) {
    ((f32x4*)outp)[i] = o;
  } else {
    bf16* ob = (bf16*)outp;
    #pragma unroll
    for (int j = 0; j < 4; j++) ob[i * 4 + j] = __float2bfloat16(o[j]);
  }
}

// ---------------------------------------------------------------------------
// Fused ln0 + ln1.
// ---------------------------------------------------------------------------
__global__ __launch_bounds__(256)
void ln01_kernel(const bf16* __restrict__ x,
                 const bf16* __restrict__ w0, const bf16* __restrict__ b0,
                 const bf16* __restrict__ w1, const bf16* __restrict__ b1,
                 bf16* __restrict__ x0o, bf16* __restrict__ x1o)
{
  int row = blockIdx.x, t = threadIdx.x;
  const bf16* xr = x + (size_t)row * D_MODEL;
  __shared__ float rs[4], rq[4];
  float v[4], s = 0.f, ss = 0.f;
  #pragma unroll
  for (int i = 0; i < 4; i++) {
    v[i] = __bfloat162float(xr[t + 256 * i]);
    s += v[i]; ss += v[i] * v[i];
  }
  #pragma unroll
  for (int o = 32; o; o >>= 1) { s += __shfl_down(s, o); ss += __shfl_down(ss, o); }
  if ((t & 63) == 0) { rs[t >> 6] = s; rq[t >> 6] = ss; }
  __syncthreads();
  float S = rs[0] + rs[1] + rs[2] + rs[3];
  float Q = rq[0] + rq[1] + rq[2] + rq[3];
  float mean = S * (1.f / D_MODEL);
  float rstd = rsqrtf(Q * (1.f / D_MODEL) - mean * mean + 1e-5f);
  float u[4]; s = 0.f; ss = 0.f;
  #pragma unroll
  for (int i = 0; i < 4; i++) {
    int c = t + 256 * i;
    u[i] = (v[i] - mean) * rstd * __bfloat162float(w0[c]) + __bfloat162float(b0[c]);
    s += u[i]; ss += u[i] * u[i];
    x0o[(size_t)row * D_MODEL + c] = __float2bfloat16(u[i]);
  }
  __syncthreads();
  #pragma unroll
  for (int o = 32; o; o >>= 1) { s += __shfl_down(s, o); ss += __shfl_down(ss, o); }
  if ((t & 63) == 0) { rs[t >> 6] = s; rq[t >> 6] = ss; }
  __syncthreads();
  S = rs[0] + rs[1] + rs[2] + rs[3];
  Q = rq[0] + rq[1] + rq[2] + rq[3];
  mean = S * (1.f / D_MODEL);
  rstd = rsqrtf(Q * (1.f / D_MODEL) - mean * mean + 1e-5f);
  #pragma unroll
  for (int i = 0; i < 4; i++) {
    int c = t + 256 * i;
    x1o[(size_t)row * D_MODEL + c] =
        __float2bfloat16((u[i] - mean) * rstd * __bfloat162float(w1[c]) + __bfloat162float(b1[c]));
  }
}

// ---------------------------------------------------------------------------
// Causal depthwise conv (k=4) + SiLU -> bf16 xact.
// ---------------------------------------------------------------------------
__global__ __launch_bounds__(256)
void conv_silu_kernel(const bf16* __restrict__ zxb, const bf16* __restrict__ cw,
                      const bf16* __restrict__ cb, bf16* __restrict__ xact)
{
  int c = blockIdx.x * 256 + threadIdx.x;
  int row = blockIdx.y;
  if (c >= CONV_DIM) return;
  int l = row & (SEQ - 1);
  float acc = __bfloat162float(cb[c]);
  #pragma unroll
  for (int k = 0; k < 4; k++) {
    int lt = l - 3 + k;
    if (lt >= 0)
      acc += __bfloat162float(zxb[(size_t)(row - 3 + k) * D_IN_PROJ + D_INNER + c]) *
             __bfloat162float(cw[c * 4 + k]);
  }
  xact[(size_t)row * CONV_DIM + c] = __float2bfloat16(acc / (1.f + expf(-acc)));
}

// ---------------------------------------------------------------------------
// dt = softplus(raw + dt_bias); lda = dt * A
// ---------------------------------------------------------------------------
__global__ __launch_bounds__(256)
void dt_kernel(const bf16* __restrict__ zxb, const bf16* __restrict__ dt_bias,
               const bf16* __restrict__ A_log, float* __restrict__ dts,
               float* __restrict__ ldab)
{
  int i = blockIdx.x * 256 + threadIdx.x;
  int row = i >> 5, h = i & 31;
  float v = __bfloat162float(zxb[(size_t)row * D_IN_PROJ + (D_INNER + CONV_DIM) + h]) +
            __bfloat162float(dt_bias[h]);
  float sp = (v > 20.f) ? v : log1pf(expf(v));
  dts[i] = sp;
  ldab[i] = -sp * expf(__bfloat162float(A_log[h]));
}

// ---------------------------------------------------------------------------
// MFMA chunk scan, pass 1 (chunk states). xact is bf16.
// ---------------------------------------------------------------------------
__global__ __launch_bounds__(256)
void scan_state_kernel(const bf16* __restrict__ xact, const float* __restrict__ dts,
                       const float* __restrict__ ldab, bf16* __restrict__ Sbuf,
                       float* __restrict__ acb)
{
  __shared__ __align__(16) bf16 wBT[64][72];
  __shared__ __align__(16) bf16 XT[64][72];
  __shared__ float lsS[64], dtS[64];
  const int bid = blockIdx.x;
  const int bh = bid & 63, c = bid >> 6;
  const int b = bh >> 5, h = bh & 31;
  const int t0 = c * TC;
  const int tid = threadIdx.x;
  const int w = tid >> 6, lane = tid & 63;
  const int lr = lane & 15, lq = lane >> 4;

  if (w == 0) {
    float v = ldab[(size_t)(b * SEQ + t0 + lane) * NHEADS + h];
    #pragma unroll
    for (int o = 1; o < 64; o <<= 1) {
      float up = __shfl_up(v, o);
      if (lane >= o) v += up;
    }
    lsS[lane] = v;
    dtS[lane] = dts[(size_t)(b * SEQ + t0 + lane) * NHEADS + h];
  }
  __syncthreads();
  const float lsT = lsS[63];
  {
    int nn = tid & 63, u0 = (tid >> 6) * 16;
    for (int i = 0; i < 16; i++) {
      int u = u0 + i;
      const bf16* rowp = xact + (size_t)(b * SEQ + t0 + u) * CONV_DIM;
      float wgt = dtS[u] * __expf(lsT - lsS[u]);
      wBT[nn][u] = __float2bfloat16(__bfloat162float(rowp[D_INNER + nn]) * wgt);
      XT[nn][u]  = rowp[h * 64 + nn];
    }
  }
  __syncthreads();

  bhalf8 af0 = *(const bhalf8*)&wBT[16 * w + lr][lq * 8];
  bhalf8 af1 = *(const bhalf8*)&wBT[16 * w + lr][32 + lq * 8];
  bf16* sb = Sbuf + ((size_t)bh * NCH + c) * 4096;
  #pragma unroll
  for (int jt = 0; jt < 4; jt++) {
    bhalf8 xf0 = *(const bhalf8*)&XT[16 * jt + lr][lq * 8];
    bhalf8 xf1 = *(const bhalf8*)&XT[16 * jt + lr][32 + lq * 8];
    f32x4 acc = (f32x4){0.f, 0.f, 0.f, 0.f};
    acc = __builtin_amdgcn_mfma_f32_16x16x32_bf16(af0, xf0, acc, 0, 0, 0);
    acc = __builtin_amdgcn_mfma_f32_16x16x32_bf16(af1, xf1, acc, 0, 0, 0);
    #pragma unroll
    for (int r = 0; r < 4; r++) {
      int n = 16 * w + lq * 4 + r;
      int p = 16 * jt + lr;
      sb[p * 64 + n] = __float2bfloat16(acc[r]);
    }
  }
  if (tid == 0) acb[bh * NCH + c] = __expf(lsT);
}

// ---------------------------------------------------------------------------
// Pass 2: serial inter-chunk propagation (in-place).
// ---------------------------------------------------------------------------
__global__ __launch_bounds__(256)
void state_prop_kernel(bf16* __restrict__ Sbuf, const float* __restrict__ acb)
{
  const int bh = blockIdx.x >> 2, q = blockIdx.x & 3;
  const int t = threadIdx.x;
  bf16* sp = Sbuf + (size_t)bh * NCH * 4096 + q * 1024 + t;
  const float* ap = acb + bh * NCH;
  float h0 = 0.f, h1 = 0.f, h2 = 0.f, h3 = 0.f;
  for (int c = 0; c < NCH; c++) {
    bf16* pc = sp + (size_t)c * 4096;
    float s0 = __bfloat162float(pc[0]);
    float s1 = __bfloat162float(pc[256]);
    float s2 = __bfloat162float(pc[512]);
    float s3 = __bfloat162float(pc[768]);
    float a = ap[c];
    pc[0]   = __float2bfloat16(h0);
    pc[256] = __float2bfloat16(h1);
    pc[512] = __float2bfloat16(h2);
    pc[768] = __float2bfloat16(h3);
    h0 = fmaf(h0, a, s0); h1 = fmaf(h1, a, s1);
    h2 = fmaf(h2, a, s2); h3 = fmaf(h3, a, s3);
  }
}

// ---------------------------------------------------------------------------
// MFMA chunk scan, pass 3. xact is bf16.
// ---------------------------------------------------------------------------
__global__ __launch_bounds__(256)
void scan_y_kernel(const bf16* __restrict__ xact, const float* __restrict__ dts,
                   const float* __restrict__ ldab, const bf16* __restrict__ Sbuf,
                   bf16* __restrict__ yfull)
{
  __shared__ __align__(16) bf16 Cs[64][72];
  __shared__ __align__(16) bf16 Bs[64][72];
  __shared__ __align__(16) bf16 XT[64][72];
  __shared__ __align__(16) bf16 HT[64][72];
  __shared__ __align__(16) bf16 Ms[64][72];
  __shared__ float lsS[64], dtS[64];
  const int bid = blockIdx.x;
  const int bh = bid & 63, c = bid >> 6;
  const int b = bh >> 5, h = bh & 31;
  const int t0 = c * TC;
  const int tid = threadIdx.x;
  const int w = tid >> 6, lane = tid & 63;
  const int lr = lane & 15, lq = lane >> 4;

  if (w == 0) {
    float v = ldab[(size_t)(b * SEQ + t0 + lane) * NHEADS + h];
    #pragma unroll
    for (int o = 1; o < 64; o <<= 1) {
      float up = __shfl_up(v, o);
      if (lane >= o) v += up;
    }
    lsS[lane] = v;
    dtS[lane] = dts[(size_t)(b * SEQ + t0 + lane) * NHEADS + h];
  }
  {
    int nn = tid & 63, u0 = (tid >> 6) * 16;
    for (int i = 0; i < 16; i++) {
      int u = u0 + i;
      const bf16* rowp = xact + (size_t)(b * SEQ + t0 + u) * CONV_DIM;
      Bs[u][nn] = rowp[D_INNER + nn];
      Cs[u][nn] = rowp[D_INNER + 64 + nn];
      XT[nn][u] = rowp[h * 64 + nn];
    }
    const bf16* sb = Sbuf + ((size_t)bh * NCH + c) * 4096;
    for (int i = 0; i < 16; i++) {
      int e = tid + 256 * i;
      HT[e >> 6][e & 63] = sb[e];
    }
  }
  __syncthreads();

  bhalf8 cf0 = *(const bhalf8*)&Cs[16 * w + lr][lq * 8];
  bhalf8 cf1 = *(const bhalf8*)&Cs[16 * w + lr][32 + lq * 8];
  f32x4 accH[4];
  #pragma unroll
  for (int jt = 0; jt < 4; jt++) {
    bhalf8 bf0 = *(const bhalf8*)&Bs[16 * jt + lr][lq * 8];
    bhalf8 bf1 = *(const bhalf8*)&Bs[16 * jt + lr][32 + lq * 8];
    f32x4 g = (f32x4){0.f, 0.f, 0.f, 0.f};
    g = __builtin_amdgcn_mfma_f32_16x16x32_bf16(cf0, bf0, g, 0, 0, 0);
    g = __builtin_amdgcn_mfma_f32_16x16x32_bf16(cf1, bf1, g, 0, 0, 0);
    bhalf8 hf0 = *(const bhalf8*)&HT[16 * jt + lr][lq * 8];
    bhalf8 hf1 = *(const bhalf8*)&HT[16 * jt + lr][32 + lq * 8];
    f32x4 ah = (f32x4){0.f, 0.f, 0.f, 0.f};
    ah = __builtin_amdgcn_mfma_f32_16x16x32_bf16(cf0, hf0, ah, 0, 0, 0);
    ah = __builtin_amdgcn_mfma_f32_16x16x32_bf16(cf1, hf1, ah, 0, 0, 0);
    accH[jt] = ah;
    #pragma unroll
    for (int r = 0; r < 4; r++) {
      int t = 16 * w + lq * 4 + r;
      int u = 16 * jt + lr;
      float m = 0.f;
      if (u <= t) m = g[r] * __expf(lsS[t] - lsS[u]) * dtS[u];
      Ms[t][u] = __float2bfloat16(m);
    }
  }
  __syncthreads();

  bhalf8 mf0 = *(const bhalf8*)&Ms[16 * w + lr][lq * 8];
  bhalf8 mf1 = *(const bhalf8*)&Ms[16 * w + lr][32 + lq * 8];
  #pragma unroll
  for (int jt = 0; jt < 4; jt++) {
    bhalf8 xf0 = *(const bhalf8*)&XT[16 * jt + lr][lq * 8];
    bhalf8 xf1 = *(const bhalf8*)&XT[16 * jt + lr][32 + lq * 8];
    f32x4 acc = (f32x4){0.f, 0.f, 0.f, 0.f};
    acc = __builtin_amdgcn_mfma_f32_16x16x32_bf16(mf0, xf0, acc, 0, 0, 0);
    acc = __builtin_amdgcn_mfma_f32_16x16x32_bf16(mf1, xf1, acc, 0, 0, 0);
    #pragma unroll
    for (int r = 0; r < 4; r++) {
      int t = 16 * w + lq * 4 + r;
      int p = 16 * jt + lr;
      float y = acc[r] + __expf(lsS[t]) * accH[jt][r];
      yfull[(size_t)(b * SEQ + t0 + t) * D_INNER + h * 64 + p] = __float2bfloat16(y);
    }
  }
}

// ---------------------------------------------------------------------------
// y = yfull + D*x;  y *= silu(z);  RMSNorm * norm_w -> bf16. xact is bf16.
// ---------------------------------------------------------------------------
__global__ __launch_bounds__(256)
void gate_rms_kernel(const bf16* __restrict__ yfull, const bf16* __restrict__ xact,
                     const bf16* __restrict__ zxb, const bf16* __restrict__ Dp,
                     const bf16* __restrict__ nw, bf16* __restrict__ yn)
{
  int row = blockIdx.x, t = threadIdx.x;
  __shared__ float rq[4];
  float yv[8]; float ss = 0.f;
  #pragma unroll
  for (int i = 0; i < 8; i++) {
    int c = t + 256 * i;
    float y = __bfloat162float(yfull[(size_t)row * D_INNER + c]) +
              __bfloat162float(Dp[c >> 6]) *
              __bfloat162float(xact[(size_t)row * CONV_DIM + c]);
    float z = __bfloat162float(zxb[(size_t)row * D_IN_PROJ + c]);
    yv[i] = y * (z / (1.f + expf(-z)));
    ss += yv[i] * yv[i];
  }
  #pragma unroll
  for (int o = 32; o; o >>= 1) ss += __shfl_down(ss, o);
  if ((t & 63) == 0) rq[t >> 6] = ss;
  __syncthreads();
  float tot = rq[0] + rq[1] + rq[2] + rq[3];
  float rr = rsqrtf(tot * (1.f / D_INNER) + 1e-5f);
  #pragma unroll
  for (int i = 0; i < 8; i++) {
    int c = t + 256 * i;
    yn[(size_t)row * D_INNER + c] =
        __float2bfloat16(yv[i] * rr * __bfloat162float(nw[c]));
  }
}

// ---------------------------------------------------------------------------
// ln2 on fp32 x2 -> bf16
// ---------------------------------------------------------------------------
__global__ __launch_bounds__(256)
void ln2_kernel(const float* __restrict__ xin, const bf16* __restrict__ w,
                const bf16* __restrict__ b, bf16* __restrict__ out)
{
  int row = blockIdx.x, t = threadIdx.x;
  const float* xr = xin + (size_t)row * D_MODEL;
  __shared__ float rs[4], rq[4];
  float v[4], s = 0.f, ss = 0.f;
  #pragma unroll
  for (int i = 0; i < 4; i++) {
    v[i] = xr[t + 256 * i];
    s += v[i]; ss += v[i] * v[i];
  }
  #pragma unroll
  for (int o = 32; o; o >>= 1) { s += __shfl_down(s, o); ss += __shfl_down(ss, o); }
  if ((t & 63) == 0) { rs[t >> 6] = s; rq[t >> 6] = ss; }
  __syncthreads();
  float S = rs[0] + rs[1] + rs[2] + rs[3];
  float Q = rq[0] + rq[1] + rq[2] + rq[3];
  float mean = S * (1.f / D_MODEL);
  float rstd = rsqrtf(Q * (1.f / D_MODEL) - mean * mean + 1e-5f);
  #pragma unroll
  for (int i = 0; i < 4; i++) {
    int c = t + 256 * i;
    out[(size_t)row * D_MODEL + c] =
        __float2bfloat16((v[i] - mean) * rstd * __bfloat162float(w[c]) + __bfloat162float(b[c]));
  }
}

// ---------------------------------------------------------------------------
extern "C" void kernel_launch(void* const* d_in, const int* in_sizes, int n_in,
                              void* d_out, int out_size, void* d_ws, size_t ws_size,
                              hipStream_t stream)
{
  char* ws = (char*)d_ws;
  // Workspace layout (lifetimes as round 6; xact now bf16 17.8MB, same slot).
  bf16*  xcvt  = (bf16*) (ws + 0);           //  [2->3]
  bf16*  x1b   = (bf16*) (ws + 8388608);     //  [3->4]
  bf16*  Sbuf  = (bf16*) (ws + 0);           //  [7->9]   alias xcvt+x1b
  bf16*  ynb   = (bf16*) (ws + 0);           //  [10->11] alias Sbuf
  float* pf0   = (float*)(ws + 0);           //  [14->14b] alias ynb
  bf16*  wproj = (bf16*) (ws + 16777216);    //  [2->4]
  float* acb   = (float*)(ws + 16777216);    //  [7->8]   alias wproj
  float* dtsb  = (float*)(ws + 16785408);    //  [6->9]   alias wproj
  float* ldab  = (float*)(ws + 17309696);    //  [6->9]   alias wproj
  float* pf1   = (float*)(ws + 16777216);    //  [14->14b] alias wproj region
  bf16*  wout  = (bf16*) (ws + 25493504);    //  [2->11]
  bf16*  w1c   = (bf16*) (ws + 29687808);    //  [2->13]
  bf16*  w2c   = (bf16*) (ws + 38076416);    //  [2->14]
  bf16*  ln0w  = (bf16*) (ws + 46465024);
  bf16*  ln0b  = (bf16*) (ws + 46467072);
  bf16*  ln1w  = (bf16*) (ws + 46469120);
  bf16*  ln1b  = (bf16*) (ws + 46471168);
  bf16*  ln2w  = (bf16*) (ws + 46473216);
  bf16*  ln2b  = (bf16*) (ws + 46475264);
  bf16*  convw = (bf16*) (ws + 46477312);
  bf16*  convb = (bf16*) (ws + 46494720);
  bf16*  dtb   = (bf16*) (ws + 46499072);
  bf16*  alog  = (bf16*) (ws + 46499136);
  bf16*  Dp    = (bf16*) (ws + 46499200);
  bf16*  normw = (bf16*) (ws + 46499264);
  bf16*  b1c   = (bf16*) (ws + 46503360);
  bf16*  b2c   = (bf16*) (ws + 46511552);
  int*   flag  = (int*)  (ws + 46513600);
  bf16*  x0b   = (bf16*) (ws + 46514176);    //  [3->11b]
  bf16*  zxb   = (bf16*) (ws + 54902784);    //  [4->10]
  float* x2f   = (float*)(ws + 54902784);    //  [11b->14b] alias zxb
  float* pf3   = (float*)(ws + 71680000);    //  [14->14b] tail of zxb region
  bf16*  xact  = (bf16*) (ws + 89767936);    //  [5->10]  bf16 17.8MB
  float* pout0 = (float*)(ws + 89767936);    //  [11->11b] alias xact (dead @10)
  float* pout1 = (float*)(ws + 106545152);   //  [11->11b]
  bf16*  gbuf  = (bf16*) (ws + 89767936);    //  [13->14] alias xact region
  bf16*  yfull = (bf16*) (ws + 125419520);   //  [9->10]
  bf16*  hln   = (bf16*) (ws + 125419520);   //  [12->13] alias yfull
  float* pf2   = (float*)(ws + 125419520);   //  [14->14b] alias hln

  detect_kernel<<<1, 64, 0, stream>>>((const unsigned short*)d_in[0], flag);

  CvtArgs ca;
  void* dsts[NT] = { xcvt, ln0w, ln0b, ln1w, ln1b, ln2w, ln2b, wproj, convw, convb,
                     dtb, alog, Dp, normw, wout, w1c, b1c, w2c, b2c };
  int cc = 0;
  ca.ccum[0] = 0;
  for (int i = 0; i < NT; i++) {
    ca.src[i] = d_in[i];
    ca.dst[i] = dsts[i];
    ca.nel[i] = in_sizes[i];
    cc += (in_sizes[i] + 2047) / 2048;
    ca.ccum[i + 1] = cc;
  }
  cvt_kernel<<<cc, 256, 0, stream>>>(ca, flag);

  ln01_kernel<<<NROWS, 256, 0, stream>>>(xcvt, ln0w, ln0b, ln1w, ln1b, x0b, x1b);

  gemm_bt<0><<<dim3(34, 32), 256, 0, stream>>>(x1b, wproj, NROWS, D_IN_PROJ, D_MODEL,
                                               zxb, nullptr);

  conv_silu_kernel<<<dim3(9, NROWS), 256, 0, stream>>>(zxb, convw, convb, xact);
  dt_kernel<<<(NROWS * NHEADS) / 256, 256, 0, stream>>>(zxb, dtb, alog, dtsb, ldab);

  scan_state_kernel<<<NCH * 64, 256, 0, stream>>>(xact, dtsb, ldab, Sbuf, acb);
  state_prop_kernel<<<64 * 4, 256, 0, stream>>>(Sbuf, acb);
  scan_y_kernel<<<NCH * 64, 256, 0, stream>>>(xact, dtsb, ldab, Sbuf, yfull);

  gate_rms_kernel<<<NROWS, 256, 0, stream>>>(yfull, xact, zxb, Dp, normw, ynb);

  // out_proj: split-K=2 (K=2048 -> 2x1024)
  SkParts po = { pout0, pout1, pout0, pout0 };
  gemm_sk<<<dim3(8, 32, 2), 256, 0, stream>>>(ynb, wout, NROWS, D_MODEL, D_INNER, 1024, po);
  reduce_out_kernel<<<(NROWS * D_MODEL) / 1024, 256, 0, stream>>>(pout0, pout1, x0b, x2f);

  ln2_kernel<<<NROWS, 256, 0, stream>>>(x2f, ln2w, ln2b, hln);

  gemm_bt<2><<<dim3(32, 32), 256, 0, stream>>>(hln, w1c, NROWS, FFN_DIM, D_MODEL,
                                               gbuf, b1c);

  // ffn2: split-K=4 (K=4096 -> 4x1024)
  SkParts pfp = { pf0, pf1, pf2, pf3 };
  gemm_sk<<<dim3(8, 32, 4), 256, 0, stream>>>(gbuf, w2c, NROWS, D_MODEL, FFN_DIM, 1024, pfp);
  reduce_ffn_kernel<<<(NROWS * D_MODEL) / 1024, 256, 0, stream>>>(pf0, pf1, pf2, pf3,
                                                                  b2c, x2f, d_out, flag);
}

// Round 8
// 477.811 us; speedup vs baseline: 4.0110x; 1.0066x over previous
//
#include <hip/hip_runtime.h>
#include <hip/hip_bf16.h>
#include <math.h>

typedef __hip_bfloat16 bf16;
typedef __bf16 bhalf;
typedef bhalf bhalf8 __attribute__((ext_vector_type(8)));
typedef float f32x4 __attribute__((ext_vector_type(4)));
typedef unsigned short u16;
typedef u16 u16x4 __attribute__((ext_vector_type(4)));

#define D_MODEL   1024
#define D_STATE   64
#define HEADDIM   64
#define D_INNER   2048
#define NHEADS    32
#define CONV_DIM  2176
#define D_IN_PROJ 4256
#define FFN_DIM   4096
#define BSZ       2
#define SEQ       2048
#define NROWS     (BSZ*SEQ)
#define TC        64
#define NCH       (SEQ/TC)

#define AS1 __attribute__((address_space(1)))
#define AS3 __attribute__((address_space(3)))
__device__ __forceinline__ void load_lds16(const void* g, void* l) {
  __builtin_amdgcn_global_load_lds((AS1 void*)g, (AS3 void*)l, 16, 0, 0);
}

// ---------------------------------------------------------------------------
// Input dtype detection (inputs proven fp32 => flag=1; kept for robustness).
// ---------------------------------------------------------------------------
__global__ __launch_bounds__(64)
void detect_kernel(const unsigned short* __restrict__ x, int* __restrict__ flagp)
{
  int bad = 0;
  for (int i = threadIdx.x; i < 4096; i += 64) {
    unsigned u = ((unsigned)x[i]) << 16;
    float v = __uint_as_float(u);
    if (!(fabsf(v) <= 1e6f)) bad = 1;
  }
  unsigned long long any = __ballot(bad);
  if (threadIdx.x == 0) *flagp = (any != 0ULL) ? 1 : 0;
}

// ---------------------------------------------------------------------------
// Normalize all inputs to bf16 workspace copies.
// ---------------------------------------------------------------------------
#define NT 19
struct CvtArgs {
  const void* src[NT];
  void*       dst[NT];
  int ccum[NT + 1];
  int nel[NT];
};

__global__ __launch_bounds__(256)
void cvt_kernel(CvtArgs a, const int* __restrict__ flagp)
{
  int c = blockIdx.x;
  int ti = 0;
  while (c >= a.ccum[ti + 1]) ti++;
  int base = (c - a.ccum[ti]) * 2048;
  int n = a.nel[ti];
  if (*flagp) {
    const float* s = (const float*)a.src[ti];
    bf16* d = (bf16*)a.dst[ti];
    for (int i = threadIdx.x; i < 2048; i += 256) {
      int j = base + i;
      if (j < n) d[j] = __float2bfloat16(s[j]);
    }
  } else {
    const unsigned short* s = (const unsigned short*)a.src[ti];
    unsigned short* d = (unsigned short*)a.dst[ti];
    for (int i = threadIdx.x; i < 2048; i += 256) {
      int j = base + i;
      if (j < n) d[j] = s[j];
    }
  }
}

// ---------------------------------------------------------------------------
// GEMM 128x128: C[M,N] = A[M,K] @ W[N,K]^T, bf16, fp32 accum, BK=64,
// XOR-swizzled LDS, 1D XCD-grouped grid: blocks sharing an A-tile (same m)
// get ids == const (mod 8) so round-robin dispatch keeps them on one XCD.
// EPI 0: store bf16   EPI 2: store bf16(gelu(acc+bias))
// ---------------------------------------------------------------------------
template<int EPI>
__global__ __launch_bounds__(256, 2)
void gemm_bt(const bf16* __restrict__ A, const bf16* __restrict__ W,
             int M, int N, int K, int nb,
             bf16* __restrict__ outB,
             const bf16* __restrict__ bias)
{
  __shared__ __align__(16) bhalf sA[128 * 64];
  __shared__ __align__(16) bhalf sW[128 * 64];
  const int id   = blockIdx.x;
  const int per  = nb * 8;
  const int hi   = id / per;
  const int rem  = id - hi * per;
  const int jn   = rem >> 3;
  const int mi   = hi * 8 + (rem & 7);
  const int n0   = jn * 128;
  const int m0   = mi * 128;
  const int t    = threadIdx.x;
  const int w    = t >> 6;
  const int lane = t & 63;
  const int wm   = (w >> 1) * 64;
  const int wn   = (w & 1) * 64;
  const int lr   = lane & 15;
  const int lq   = lane >> 4;

  f32x4 acc[4][4];
  #pragma unroll
  for (int i = 0; i < 4; i++)
    #pragma unroll
    for (int j = 0; j < 4; j++)
      acc[i][j] = (f32x4){0.f, 0.f, 0.f, 0.f};

  for (int k0 = 0; k0 < K; k0 += 64) {
    #pragma unroll
    for (int j = 0; j < 4; j++) {
      int s  = t + 256 * j;
      int r  = s >> 3;
      int cs = (s & 7) ^ (r & 7);
      load_lds16(A + (size_t)(m0 + r) * K + k0 + cs * 8, sA + s * 8);
      int wr = n0 + r; wr = wr < N ? wr : N - 1;
      load_lds16(W + (size_t)wr * K + k0 + cs * 8, sW + s * 8);
    }
    __syncthreads();
    #pragma unroll
    for (int kk = 0; kk < 2; kk++) {
      bhalf8 af[4], bfr[4];
      #pragma unroll
      for (int i = 0; i < 4; i++) {
        int r = wm + i * 16 + lr;
        int c = (kk * 4 + lq) ^ (r & 7);
        af[i] = *(const bhalf8*)(sA + r * 64 + c * 8);
      }
      #pragma unroll
      for (int j = 0; j < 4; j++) {
        int r = wn + j * 16 + lr;
        int c = (kk * 4 + lq) ^ (r & 7);
        bfr[j] = *(const bhalf8*)(sW + r * 64 + c * 8);
      }
      #pragma unroll
      for (int i = 0; i < 4; i++)
        #pragma unroll
        for (int j = 0; j < 4; j++)
          acc[i][j] = __builtin_amdgcn_mfma_f32_16x16x32_bf16(af[i], bfr[j], acc[i][j], 0, 0, 0);
    }
    __syncthreads();
  }

  #pragma unroll
  for (int i = 0; i < 4; i++) {
    #pragma unroll
    for (int j = 0; j < 4; j++) {
      #pragma unroll
      for (int r = 0; r < 4; r++) {
        int m = m0 + wm + i * 16 + lq * 4 + r;
        int n = n0 + wn + j * 16 + lr;
        if (n < N) {
          float v = acc[i][j][r];
          size_t idx = (size_t)m * N + n;
          if (EPI == 0) {
            outB[idx] = __float2bfloat16(v);
          } else {
            v += __bfloat162float(bias[n]);
            outB[idx] = __float2bfloat16(0.5f * v * (1.0f + erff(v * 0.70710678118654752f)));
          }
        }
      }
    }
  }
}

// ---------------------------------------------------------------------------
// Skinny GEMM 64x128 tile (N=1024 => 8 n-blocks), full K, no split, fused
// epilogues. Grid = (M/64)*8 = 512 blocks (2/CU). Same swizzle + XCD grouping.
// EPI 0: outF = acc + resB(bf16)            [out_proj]
// EPI 1: out  = acc + bias + resF, dtype per flag -> d_out   [ffn2]
// ---------------------------------------------------------------------------
template<int EPI>
__global__ __launch_bounds__(256, 2)
void gemm_skinny(const bf16* __restrict__ A, const bf16* __restrict__ W,
                 int M, int N, int K,
                 float* __restrict__ outF, void* __restrict__ outAny,
                 const bf16* __restrict__ bias,
                 const bf16* __restrict__ resB,
                 const float* __restrict__ resF,
                 const int* __restrict__ flagp)
{
  __shared__ __align__(16) bhalf sA[64 * 64];
  __shared__ __align__(16) bhalf sW[128 * 64];
  const int id   = blockIdx.x;         // 64 m-groups x 8 n
  const int hi   = id >> 6;            // id / 64
  const int rem  = id & 63;
  const int jn   = rem >> 3;           // n-block 0..7
  const int mi   = hi * 8 + (rem & 7); // m-block 0..63 (same-mi blocks share XCD)
  const int m0   = mi * 64;
  const int n0   = jn * 128;
  const int t    = threadIdx.x;
  const int w    = t >> 6;
  const int lane = t & 63;
  const int wm   = (w >> 1) * 32;
  const int wn   = (w & 1) * 64;
  const int lr   = lane & 15;
  const int lq   = lane >> 4;

  f32x4 acc[2][4];
  #pragma unroll
  for (int i = 0; i < 2; i++)
    #pragma unroll
    for (int j = 0; j < 4; j++)
      acc[i][j] = (f32x4){0.f, 0.f, 0.f, 0.f};

  for (int k0 = 0; k0 < K; k0 += 64) {
    {   // A: 64x64 = 512 chunks, 2 per thread
      #pragma unroll
      for (int j = 0; j < 2; j++) {
        int s  = t + 256 * j;
        int r  = s >> 3;
        int cs = (s & 7) ^ (r & 7);
        load_lds16(A + (size_t)(m0 + r) * K + k0 + cs * 8, sA + s * 8);
      }
      // W: 128x64 = 1024 chunks, 4 per thread
      #pragma unroll
      for (int j = 0; j < 4; j++) {
        int s  = t + 256 * j;
        int r  = s >> 3;
        int cs = (s & 7) ^ (r & 7);
        load_lds16(W + (size_t)(n0 + r) * K + k0 + cs * 8, sW + s * 8);
      }
    }
    __syncthreads();
    #pragma unroll
    for (int kk = 0; kk < 2; kk++) {
      bhalf8 af[2], bfr[4];
      #pragma unroll
      for (int i = 0; i < 2; i++) {
        int r = wm + i * 16 + lr;
        int c = (kk * 4 + lq) ^ (r & 7);
        af[i] = *(const bhalf8*)(sA + r * 64 + c * 8);
      }
      #pragma unroll
      for (int j = 0; j < 4; j++) {
        int r = wn + j * 16 + lr;
        int c = (kk * 4 + lq) ^ (r & 7);
        bfr[j] = *(const bhalf8*)(sW + r * 64 + c * 8);
      }
      #pragma unroll
      for (int i = 0; i < 2; i++)
        #pragma unroll
        for (int j = 0; j < 4; j++)
          acc[i][j] = __builtin_amdgcn_mfma_f32_16x16x32_bf16(af[i], bfr[j], acc[i][j], 0, 0, 0);
    }
    __syncthreads();
  }

  const bool f32o = (EPI == 1) && (*flagp != 0);
  #pragma unroll
  for (int i = 0; i < 2; i++) {
    #pragma unroll
    for (int j = 0; j < 4; j++) {
      #pragma unroll
      for (int r = 0; r < 4; r++) {
        int m = m0 + wm + i * 16 + lq * 4 + r;
        int n = n0 + wn + j * 16 + lr;
        size_t idx = (size_t)m * N + n;
        float v = acc[i][j][r];
        if (EPI == 0) {
          outF[idx] = v + __bfloat162float(resB[idx]);
        } else {
          v += __bfloat162float(bias[n]) + resF[idx];
          if (f32o) ((float*)outAny)[idx] = v;
          else      ((bf16*)outAny)[idx] = __float2bfloat16(v);
        }
      }
    }
  }
}

// ---------------------------------------------------------------------------
// Fused ln0 + ln1.
// ---------------------------------------------------------------------------
__global__ __launch_bounds__(256)
void ln01_kernel(const bf16* __restrict__ x,
                 const bf16* __restrict__ w0, const bf16* __restrict__ b0,
                 const bf16* __restrict__ w1, const bf16* __restrict__ b1,
                 bf16* __restrict__ x0o, bf16* __restrict__ x1o)
{
  int row = blockIdx.x, t = threadIdx.x;
  const bf16* xr = x + (size_t)row * D_MODEL;
  __shared__ float rs[4], rq[4];
  float v[4], s = 0.f, ss = 0.f;
  #pragma unroll
  for (int i = 0; i < 4; i++) {
    v[i] = __bfloat162float(xr[t + 256 * i]);
    s += v[i]; ss += v[i] * v[i];
  }
  #pragma unroll
  for (int o = 32; o; o >>= 1) { s += __shfl_down(s, o); ss += __shfl_down(ss, o); }
  if ((t & 63) == 0) { rs[t >> 6] = s; rq[t >> 6] = ss; }
  __syncthreads();
  float S = rs[0] + rs[1] + rs[2] + rs[3];
  float Q = rq[0] + rq[1] + rq[2] + rq[3];
  float mean = S * (1.f / D_MODEL);
  float rstd = rsqrtf(Q * (1.f / D_MODEL) - mean * mean + 1e-5f);
  float u[4]; s = 0.f; ss = 0.f;
  #pragma unroll
  for (int i = 0; i < 4; i++) {
    int c = t + 256 * i;
    u[i] = (v[i] - mean) * rstd * __bfloat162float(w0[c]) + __bfloat162float(b0[c]);
    s += u[i]; ss += u[i] * u[i];
    x0o[(size_t)row * D_MODEL + c] = __float2bfloat16(u[i]);
  }
  __syncthreads();
  #pragma unroll
  for (int o = 32; o; o >>= 1) { s += __shfl_down(s, o); ss += __shfl_down(ss, o); }
  if ((t & 63) == 0) { rs[t >> 6] = s; rq[t >> 6] = ss; }
  __syncthreads();
  S = rs[0] + rs[1] + rs[2] + rs[3];
  Q = rq[0] + rq[1] + rq[2] + rq[3];
  mean = S * (1.f / D_MODEL);
  rstd = rsqrtf(Q * (1.f / D_MODEL) - mean * mean + 1e-5f);
  #pragma unroll
  for (int i = 0; i < 4; i++) {
    int c = t + 256 * i;
    x1o[(size_t)row * D_MODEL + c] =
        __float2bfloat16((u[i] - mean) * rstd * __bfloat162float(w1[c]) + __bfloat162float(b1[c]));
  }
}

// ---------------------------------------------------------------------------
// Causal depthwise conv (k=4) + SiLU -> bf16 xact.
// ---------------------------------------------------------------------------
__global__ __launch_bounds__(256)
void conv_silu_kernel(const bf16* __restrict__ zxb, const bf16* __restrict__ cw,
                      const bf16* __restrict__ cb, bf16* __restrict__ xact)
{
  int c = blockIdx.x * 256 + threadIdx.x;
  int row = blockIdx.y;
  if (c >= CONV_DIM) return;
  int l = row & (SEQ - 1);
  float acc = __bfloat162float(cb[c]);
  #pragma unroll
  for (int k = 0; k < 4; k++) {
    int lt = l - 3 + k;
    if (lt >= 0)
      acc += __bfloat162float(zxb[(size_t)(row - 3 + k) * D_IN_PROJ + D_INNER + c]) *
             __bfloat162float(cw[c * 4 + k]);
  }
  xact[(size_t)row * CONV_DIM + c] = __float2bfloat16(acc / (1.f + expf(-acc)));
}

// ---------------------------------------------------------------------------
// dt = softplus(raw + dt_bias); lda = dt * A
// ---------------------------------------------------------------------------
__global__ __launch_bounds__(256)
void dt_kernel(const bf16* __restrict__ zxb, const bf16* __restrict__ dt_bias,
               const bf16* __restrict__ A_log, float* __restrict__ dts,
               float* __restrict__ ldab)
{
  int i = blockIdx.x * 256 + threadIdx.x;
  int row = i >> 5, h = i & 31;
  float v = __bfloat162float(zxb[(size_t)row * D_IN_PROJ + (D_INNER + CONV_DIM) + h]) +
            __bfloat162float(dt_bias[h]);
  float sp = (v > 20.f) ? v : log1pf(expf(v));
  dts[i] = sp;
  ldab[i] = -sp * expf(__bfloat162float(A_log[h]));
}

// ---------------------------------------------------------------------------
// MFMA chunk scan, pass 1 (chunk states). xact is bf16.
// ---------------------------------------------------------------------------
__global__ __launch_bounds__(256)
void scan_state_kernel(const bf16* __restrict__ xact, const float* __restrict__ dts,
                       const float* __restrict__ ldab, bf16* __restrict__ Sbuf,
                       float* __restrict__ acb)
{
  __shared__ __align__(16) bf16 wBT[64][72];
  __shared__ __align__(16) bf16 XT[64][72];
  __shared__ float lsS[64], dtS[64];
  const int bid = blockIdx.x;
  const int bh = bid & 63, c = bid >> 6;
  const int b = bh >> 5, h = bh & 31;
  const int t0 = c * TC;
  const int tid = threadIdx.x;
  const int w = tid >> 6, lane = tid & 63;
  const int lr = lane & 15, lq = lane >> 4;

  if (w == 0) {
    float v = ldab[(size_t)(b * SEQ + t0 + lane) * NHEADS + h];
    #pragma unroll
    for (int o = 1; o < 64; o <<= 1) {
      float up = __shfl_up(v, o);
      if (lane >= o) v += up;
    }
    lsS[lane] = v;
    dtS[lane] = dts[(size_t)(b * SEQ + t0 + lane) * NHEADS + h];
  }
  __syncthreads();
  const float lsT = lsS[63];
  {
    int nn = tid & 63, u0 = (tid >> 6) * 16;
    for (int i = 0; i < 16; i++) {
      int u = u0 + i;
      const bf16* rowp = xact + (size_t)(b * SEQ + t0 + u) * CONV_DIM;
      float wgt = dtS[u] * __expf(lsT - lsS[u]);
      wBT[nn][u] = __float2bfloat16(__bfloat162float(rowp[D_INNER + nn]) * wgt);
      XT[nn][u]  = rowp[h * 64 + nn];
    }
  }
  __syncthreads();

  bhalf8 af0 = *(const bhalf8*)&wBT[16 * w + lr][lq * 8];
  bhalf8 af1 = *(const bhalf8*)&wBT[16 * w + lr][32 + lq * 8];
  bf16* sb = Sbuf + ((size_t)bh * NCH + c) * 4096;
  #pragma unroll
  for (int jt = 0; jt < 4; jt++) {
    bhalf8 xf0 = *(const bhalf8*)&XT[16 * jt + lr][lq * 8];
    bhalf8 xf1 = *(const bhalf8*)&XT[16 * jt + lr][32 + lq * 8];
    f32x4 acc = (f32x4){0.f, 0.f, 0.f, 0.f};
    acc = __builtin_amdgcn_mfma_f32_16x16x32_bf16(af0, xf0, acc, 0, 0, 0);
    acc = __builtin_amdgcn_mfma_f32_16x16x32_bf16(af1, xf1, acc, 0, 0, 0);
    #pragma unroll
    for (int r = 0; r < 4; r++) {
      int n = 16 * w + lq * 4 + r;
      int p = 16 * jt + lr;
      sb[p * 64 + n] = __float2bfloat16(acc[r]);
    }
  }
  if (tid == 0) acb[bh * NCH + c] = __expf(lsT);
}

// ---------------------------------------------------------------------------
// Pass 2: serial inter-chunk propagation (in-place).
// ---------------------------------------------------------------------------
__global__ __launch_bounds__(256)
void state_prop_kernel(bf16* __restrict__ Sbuf, const float* __restrict__ acb)
{
  const int bh = blockIdx.x >> 2, q = blockIdx.x & 3;
  const int t = threadIdx.x;
  bf16* sp = Sbuf + (size_t)bh * NCH * 4096 + q * 1024 + t;
  const float* ap = acb + bh * NCH;
  float h0 = 0.f, h1 = 0.f, h2 = 0.f, h3 = 0.f;
  for (int c = 0; c < NCH; c++) {
    bf16* pc = sp + (size_t)c * 4096;
    float s0 = __bfloat162float(pc[0]);
    float s1 = __bfloat162float(pc[256]);
    float s2 = __bfloat162float(pc[512]);
    float s3 = __bfloat162float(pc[768]);
    float a = ap[c];
    pc[0]   = __float2bfloat16(h0);
    pc[256] = __float2bfloat16(h1);
    pc[512] = __float2bfloat16(h2);
    pc[768] = __float2bfloat16(h3);
    h0 = fmaf(h0, a, s0); h1 = fmaf(h1, a, s1);
    h2 = fmaf(h2, a, s2); h3 = fmaf(h3, a, s3);
  }
}

// ---------------------------------------------------------------------------
// MFMA chunk scan, pass 3. xact is bf16.
// ---------------------------------------------------------------------------
__global__ __launch_bounds__(256)
void scan_y_kernel(const bf16* __restrict__ xact, const float* __restrict__ dts,
                   const float* __restrict__ ldab, const bf16* __restrict__ Sbuf,
                   bf16* __restrict__ yfull)
{
  __shared__ __align__(16) bf16 Cs[64][72];
  __shared__ __align__(16) bf16 Bs[64][72];
  __shared__ __align__(16) bf16 XT[64][72];
  __shared__ __align__(16) bf16 HT[64][72];
  __shared__ __align__(16) bf16 Ms[64][72];
  __shared__ float lsS[64], dtS[64];
  const int bid = blockIdx.x;
  const int bh = bid & 63, c = bid >> 6;
  const int b = bh >> 5, h = bh & 31;
  const int t0 = c * TC;
  const int tid = threadIdx.x;
  const int w = tid >> 6, lane = tid & 63;
  const int lr = lane & 15, lq = lane >> 4;

  if (w == 0) {
    float v = ldab[(size_t)(b * SEQ + t0 + lane) * NHEADS + h];
    #pragma unroll
    for (int o = 1; o < 64; o <<= 1) {
      float up = __shfl_up(v, o);
      if (lane >= o) v += up;
    }
    lsS[lane] = v;
    dtS[lane] = dts[(size_t)(b * SEQ + t0 + lane) * NHEADS + h];
  }
  {
    int nn = tid & 63, u0 = (tid >> 6) * 16;
    for (int i = 0; i < 16; i++) {
      int u = u0 + i;
      const bf16* rowp = xact + (size_t)(b * SEQ + t0 + u) * CONV_DIM;
      Bs[u][nn] = rowp[D_INNER + nn];
      Cs[u][nn] = rowp[D_INNER + 64 + nn];
      XT[nn][u] = rowp[h * 64 + nn];
    }
    const bf16* sb = Sbuf + ((size_t)bh * NCH + c) * 4096;
    for (int i = 0; i < 16; i++) {
      int e = tid + 256 * i;
      HT[e >> 6][e & 63] = sb[e];
    }
  }
  __syncthreads();

  bhalf8 cf0 = *(const bhalf8*)&Cs[16 * w + lr][lq * 8];
  bhalf8 cf1 = *(const bhalf8*)&Cs[16 * w + lr][32 + lq * 8];
  f32x4 accH[4];
  #pragma unroll
  for (int jt = 0; jt < 4; jt++) {
    bhalf8 bf0 = *(const bhalf8*)&Bs[16 * jt + lr][lq * 8];
    bhalf8 bf1 = *(const bhalf8*)&Bs[16 * jt + lr][32 + lq * 8];
    f32x4 g = (f32x4){0.f, 0.f, 0.f, 0.f};
    g = __builtin_amdgcn_mfma_f32_16x16x32_bf16(cf0, bf0, g, 0, 0, 0);
    g = __builtin_amdgcn_mfma_f32_16x16x32_bf16(cf1, bf1, g, 0, 0, 0);
    bhalf8 hf0 = *(const bhalf8*)&HT[16 * jt + lr][lq * 8];
    bhalf8 hf1 = *(const bhalf8*)&HT[16 * jt + lr][32 + lq * 8];
    f32x4 ah = (f32x4){0.f, 0.f, 0.f, 0.f};
    ah = __builtin_amdgcn_mfma_f32_16x16x32_bf16(cf0, hf0, ah, 0, 0, 0);
    ah = __builtin_amdgcn_mfma_f32_16x16x32_bf16(cf1, hf1, ah, 0, 0, 0);
    accH[jt] = ah;
    #pragma unroll
    for (int r = 0; r < 4; r++) {
      int t = 16 * w + lq * 4 + r;
      int u = 16 * jt + lr;
      float m = 0.f;
      if (u <= t) m = g[r] * __expf(lsS[t] - lsS[u]) * dtS[u];
      Ms[t][u] = __float2bfloat16(m);
    }
  }
  __syncthreads();

  bhalf8 mf0 = *(const bhalf8*)&Ms[16 * w + lr][lq * 8];
  bhalf8 mf1 = *(const bhalf8*)&Ms[16 * w + lr][32 + lq * 8];
  #pragma unroll
  for (int jt = 0; jt < 4; jt++) {
    bhalf8 xf0 = *(const bhalf8*)&XT[16 * jt + lr][lq * 8];
    bhalf8 xf1 = *(const bhalf8*)&XT[16 * jt + lr][32 + lq * 8];
    f32x4 acc = (f32x4){0.f, 0.f, 0.f, 0.f};
    acc = __builtin_amdgcn_mfma_f32_16x16x32_bf16(mf0, xf0, acc, 0, 0, 0);
    acc = __builtin_amdgcn_mfma_f32_16x16x32_bf16(mf1, xf1, acc, 0, 0, 0);
    #pragma unroll
    for (int r = 0; r < 4; r++) {
      int t = 16 * w + lq * 4 + r;
      int p = 16 * jt + lr;
      float y = acc[r] + __expf(lsS[t]) * accH[jt][r];
      yfull[(size_t)(b * SEQ + t0 + t) * D_INNER + h * 64 + p] = __float2bfloat16(y);
    }
  }
}

// ---------------------------------------------------------------------------
// y = yfull + D*x;  y *= silu(z);  RMSNorm * norm_w -> bf16. xact is bf16.
// ---------------------------------------------------------------------------
__global__ __launch_bounds__(256)
void gate_rms_kernel(const bf16* __restrict__ yfull, const bf16* __restrict__ xact,
                     const bf16* __restrict__ zxb, const bf16* __restrict__ Dp,
                     const bf16* __restrict__ nw, bf16* __restrict__ yn)
{
  int row = blockIdx.x, t = threadIdx.x;
  __shared__ float rq[4];
  float yv[8]; float ss = 0.f;
  #pragma unroll
  for (int i = 0; i < 8; i++) {
    int c = t + 256 * i;
    float y = __bfloat162float(yfull[(size_t)row * D_INNER + c]) +
              __bfloat162float(Dp[c >> 6]) *
              __bfloat162float(xact[(size_t)row * CONV_DIM + c]);
    float z = __bfloat162float(zxb[(size_t)row * D_IN_PROJ + c]);
    yv[i] = y * (z / (1.f + expf(-z)));
    ss += yv[i] * yv[i];
  }
  #pragma unroll
  for (int o = 32; o; o >>= 1) ss += __shfl_down(ss, o);
  if ((t & 63) == 0) rq[t >> 6] = ss;
  __syncthreads();
  float tot = rq[0] + rq[1] + rq[2] + rq[3];
  float rr = rsqrtf(tot * (1.f / D_INNER) + 1e-5f);
  #pragma unroll
  for (int i = 0; i < 8; i++) {
    int c = t + 256 * i;
    yn[(size_t)row * D_INNER + c] =
        __float2bfloat16(yv[i] * rr * __bfloat162float(nw[c]));
  }
}

// ---------------------------------------------------------------------------
// ln2 on fp32 x2 -> bf16
// ---------------------------------------------------------------------------
__global__ __launch_bounds__(256)
void ln2_kernel(const float* __restrict__ xin, const bf16* __restrict__ w,
                const bf16* __restrict__ b, bf16* __restrict__ out)
{
  int row = blockIdx.x, t = threadIdx.x;
  const float* xr = xin + (size_t)row * D_MODEL;
  __shared__ float rs[4], rq[4];
  float v[4], s = 0.f, ss = 0.f;
  #pragma unroll
  for (int i = 0; i < 4; i++) {
    v[i] = xr[t + 256 * i];
    s += v[i]; ss += v[i] * v[i];
  }
  #pragma unroll
  for (int o = 32; o; o >>= 1) { s += __shfl_down(s, o); ss += __shfl_down(ss, o); }
  if ((t & 63) == 0) { rs[t >> 6] = s; rq[t >> 6] = ss; }
  __syncthreads();
  float S = rs[0] + rs[1] + rs[2] + rs[3];
  float Q = rq[0] + rq[1] + rq[2] + rq[3];
  float mean = S * (1.f / D_MODEL);
  float rstd = rsqrtf(Q * (1.f / D_MODEL) - mean * mean + 1e-5f);
  #pragma unroll
  for (int i = 0; i < 4; i++) {
    int c = t + 256 * i;
    out[(size_t)row * D_MODEL + c] =
        __float2bfloat16((v[i] - mean) * rstd * __bfloat162float(w[c]) + __bfloat162float(b[c]));
  }
}

// ---------------------------------------------------------------------------
extern "C" void kernel_launch(void* const* d_in, const int* in_sizes, int n_in,
                              void* d_out, int out_size, void* d_ws, size_t ws_size,
                              hipStream_t stream)
{
  char* ws = (char*)d_ws;
  // Workspace layout (lifetimes as round 7; split-K partials removed).
  bf16*  xcvt  = (bf16*) (ws + 0);           //  [2->3]
  bf16*  x1b   = (bf16*) (ws + 8388608);     //  [3->4]
  bf16*  Sbuf  = (bf16*) (ws + 0);           //  [7->9]   alias xcvt+x1b
  bf16*  ynb   = (bf16*) (ws + 0);           //  [10->11] alias Sbuf
  bf16*  wproj = (bf16*) (ws + 16777216);    //  [2->4]
  float* acb   = (float*)(ws + 16777216);    //  [7->8]   alias wproj
  float* dtsb  = (float*)(ws + 16785408);    //  [6->9]   alias wproj
  float* ldab  = (float*)(ws + 17309696);    //  [6->9]   alias wproj
  bf16*  wout  = (bf16*) (ws + 25493504);    //  [2->11]
  bf16*  w1c   = (bf16*) (ws + 29687808);    //  [2->13]
  bf16*  w2c   = (bf16*) (ws + 38076416);    //  [2->14]
  bf16*  ln0w  = (bf16*) (ws + 46465024);
  bf16*  ln0b  = (bf16*) (ws + 46467072);
  bf16*  ln1w  = (bf16*) (ws + 46469120);
  bf16*  ln1b  = (bf16*) (ws + 46471168);
  bf16*  ln2w  = (bf16*) (ws + 46473216);
  bf16*  ln2b  = (bf16*) (ws + 46475264);
  bf16*  convw = (bf16*) (ws + 46477312);
  bf16*  convb = (bf16*) (ws + 46494720);
  bf16*  dtb   = (bf16*) (ws + 46499072);
  bf16*  alog  = (bf16*) (ws + 46499136);
  bf16*  Dp    = (bf16*) (ws + 46499200);
  bf16*  normw = (bf16*) (ws + 46499264);
  bf16*  b1c   = (bf16*) (ws + 46503360);
  bf16*  b2c   = (bf16*) (ws + 46511552);
  int*   flag  = (int*)  (ws + 46513600);
  bf16*  x0b   = (bf16*) (ws + 46514176);    //  [3->11]
  bf16*  zxb   = (bf16*) (ws + 54902784);    //  [4->10]
  float* x2f   = (float*)(ws + 54902784);    //  [11->14] alias zxb
  bf16*  xact  = (bf16*) (ws + 89767936);    //  [5->10]  bf16 17.8MB
  bf16*  gbuf  = (bf16*) (ws + 89767936);    //  [13->14] alias xact
  bf16*  yfull = (bf16*) (ws + 125419520);   //  [9->10]
  bf16*  hln   = (bf16*) (ws + 125419520);   //  [12->13] alias yfull

  detect_kernel<<<1, 64, 0, stream>>>((const unsigned short*)d_in[0], flag);

  CvtArgs ca;
  void* dsts[NT] = { xcvt, ln0w, ln0b, ln1w, ln1b, ln2w, ln2b, wproj, convw, convb,
                     dtb, alog, Dp, normw, wout, w1c, b1c, w2c, b2c };
  int cc = 0;
  ca.ccum[0] = 0;
  for (int i = 0; i < NT; i++) {
    ca.src[i] = d_in[i];
    ca.dst[i] = dsts[i];
    ca.nel[i] = in_sizes[i];
    cc += (in_sizes[i] + 2047) / 2048;
    ca.ccum[i + 1] = cc;
  }
  cvt_kernel<<<cc, 256, 0, stream>>>(ca, flag);

  ln01_kernel<<<NROWS, 256, 0, stream>>>(xcvt, ln0w, ln0b, ln1w, ln1b, x0b, x1b);

  gemm_bt<0><<<34 * 32, 256, 0, stream>>>(x1b, wproj, NROWS, D_IN_PROJ, D_MODEL, 34,
                                          zxb, nullptr);

  conv_silu_kernel<<<dim3(9, NROWS), 256, 0, stream>>>(zxb, convw, convb, xact);
  dt_kernel<<<(NROWS * NHEADS) / 256, 256, 0, stream>>>(zxb, dtb, alog, dtsb, ldab);

  scan_state_kernel<<<NCH * 64, 256, 0, stream>>>(xact, dtsb, ldab, Sbuf, acb);
  state_prop_kernel<<<64 * 4, 256, 0, stream>>>(Sbuf, acb);
  scan_y_kernel<<<NCH * 64, 256, 0, stream>>>(xact, dtsb, ldab, Sbuf, yfull);

  gate_rms_kernel<<<NROWS, 256, 0, stream>>>(yfull, xact, zxb, Dp, normw, ynb);

  // out_proj: 64x128 skinny GEMM, fused +residual -> x2f (fp32)
  gemm_skinny<0><<<512, 256, 0, stream>>>(ynb, wout, NROWS, D_MODEL, D_INNER,
                                          x2f, nullptr, nullptr, x0b, nullptr, flag);

  ln2_kernel<<<NROWS, 256, 0, stream>>>(x2f, ln2w, ln2b, hln);

  gemm_bt<2><<<32 * 32, 256, 0, stream>>>(hln, w1c, NROWS, FFN_DIM, D_MODEL, 32,
                                          gbuf, b1c);

  // ffn2: 64x128 skinny GEMM, fused +bias+residual -> d_out (dtype per flag)
  gemm_skinny<1><<<512, 256, 0, stream>>>(gbuf, w2c, NROWS, D_MODEL, FFN_DIM,
                                          nullptr, d_out, b2c, nullptr, x2f, flag);
}

// Round 9
// 455.558 us; speedup vs baseline: 4.2070x; 1.0488x over previous
//
#include <hip/hip_runtime.h>
#include <hip/hip_bf16.h>
#include <math.h>

typedef __hip_bfloat16 bf16;
typedef __bf16 bhalf;
typedef bhalf bhalf8 __attribute__((ext_vector_type(8)));
typedef float f32x4 __attribute__((ext_vector_type(4)));
typedef unsigned short u16;
typedef u16 u16x4 __attribute__((ext_vector_type(4)));

#define D_MODEL   1024
#define D_STATE   64
#define HEADDIM   64
#define D_INNER   2048
#define NHEADS    32
#define CONV_DIM  2176
#define D_IN_PROJ 4256
#define FFN_DIM   4096
#define BSZ       2
#define SEQ       2048
#define NROWS     (BSZ*SEQ)
#define TC        64
#define NCH       (SEQ/TC)

#define AS1 __attribute__((address_space(1)))
#define AS3 __attribute__((address_space(3)))
__device__ __forceinline__ void load_lds16(const void* g, void* l) {
  __builtin_amdgcn_global_load_lds((AS1 void*)g, (AS3 void*)l, 16, 0, 0);
}

// ---------------------------------------------------------------------------
// Input dtype detection (inputs proven fp32 => flag=1; kept for robustness).
// ---------------------------------------------------------------------------
__global__ __launch_bounds__(64)
void detect_kernel(const unsigned short* __restrict__ x, int* __restrict__ flagp)
{
  int bad = 0;
  for (int i = threadIdx.x; i < 4096; i += 64) {
    unsigned u = ((unsigned)x[i]) << 16;
    float v = __uint_as_float(u);
    if (!(fabsf(v) <= 1e6f)) bad = 1;
  }
  unsigned long long any = __ballot(bad);
  if (threadIdx.x == 0) *flagp = (any != 0ULL) ? 1 : 0;
}

// ---------------------------------------------------------------------------
// Normalize weight inputs to bf16 workspace copies (x handled in ln01).
// ---------------------------------------------------------------------------
#define NT 18
struct CvtArgs {
  const void* src[NT];
  void*       dst[NT];
  int ccum[NT + 1];
  int nel[NT];
};

__global__ __launch_bounds__(256)
void cvt_kernel(CvtArgs a, const int* __restrict__ flagp)
{
  int c = blockIdx.x;
  int ti = 0;
  while (c >= a.ccum[ti + 1]) ti++;
  int base = (c - a.ccum[ti]) * 2048;
  int n = a.nel[ti];
  if (*flagp) {
    const float* s = (const float*)a.src[ti];
    bf16* d = (bf16*)a.dst[ti];
    for (int i = threadIdx.x; i < 2048; i += 256) {
      int j = base + i;
      if (j < n) d[j] = __float2bfloat16(s[j]);
    }
  } else {
    const unsigned short* s = (const unsigned short*)a.src[ti];
    unsigned short* d = (unsigned short*)a.dst[ti];
    for (int i = threadIdx.x; i < 2048; i += 256) {
      int j = base + i;
      if (j < n) d[j] = s[j];
    }
  }
}

// ---------------------------------------------------------------------------
// GEMM 128x128, BK=64, XOR-swizzled LDS, XCD-grouped 1D grid.
// EPI 0: store bf16   EPI 2: store bf16(gelu(acc+bias))
// ---------------------------------------------------------------------------
template<int EPI>
__global__ __launch_bounds__(256, 2)
void gemm_bt(const bf16* __restrict__ A, const bf16* __restrict__ W,
             int M, int N, int K, int nb,
             bf16* __restrict__ outB,
             const bf16* __restrict__ bias)
{
  __shared__ __align__(16) bhalf sA[128 * 64];
  __shared__ __align__(16) bhalf sW[128 * 64];
  const int id   = blockIdx.x;
  const int per  = nb * 8;
  const int hi   = id / per;
  const int rem  = id - hi * per;
  const int jn   = rem >> 3;
  const int mi   = hi * 8 + (rem & 7);
  const int n0   = jn * 128;
  const int m0   = mi * 128;
  const int t    = threadIdx.x;
  const int w    = t >> 6;
  const int lane = t & 63;
  const int wm   = (w >> 1) * 64;
  const int wn   = (w & 1) * 64;
  const int lr   = lane & 15;
  const int lq   = lane >> 4;

  f32x4 acc[4][4];
  #pragma unroll
  for (int i = 0; i < 4; i++)
    #pragma unroll
    for (int j = 0; j < 4; j++)
      acc[i][j] = (f32x4){0.f, 0.f, 0.f, 0.f};

  for (int k0 = 0; k0 < K; k0 += 64) {
    #pragma unroll
    for (int j = 0; j < 4; j++) {
      int s  = t + 256 * j;
      int r  = s >> 3;
      int cs = (s & 7) ^ (r & 7);
      load_lds16(A + (size_t)(m0 + r) * K + k0 + cs * 8, sA + s * 8);
      int wr = n0 + r; wr = wr < N ? wr : N - 1;
      load_lds16(W + (size_t)wr * K + k0 + cs * 8, sW + s * 8);
    }
    __syncthreads();
    #pragma unroll
    for (int kk = 0; kk < 2; kk++) {
      bhalf8 af[4], bfr[4];
      #pragma unroll
      for (int i = 0; i < 4; i++) {
        int r = wm + i * 16 + lr;
        int c = (kk * 4 + lq) ^ (r & 7);
        af[i] = *(const bhalf8*)(sA + r * 64 + c * 8);
      }
      #pragma unroll
      for (int j = 0; j < 4; j++) {
        int r = wn + j * 16 + lr;
        int c = (kk * 4 + lq) ^ (r & 7);
        bfr[j] = *(const bhalf8*)(sW + r * 64 + c * 8);
      }
      #pragma unroll
      for (int i = 0; i < 4; i++)
        #pragma unroll
        for (int j = 0; j < 4; j++)
          acc[i][j] = __builtin_amdgcn_mfma_f32_16x16x32_bf16(af[i], bfr[j], acc[i][j], 0, 0, 0);
    }
    __syncthreads();
  }

  #pragma unroll
  for (int i = 0; i < 4; i++) {
    #pragma unroll
    for (int j = 0; j < 4; j++) {
      #pragma unroll
      for (int r = 0; r < 4; r++) {
        int m = m0 + wm + i * 16 + lq * 4 + r;
        int n = n0 + wn + j * 16 + lr;
        if (n < N) {
          float v = acc[i][j][r];
          size_t idx = (size_t)m * N + n;
          if (EPI == 0) {
            outB[idx] = __float2bfloat16(v);
          } else {
            v += __bfloat162float(bias[n]);
            outB[idx] = __float2bfloat16(0.5f * v * (1.0f + erff(v * 0.70710678118654752f)));
          }
        }
      }
    }
  }
}

// ---------------------------------------------------------------------------
// Skinny GEMM 64x128 tile, split-K=2 (N=1024): 1024 blocks (4/CU),
// fp32 partials; epilogues live in the reduce kernels.
// ---------------------------------------------------------------------------
__global__ __launch_bounds__(256, 4)
void gemm_skinny_sk(const bf16* __restrict__ A, const bf16* __restrict__ W,
                    int M, int N, int K,
                    float* __restrict__ p0, float* __restrict__ p1)
{
  __shared__ __align__(16) bhalf sA[64 * 64];
  __shared__ __align__(16) bhalf sW[128 * 64];
  const int id   = blockIdx.x;
  const int z    = id >> 9;
  const int id9  = id & 511;
  const int hi   = id9 >> 6;
  const int rem  = id9 & 63;
  const int jn   = rem >> 3;
  const int mi   = hi * 8 + (rem & 7);
  const int m0   = mi * 64;
  const int n0   = jn * 128;
  const int t    = threadIdx.x;
  const int w    = t >> 6;
  const int lane = t & 63;
  const int wm   = (w >> 1) * 32;
  const int wn   = (w & 1) * 64;
  const int lr   = lane & 15;
  const int lq   = lane >> 4;

  f32x4 acc[2][4];
  #pragma unroll
  for (int i = 0; i < 2; i++)
    #pragma unroll
    for (int j = 0; j < 4; j++)
      acc[i][j] = (f32x4){0.f, 0.f, 0.f, 0.f};

  const int kh = K >> 1;
  const int kend = z * kh + kh;
  for (int k0 = z * kh; k0 < kend; k0 += 64) {
    #pragma unroll
    for (int j = 0; j < 2; j++) {
      int s  = t + 256 * j;
      int r  = s >> 3;
      int cs = (s & 7) ^ (r & 7);
      load_lds16(A + (size_t)(m0 + r) * K + k0 + cs * 8, sA + s * 8);
    }
    #pragma unroll
    for (int j = 0; j < 4; j++) {
      int s  = t + 256 * j;
      int r  = s >> 3;
      int cs = (s & 7) ^ (r & 7);
      load_lds16(W + (size_t)(n0 + r) * K + k0 + cs * 8, sW + s * 8);
    }
    __syncthreads();
    #pragma unroll
    for (int kk = 0; kk < 2; kk++) {
      bhalf8 af[2], bfr[4];
      #pragma unroll
      for (int i = 0; i < 2; i++) {
        int r = wm + i * 16 + lr;
        int c = (kk * 4 + lq) ^ (r & 7);
        af[i] = *(const bhalf8*)(sA + r * 64 + c * 8);
      }
      #pragma unroll
      for (int j = 0; j < 4; j++) {
        int r = wn + j * 16 + lr;
        int c = (kk * 4 + lq) ^ (r & 7);
        bfr[j] = *(const bhalf8*)(sW + r * 64 + c * 8);
      }
      #pragma unroll
      for (int i = 0; i < 2; i++)
        #pragma unroll
        for (int j = 0; j < 4; j++)
          acc[i][j] = __builtin_amdgcn_mfma_f32_16x16x32_bf16(af[i], bfr[j], acc[i][j], 0, 0, 0);
    }
    __syncthreads();
  }

  float* out = z ? p1 : p0;
  #pragma unroll
  for (int i = 0; i < 2; i++)
    #pragma unroll
    for (int j = 0; j < 4; j++)
      #pragma unroll
      for (int r = 0; r < 4; r++) {
        int m = m0 + wm + i * 16 + lq * 4 + r;
        int n = n0 + wn + j * 16 + lr;
        out[(size_t)m * N + n] = acc[i][j][r];
      }
}

// ---------------------------------------------------------------------------
// out_proj reduce + residual + FULL ln2, one block per row:
//   x2f = p0 + p1 + resB;  hln = LN(x2f)*w+b (bf16)
// ---------------------------------------------------------------------------
__global__ __launch_bounds__(256)
void reduce_out_ln2_kernel(const float* __restrict__ p0, const float* __restrict__ p1,
                           const bf16* __restrict__ resB, float* __restrict__ x2f,
                           const bf16* __restrict__ w, const bf16* __restrict__ b,
                           bf16* __restrict__ hln)
{
  int row = blockIdx.x, t = threadIdx.x;
  int i = row * 256 + t;
  __shared__ float rs[4], rq[4];
  f32x4 a = ((const f32x4*)p0)[i];
  f32x4 bb = ((const f32x4*)p1)[i];
  u16x4 r = ((const u16x4*)resB)[i];
  f32x4 o;
  float s = 0.f, ss = 0.f;
  #pragma unroll
  for (int j = 0; j < 4; j++) {
    o[j] = a[j] + bb[j] + __uint_as_float(((unsigned)r[j]) << 16);
    s += o[j]; ss += o[j] * o[j];
  }
  ((f32x4*)x2f)[i] = o;
  #pragma unroll
  for (int off = 32; off; off >>= 1) { s += __shfl_down(s, off); ss += __shfl_down(ss, off); }
  if ((t & 63) == 0) { rs[t >> 6] = s; rq[t >> 6] = ss; }
  __syncthreads();
  float S = rs[0] + rs[1] + rs[2] + rs[3];
  float Q = rq[0] + rq[1] + rq[2] + rq[3];
  float mean = S * (1.f / D_MODEL);
  float rstd = rsqrtf(Q * (1.f / D_MODEL) - mean * mean + 1e-5f);
  u16x4 wv = ((const u16x4*)w)[t];
  u16x4 bv = ((const u16x4*)b)[t];
  #pragma unroll
  for (int j = 0; j < 4; j++) {
    float wj = __uint_as_float(((unsigned)wv[j]) << 16);
    float bj = __uint_as_float(((unsigned)bv[j]) << 16);
    hln[(size_t)row * D_MODEL + t * 4 + j] =
        __float2bfloat16((o[j] - mean) * rstd * wj + bj);
  }
}

// ---------------------------------------------------------------------------
// ffn2 reduce: d_out = p0+p1 + bias + resF (dtype per flag)
// ---------------------------------------------------------------------------
__global__ __launch_bounds__(256)
void reduce_ffn_kernel(const float* __restrict__ p0, const float* __restrict__ p1,
                       const bf16* __restrict__ bias, const float* __restrict__ resF,
                       void* __restrict__ outp, const int* __restrict__ flagp)
{
  int i = blockIdx.x * 256 + threadIdx.x;
  int n4 = i & (D_MODEL / 4 - 1);
  f32x4 v0 = ((const f32x4*)p0)[i];
  f32x4 v1 = ((const f32x4*)p1)[i];
  f32x4 rf = ((const f32x4*)resF)[i];
  u16x4 bb = ((const u16x4*)bias)[n4];
  f32x4 o;
  #pragma unroll
  for (int j = 0; j < 4; j++)
    o[j] = v0[j] + v1[j] + rf[j] + __uint_as_float(((unsigned)bb[j]) << 16);
  if (*flagp) {
    ((f32x4*)outp)[i] = o;
  } else {
    bf16* ob = (bf16*)outp;
    #pragma unroll
    for (int j = 0; j < 4; j++) ob[i * 4 + j] = __float2bfloat16(o[j]);
  }
}

// ---------------------------------------------------------------------------
// Fused ln0 + ln1; reads x directly from d_in (fp32 or bf16 per flag).
// ---------------------------------------------------------------------------
__global__ __launch_bounds__(256)
void ln01_kernel(const void* __restrict__ xin, const int* __restrict__ flagp,
                 const bf16* __restrict__ w0, const bf16* __restrict__ b0,
                 const bf16* __restrict__ w1, const bf16* __restrict__ b1,
                 bf16* __restrict__ x0o, bf16* __restrict__ x1o)
{
  int row = blockIdx.x, t = threadIdx.x;
  __shared__ float rs[4], rq[4];
  float v[4], s = 0.f, ss = 0.f;
  if (*flagp) {
    const float* xr = (const float*)xin + (size_t)row * D_MODEL;
    #pragma unroll
    for (int i = 0; i < 4; i++) v[i] = xr[t + 256 * i];
  } else {
    const bf16* xr = (const bf16*)xin + (size_t)row * D_MODEL;
    #pragma unroll
    for (int i = 0; i < 4; i++) v[i] = __bfloat162float(xr[t + 256 * i]);
  }
  #pragma unroll
  for (int i = 0; i < 4; i++) { s += v[i]; ss += v[i] * v[i]; }
  #pragma unroll
  for (int o = 32; o; o >>= 1) { s += __shfl_down(s, o); ss += __shfl_down(ss, o); }
  if ((t & 63) == 0) { rs[t >> 6] = s; rq[t >> 6] = ss; }
  __syncthreads();
  float S = rs[0] + rs[1] + rs[2] + rs[3];
  float Q = rq[0] + rq[1] + rq[2] + rq[3];
  float mean = S * (1.f / D_MODEL);
  float rstd = rsqrtf(Q * (1.f / D_MODEL) - mean * mean + 1e-5f);
  float u[4]; s = 0.f; ss = 0.f;
  #pragma unroll
  for (int i = 0; i < 4; i++) {
    int c = t + 256 * i;
    u[i] = (v[i] - mean) * rstd * __bfloat162float(w0[c]) + __bfloat162float(b0[c]);
    s += u[i]; ss += u[i] * u[i];
    x0o[(size_t)row * D_MODEL + c] = __float2bfloat16(u[i]);
  }
  __syncthreads();
  #pragma unroll
  for (int o = 32; o; o >>= 1) { s += __shfl_down(s, o); ss += __shfl_down(ss, o); }
  if ((t & 63) == 0) { rs[t >> 6] = s; rq[t >> 6] = ss; }
  __syncthreads();
  S = rs[0] + rs[1] + rs[2] + rs[3];
  Q = rq[0] + rq[1] + rq[2] + rq[3];
  mean = S * (1.f / D_MODEL);
  rstd = rsqrtf(Q * (1.f / D_MODEL) - mean * mean + 1e-5f);
  #pragma unroll
  for (int i = 0; i < 4; i++) {
    int c = t + 256 * i;
    x1o[(size_t)row * D_MODEL + c] =
        __float2bfloat16((u[i] - mean) * rstd * __bfloat162float(w1[c]) + __bfloat162float(b1[c]));
  }
}

// ---------------------------------------------------------------------------
// Causal depthwise conv (k=4) + SiLU -> bf16 xact; tail channels do dt/lda.
// ---------------------------------------------------------------------------
__global__ __launch_bounds__(256)
void conv_silu_dt_kernel(const bf16* __restrict__ zxb, const bf16* __restrict__ cw,
                         const bf16* __restrict__ cb, bf16* __restrict__ xact,
                         const bf16* __restrict__ dtb, const bf16* __restrict__ alog,
                         float* __restrict__ dts, float* __restrict__ ldab)
{
  int c = blockIdx.x * 256 + threadIdx.x;
  int row = blockIdx.y;
  if (c < CONV_DIM) {
    int l = row & (SEQ - 1);
    float acc = __bfloat162float(cb[c]);
    #pragma unroll
    for (int k = 0; k < 4; k++) {
      int lt = l - 3 + k;
      if (lt >= 0)
        acc += __bfloat162float(zxb[(size_t)(row - 3 + k) * D_IN_PROJ + D_INNER + c]) *
               __bfloat162float(cw[c * 4 + k]);
    }
    xact[(size_t)row * CONV_DIM + c] = __float2bfloat16(acc / (1.f + expf(-acc)));
  } else if (c < CONV_DIM + NHEADS) {
    int h = c - CONV_DIM;
    float v = __bfloat162float(zxb[(size_t)row * D_IN_PROJ + (D_INNER + CONV_DIM) + h]) +
              __bfloat162float(dtb[h]);
    float sp = (v > 20.f) ? v : log1pf(expf(v));
    dts[row * NHEADS + h] = sp;
    ldab[row * NHEADS + h] = -sp * expf(__bfloat162float(alog[h]));
  }
}

// ---------------------------------------------------------------------------
// MFMA chunk scan, pass 1 (chunk states).
// ---------------------------------------------------------------------------
__global__ __launch_bounds__(256)
void scan_state_kernel(const bf16* __restrict__ xact, const float* __restrict__ dts,
                       const float* __restrict__ ldab, bf16* __restrict__ Sbuf,
                       float* __restrict__ acb)
{
  __shared__ __align__(16) bf16 wBT[64][72];
  __shared__ __align__(16) bf16 XT[64][72];
  __shared__ float lsS[64], dtS[64];
  const int bid = blockIdx.x;
  const int bh = bid & 63, c = bid >> 6;
  const int b = bh >> 5, h = bh & 31;
  const int t0 = c * TC;
  const int tid = threadIdx.x;
  const int w = tid >> 6, lane = tid & 63;
  const int lr = lane & 15, lq = lane >> 4;

  if (w == 0) {
    float v = ldab[(size_t)(b * SEQ + t0 + lane) * NHEADS + h];
    #pragma unroll
    for (int o = 1; o < 64; o <<= 1) {
      float up = __shfl_up(v, o);
      if (lane >= o) v += up;
    }
    lsS[lane] = v;
    dtS[lane] = dts[(size_t)(b * SEQ + t0 + lane) * NHEADS + h];
  }
  __syncthreads();
  const float lsT = lsS[63];
  {
    int nn = tid & 63, u0 = (tid >> 6) * 16;
    for (int i = 0; i < 16; i++) {
      int u = u0 + i;
      const bf16* rowp = xact + (size_t)(b * SEQ + t0 + u) * CONV_DIM;
      float wgt = dtS[u] * __expf(lsT - lsS[u]);
      wBT[nn][u] = __float2bfloat16(__bfloat162float(rowp[D_INNER + nn]) * wgt);
      XT[nn][u]  = rowp[h * 64 + nn];
    }
  }
  __syncthreads();

  bhalf8 af0 = *(const bhalf8*)&wBT[16 * w + lr][lq * 8];
  bhalf8 af1 = *(const bhalf8*)&wBT[16 * w + lr][32 + lq * 8];
  bf16* sb = Sbuf + ((size_t)bh * NCH + c) * 4096;
  #pragma unroll
  for (int jt = 0; jt < 4; jt++) {
    bhalf8 xf0 = *(const bhalf8*)&XT[16 * jt + lr][lq * 8];
    bhalf8 xf1 = *(const bhalf8*)&XT[16 * jt + lr][32 + lq * 8];
    f32x4 acc = (f32x4){0.f, 0.f, 0.f, 0.f};
    acc = __builtin_amdgcn_mfma_f32_16x16x32_bf16(af0, xf0, acc, 0, 0, 0);
    acc = __builtin_amdgcn_mfma_f32_16x16x32_bf16(af1, xf1, acc, 0, 0, 0);
    #pragma unroll
    for (int r = 0; r < 4; r++) {
      int n = 16 * w + lq * 4 + r;
      int p = 16 * jt + lr;
      sb[p * 64 + n] = __float2bfloat16(acc[r]);
    }
  }
  if (tid == 0) acb[bh * NCH + c] = __expf(lsT);
}

// ---------------------------------------------------------------------------
// Pass 2: serial inter-chunk propagation (in-place).
// ---------------------------------------------------------------------------
__global__ __launch_bounds__(256)
void state_prop_kernel(bf16* __restrict__ Sbuf, const float* __restrict__ acb)
{
  const int bh = blockIdx.x >> 2, q = blockIdx.x & 3;
  const int t = threadIdx.x;
  bf16* sp = Sbuf + (size_t)bh * NCH * 4096 + q * 1024 + t;
  const float* ap = acb + bh * NCH;
  float h0 = 0.f, h1 = 0.f, h2 = 0.f, h3 = 0.f;
  for (int c = 0; c < NCH; c++) {
    bf16* pc = sp + (size_t)c * 4096;
    float s0 = __bfloat162float(pc[0]);
    float s1 = __bfloat162float(pc[256]);
    float s2 = __bfloat162float(pc[512]);
    float s3 = __bfloat162float(pc[768]);
    float a = ap[c];
    pc[0]   = __float2bfloat16(h0);
    pc[256] = __float2bfloat16(h1);
    pc[512] = __float2bfloat16(h2);
    pc[768] = __float2bfloat16(h3);
    h0 = fmaf(h0, a, s0); h1 = fmaf(h1, a, s1);
    h2 = fmaf(h2, a, s2); h3 = fmaf(h3, a, s3);
  }
}

// ---------------------------------------------------------------------------
// MFMA chunk scan, pass 3.
// ---------------------------------------------------------------------------
__global__ __launch_bounds__(256)
void scan_y_kernel(const bf16* __restrict__ xact, const float* __restrict__ dts,
                   const float* __restrict__ ldab, const bf16* __restrict__ Sbuf,
                   bf16* __restrict__ yfull)
{
  __shared__ __align__(16) bf16 Cs[64][72];
  __shared__ __align__(16) bf16 Bs[64][72];
  __shared__ __align__(16) bf16 XT[64][72];
  __shared__ __align__(16) bf16 HT[64][72];
  __shared__ __align__(16) bf16 Ms[64][72];
  __shared__ float lsS[64], dtS[64];
  const int bid = blockIdx.x;
  const int bh = bid & 63, c = bid >> 6;
  const int b = bh >> 5, h = bh & 31;
  const int t0 = c * TC;
  const int tid = threadIdx.x;
  const int w = tid >> 6, lane = tid & 63;
  const int lr = lane & 15, lq = lane >> 4;

  if (w == 0) {
    float v = ldab[(size_t)(b * SEQ + t0 + lane) * NHEADS + h];
    #pragma unroll
    for (int o = 1; o < 64; o <<= 1) {
      float up = __shfl_up(v, o);
      if (lane >= o) v += up;
    }
    lsS[lane] = v;
    dtS[lane] = dts[(size_t)(b * SEQ + t0 + lane) * NHEADS + h];
  }
  {
    int nn = tid & 63, u0 = (tid >> 6) * 16;
    for (int i = 0; i < 16; i++) {
      int u = u0 + i;
      const bf16* rowp = xact + (size_t)(b * SEQ + t0 + u) * CONV_DIM;
      Bs[u][nn] = rowp[D_INNER + nn];
      Cs[u][nn] = rowp[D_INNER + 64 + nn];
      XT[nn][u] = rowp[h * 64 + nn];
    }
    const bf16* sb = Sbuf + ((size_t)bh * NCH + c) * 4096;
    for (int i = 0; i < 16; i++) {
      int e = tid + 256 * i;
      HT[e >> 6][e & 63] = sb[e];
    }
  }
  __syncthreads();

  bhalf8 cf0 = *(const bhalf8*)&Cs[16 * w + lr][lq * 8];
  bhalf8 cf1 = *(const bhalf8*)&Cs[16 * w + lr][32 + lq * 8];
  f32x4 accH[4];
  #pragma unroll
  for (int jt = 0; jt < 4; jt++) {
    bhalf8 bf0 = *(const bhalf8*)&Bs[16 * jt + lr][lq * 8];
    bhalf8 bf1 = *(const bhalf8*)&Bs[16 * jt + lr][32 + lq * 8];
    f32x4 g = (f32x4){0.f, 0.f, 0.f, 0.f};
    g = __builtin_amdgcn_mfma_f32_16x16x32_bf16(cf0, bf0, g, 0, 0, 0);
    g = __builtin_amdgcn_mfma_f32_16x16x32_bf16(cf1, bf1, g, 0, 0, 0);
    bhalf8 hf0 = *(const bhalf8*)&HT[16 * jt + lr][lq * 8];
    bhalf8 hf1 = *(const bhalf8*)&HT[16 * jt + lr][32 + lq * 8];
    f32x4 ah = (f32x4){0.f, 0.f, 0.f, 0.f};
    ah = __builtin_amdgcn_mfma_f32_16x16x32_bf16(cf0, hf0, ah, 0, 0, 0);
    ah = __builtin_amdgcn_mfma_f32_16x16x32_bf16(cf1, hf1, ah, 0, 0, 0);
    accH[jt] = ah;
    #pragma unroll
    for (int r = 0; r < 4; r++) {
      int t = 16 * w + lq * 4 + r;
      int u = 16 * jt + lr;
      float m = 0.f;
      if (u <= t) m = g[r] * __expf(lsS[t] - lsS[u]) * dtS[u];
      Ms[t][u] = __float2bfloat16(m);
    }
  }
  __syncthreads();

  bhalf8 mf0 = *(const bhalf8*)&Ms[16 * w + lr][lq * 8];
  bhalf8 mf1 = *(const bhalf8*)&Ms[16 * w + lr][32 + lq * 8];
  #pragma unroll
  for (int jt = 0; jt < 4; jt++) {
    bhalf8 xf0 = *(const bhalf8*)&XT[16 * jt + lr][lq * 8];
    bhalf8 xf1 = *(const bhalf8*)&XT[16 * jt + lr][32 + lq * 8];
    f32x4 acc = (f32x4){0.f, 0.f, 0.f, 0.f};
    acc = __builtin_amdgcn_mfma_f32_16x16x32_bf16(mf0, xf0, acc, 0, 0, 0);
    acc = __builtin_amdgcn_mfma_f32_16x16x32_bf16(mf1, xf1, acc, 0, 0, 0);
    #pragma unroll
    for (int r = 0; r < 4; r++) {
      int t = 16 * w + lq * 4 + r;
      int p = 16 * jt + lr;
      float y = acc[r] + __expf(lsS[t]) * accH[jt][r];
      yfull[(size_t)(b * SEQ + t0 + t) * D_INNER + h * 64 + p] = __float2bfloat16(y);
    }
  }
}

// ---------------------------------------------------------------------------
// y = yfull + D*x;  y *= silu(z);  RMSNorm * norm_w -> bf16.
// ---------------------------------------------------------------------------
__global__ __launch_bounds__(256)
void gate_rms_kernel(const bf16* __restrict__ yfull, const bf16* __restrict__ xact,
                     const bf16* __restrict__ zxb, const bf16* __restrict__ Dp,
                     const bf16* __restrict__ nw, bf16* __restrict__ yn)
{
  int row = blockIdx.x, t = threadIdx.x;
  __shared__ float rq[4];
  float yv[8]; float ss = 0.f;
  #pragma unroll
  for (int i = 0; i < 8; i++) {
    int c = t + 256 * i;
    float y = __bfloat162float(yfull[(size_t)row * D_INNER + c]) +
              __bfloat162float(Dp[c >> 6]) *
              __bfloat162float(xact[(size_t)row * CONV_DIM + c]);
    float z = __bfloat162float(zxb[(size_t)row * D_IN_PROJ + c]);
    yv[i] = y * (z / (1.f + expf(-z)));
    ss += yv[i] * yv[i];
  }
  #pragma unroll
  for (int o = 32; o; o >>= 1) ss += __shfl_down(ss, o);
  if ((t & 63) == 0) rq[t >> 6] = ss;
  __syncthreads();
  float tot = rq[0] + rq[1] + rq[2] + rq[3];
  float rr = rsqrtf(tot * (1.f / D_INNER) + 1e-5f);
  #pragma unroll
  for (int i = 0; i < 8; i++) {
    int c = t + 256 * i;
    yn[(size_t)row * D_INNER + c] =
        __float2bfloat16(yv[i] * rr * __bfloat162float(nw[c]));
  }
}

// ---------------------------------------------------------------------------
extern "C" void kernel_launch(void* const* d_in, const int* in_sizes, int n_in,
                              void* d_out, int out_size, void* d_ws, size_t ws_size,
                              hipStream_t stream)
{
  char* ws = (char*)d_ws;
  // Stages: 1 detect, 2 cvt, 3 ln01, 4 in_proj, 5 conv+dt, 7 scanP1, 8 prop,
  // 9 scanP3, 10 gate_rms, 11 out_proj_sk, 11b reduce+ln2, 13 ffn1,
  // 14 ffn2_sk, 14b reduce_ffn.
  bf16*  x1b   = (bf16*) (ws + 0);           //  [3->4]
  bf16*  Sbuf  = (bf16*) (ws + 0);           //  [7->9]   alias x1b (dead @4)
  bf16*  ynb   = (bf16*) (ws + 0);           //  [10->11] alias Sbuf
  float* pf0   = (float*)(ws + 0);           //  [14->14b] alias ynb
  bf16*  wproj = (bf16*) (ws + 16777216);    //  [2->4]
  float* acb   = (float*)(ws + 16777216);    //  [7->8]   alias wproj
  float* dtsb  = (float*)(ws + 16785408);    //  [5->9]   alias wproj
  float* ldab  = (float*)(ws + 17309696);    //  [5->9]   alias wproj
  float* pf1   = (float*)(ws + 16777216);    //  [14->14b] alias wproj region
  bf16*  wout  = (bf16*) (ws + 25493504);    //  [2->11]
  bf16*  w1c   = (bf16*) (ws + 29687808);    //  [2->13]
  bf16*  w2c   = (bf16*) (ws + 38076416);    //  [2->14]
  bf16*  ln0w  = (bf16*) (ws + 46465024);
  bf16*  ln0b  = (bf16*) (ws + 46467072);
  bf16*  ln1w  = (bf16*) (ws + 46469120);
  bf16*  ln1b  = (bf16*) (ws + 46471168);
  bf16*  ln2w  = (bf16*) (ws + 46473216);
  bf16*  ln2b  = (bf16*) (ws + 46475264);
  bf16*  convw = (bf16*) (ws + 46477312);
  bf16*  convb = (bf16*) (ws + 46494720);
  bf16*  dtb   = (bf16*) (ws + 46499072);
  bf16*  alog  = (bf16*) (ws + 46499136);
  bf16*  Dp    = (bf16*) (ws + 46499200);
  bf16*  normw = (bf16*) (ws + 46499264);
  bf16*  b1c   = (bf16*) (ws + 46503360);
  bf16*  b2c   = (bf16*) (ws + 46511552);
  int*   flag  = (int*)  (ws + 46513600);
  bf16*  x0b   = (bf16*) (ws + 46514176);    //  [3->11b]
  bf16*  zxb   = (bf16*) (ws + 54902784);    //  [4->10]
  float* x2f   = (float*)(ws + 54902784);    //  [11b->14b] alias zxb
  bf16*  xact  = (bf16*) (ws + 89767936);    //  [5->10]
  float* pout0 = (float*)(ws + 89767936);    //  [11->11b] alias xact
  float* pout1 = (float*)(ws + 106545152);   //  [11->11b]
  bf16*  gbuf  = (bf16*) (ws + 89767936);    //  [13->14] alias xact region
  bf16*  yfull = (bf16*) (ws + 125419520);   //  [9->10]
  bf16*  hln   = (bf16*) (ws + 125419520);   //  [11b->13] alias yfull

  detect_kernel<<<1, 64, 0, stream>>>((const unsigned short*)d_in[0], flag);

  CvtArgs ca;
  void* dsts[NT] = { ln0w, ln0b, ln1w, ln1b, ln2w, ln2b, wproj, convw, convb,
                     dtb, alog, Dp, normw, wout, w1c, b1c, w2c, b2c };
  int cc = 0;
  ca.ccum[0] = 0;
  for (int i = 0; i < NT; i++) {
    ca.src[i] = d_in[i + 1];
    ca.dst[i] = dsts[i];
    ca.nel[i] = in_sizes[i + 1];
    cc += (in_sizes[i + 1] + 2047) / 2048;
    ca.ccum[i + 1] = cc;
  }
  cvt_kernel<<<cc, 256, 0, stream>>>(ca, flag);

  ln01_kernel<<<NROWS, 256, 0, stream>>>(d_in[0], flag, ln0w, ln0b, ln1w, ln1b,
                                         x0b, x1b);

  gemm_bt<0><<<34 * 32, 256, 0, stream>>>(x1b, wproj, NROWS, D_IN_PROJ, D_MODEL, 34,
                                          zxb, nullptr);

  conv_silu_dt_kernel<<<dim3(9, NROWS), 256, 0, stream>>>(zxb, convw, convb, xact,
                                                          dtb, alog, dtsb, ldab);

  scan_state_kernel<<<NCH * 64, 256, 0, stream>>>(xact, dtsb, ldab, Sbuf, acb);
  state_prop_kernel<<<64 * 4, 256, 0, stream>>>(Sbuf, acb);
  scan_y_kernel<<<NCH * 64, 256, 0, stream>>>(xact, dtsb, ldab, Sbuf, yfull);

  gate_rms_kernel<<<NROWS, 256, 0, stream>>>(yfull, xact, zxb, Dp, normw, ynb);

  // out_proj: 64x128 split-K=2 -> partials, then fused reduce+residual+ln2
  gemm_skinny_sk<<<1024, 256, 0, stream>>>(ynb, wout, NROWS, D_MODEL, D_INNER,
                                           pout0, pout1);
  reduce_out_ln2_kernel<<<NROWS, 256, 0, stream>>>(pout0, pout1, x0b, x2f,
                                                   ln2w, ln2b, hln);

  gemm_bt<2><<<32 * 32, 256, 0, stream>>>(hln, w1c, NROWS, FFN_DIM, D_MODEL, 32,
                                          gbuf, b1c);

  // ffn2: 64x128 split-K=2 -> partials, then fused reduce(+bias+residual)
  gemm_skinny_sk<<<1024, 256, 0, stream>>>(gbuf, w2c, NROWS, D_MODEL, FFN_DIM,
                                           pf0, pf1);
  reduce_ffn_kernel<<<(NROWS * D_MODEL) / 1024, 256, 0, stream>>>(pf0, pf1,
                                                                  b2c, x2f, d_out, flag);
}

// Round 10
// 450.654 us; speedup vs baseline: 4.2527x; 1.0109x over previous
//
#include <hip/hip_runtime.h>
#include <hip/hip_bf16.h>
#include <math.h>

typedef __hip_bfloat16 bf16;
typedef __bf16 bhalf;
typedef bhalf bhalf8 __attribute__((ext_vector_type(8)));
typedef float f32x4 __attribute__((ext_vector_type(4)));
typedef unsigned short u16;
typedef u16 u16x4 __attribute__((ext_vector_type(4)));

#define D_MODEL   1024
#define D_STATE   64
#define HEADDIM   64
#define D_INNER   2048
#define NHEADS    32
#define CONV_DIM  2176
#define D_IN_PROJ 4256
#define FFN_DIM   4096
#define BSZ       2
#define SEQ       2048
#define NROWS     (BSZ*SEQ)
#define TC        64
#define NCH       (SEQ/TC)

#define AS1 __attribute__((address_space(1)))
#define AS3 __attribute__((address_space(3)))
__device__ __forceinline__ void load_lds16(const void* g, void* l) {
  __builtin_amdgcn_global_load_lds((AS1 void*)g, (AS3 void*)l, 16, 0, 0);
}

// ---------------------------------------------------------------------------
// Input dtype detection (inputs proven fp32 => flag=1; kept for robustness).
// ---------------------------------------------------------------------------
__global__ __launch_bounds__(64)
void detect_kernel(const unsigned short* __restrict__ x, int* __restrict__ flagp)
{
  int bad = 0;
  for (int i = threadIdx.x; i < 4096; i += 64) {
    unsigned u = ((unsigned)x[i]) << 16;
    float v = __uint_as_float(u);
    if (!(fabsf(v) <= 1e6f)) bad = 1;
  }
  unsigned long long any = __ballot(bad);
  if (threadIdx.x == 0) *flagp = (any != 0ULL) ? 1 : 0;
}

// ---------------------------------------------------------------------------
// Normalize weight inputs to bf16 workspace copies (x handled in ln01).
// ---------------------------------------------------------------------------
#define NT 18
struct CvtArgs {
  const void* src[NT];
  void*       dst[NT];
  int ccum[NT + 1];
  int nel[NT];
};

__global__ __launch_bounds__(256)
void cvt_kernel(CvtArgs a, const int* __restrict__ flagp)
{
  int c = blockIdx.x;
  int ti = 0;
  while (c >= a.ccum[ti + 1]) ti++;
  int base = (c - a.ccum[ti]) * 2048;
  int n = a.nel[ti];
  if (*flagp) {
    const float* s = (const float*)a.src[ti];
    bf16* d = (bf16*)a.dst[ti];
    for (int i = threadIdx.x; i < 2048; i += 256) {
      int j = base + i;
      if (j < n) d[j] = __float2bfloat16(s[j]);
    }
  } else {
    const unsigned short* s = (const unsigned short*)a.src[ti];
    unsigned short* d = (unsigned short*)a.dst[ti];
    for (int i = threadIdx.x; i < 2048; i += 256) {
      int j = base + i;
      if (j < n) d[j] = s[j];
    }
  }
}

// ---------------------------------------------------------------------------
// GEMM 128x128, BK=64, XOR-swizzled LDS. 2D grid dim3(nb, M/128):
// blockIdx.x = n-block (fastest) -- the round-7-proven dispatch order
// (consecutive blocks share the A m-tile; W columns partition across XCDs).
// EPI 0: store bf16   EPI 2: store bf16(gelu(acc+bias))
// ---------------------------------------------------------------------------
template<int EPI>
__global__ __launch_bounds__(256, 2)
void gemm_bt(const bf16* __restrict__ A, const bf16* __restrict__ W,
             int M, int N, int K,
             bf16* __restrict__ outB,
             const bf16* __restrict__ bias)
{
  __shared__ __align__(16) bhalf sA[128 * 64];
  __shared__ __align__(16) bhalf sW[128 * 64];
  const int n0   = blockIdx.x * 128;
  const int m0   = blockIdx.y * 128;
  const int t    = threadIdx.x;
  const int w    = t >> 6;
  const int lane = t & 63;
  const int wm   = (w >> 1) * 64;
  const int wn   = (w & 1) * 64;
  const int lr   = lane & 15;
  const int lq   = lane >> 4;

  f32x4 acc[4][4];
  #pragma unroll
  for (int i = 0; i < 4; i++)
    #pragma unroll
    for (int j = 0; j < 4; j++)
      acc[i][j] = (f32x4){0.f, 0.f, 0.f, 0.f};

  for (int k0 = 0; k0 < K; k0 += 64) {
    #pragma unroll
    for (int j = 0; j < 4; j++) {
      int s  = t + 256 * j;
      int r  = s >> 3;
      int cs = (s & 7) ^ (r & 7);
      load_lds16(A + (size_t)(m0 + r) * K + k0 + cs * 8, sA + s * 8);
      int wr = n0 + r; wr = wr < N ? wr : N - 1;
      load_lds16(W + (size_t)wr * K + k0 + cs * 8, sW + s * 8);
    }
    __syncthreads();
    #pragma unroll
    for (int kk = 0; kk < 2; kk++) {
      bhalf8 af[4], bfr[4];
      #pragma unroll
      for (int i = 0; i < 4; i++) {
        int r = wm + i * 16 + lr;
        int c = (kk * 4 + lq) ^ (r & 7);
        af[i] = *(const bhalf8*)(sA + r * 64 + c * 8);
      }
      #pragma unroll
      for (int j = 0; j < 4; j++) {
        int r = wn + j * 16 + lr;
        int c = (kk * 4 + lq) ^ (r & 7);
        bfr[j] = *(const bhalf8*)(sW + r * 64 + c * 8);
      }
      #pragma unroll
      for (int i = 0; i < 4; i++)
        #pragma unroll
        for (int j = 0; j < 4; j++)
          acc[i][j] = __builtin_amdgcn_mfma_f32_16x16x32_bf16(af[i], bfr[j], acc[i][j], 0, 0, 0);
    }
    __syncthreads();
  }

  #pragma unroll
  for (int i = 0; i < 4; i++) {
    #pragma unroll
    for (int j = 0; j < 4; j++) {
      #pragma unroll
      for (int r = 0; r < 4; r++) {
        int m = m0 + wm + i * 16 + lq * 4 + r;
        int n = n0 + wn + j * 16 + lr;
        if (n < N) {
          float v = acc[i][j][r];
          size_t idx = (size_t)m * N + n;
          if (EPI == 0) {
            outB[idx] = __float2bfloat16(v);
          } else {
            v += __bfloat162float(bias[n]);
            outB[idx] = __float2bfloat16(0.5f * v * (1.0f + erff(v * 0.70710678118654752f)));
          }
        }
      }
    }
  }
}

// ---------------------------------------------------------------------------
// Skinny GEMM 64x128 tile, split-K=2 (N=1024): 1024 blocks (4/CU),
// fp32 partials; epilogues live in the reduce kernels.
// ---------------------------------------------------------------------------
__global__ __launch_bounds__(256, 4)
void gemm_skinny_sk(const bf16* __restrict__ A, const bf16* __restrict__ W,
                    int M, int N, int K,
                    float* __restrict__ p0, float* __restrict__ p1)
{
  __shared__ __align__(16) bhalf sA[64 * 64];
  __shared__ __align__(16) bhalf sW[128 * 64];
  const int id   = blockIdx.x;
  const int z    = id >> 9;
  const int id9  = id & 511;
  const int hi   = id9 >> 6;
  const int rem  = id9 & 63;
  const int jn   = rem >> 3;
  const int mi   = hi * 8 + (rem & 7);
  const int m0   = mi * 64;
  const int n0   = jn * 128;
  const int t    = threadIdx.x;
  const int w    = t >> 6;
  const int lane = t & 63;
  const int wm   = (w >> 1) * 32;
  const int wn   = (w & 1) * 64;
  const int lr   = lane & 15;
  const int lq   = lane >> 4;

  f32x4 acc[2][4];
  #pragma unroll
  for (int i = 0; i < 2; i++)
    #pragma unroll
    for (int j = 0; j < 4; j++)
      acc[i][j] = (f32x4){0.f, 0.f, 0.f, 0.f};

  const int kh = K >> 1;
  const int kend = z * kh + kh;
  for (int k0 = z * kh; k0 < kend; k0 += 64) {
    #pragma unroll
    for (int j = 0; j < 2; j++) {
      int s  = t + 256 * j;
      int r  = s >> 3;
      int cs = (s & 7) ^ (r & 7);
      load_lds16(A + (size_t)(m0 + r) * K + k0 + cs * 8, sA + s * 8);
    }
    #pragma unroll
    for (int j = 0; j < 4; j++) {
      int s  = t + 256 * j;
      int r  = s >> 3;
      int cs = (s & 7) ^ (r & 7);
      load_lds16(W + (size_t)(n0 + r) * K + k0 + cs * 8, sW + s * 8);
    }
    __syncthreads();
    #pragma unroll
    for (int kk = 0; kk < 2; kk++) {
      bhalf8 af[2], bfr[4];
      #pragma unroll
      for (int i = 0; i < 2; i++) {
        int r = wm + i * 16 + lr;
        int c = (kk * 4 + lq) ^ (r & 7);
        af[i] = *(const bhalf8*)(sA + r * 64 + c * 8);
      }
      #pragma unroll
      for (int j = 0; j < 4; j++) {
        int r = wn + j * 16 + lr;
        int c = (kk * 4 + lq) ^ (r & 7);
        bfr[j] = *(const bhalf8*)(sW + r * 64 + c * 8);
      }
      #pragma unroll
      for (int i = 0; i < 2; i++)
        #pragma unroll
        for (int j = 0; j < 4; j++)
          acc[i][j] = __builtin_amdgcn_mfma_f32_16x16x32_bf16(af[i], bfr[j], acc[i][j], 0, 0, 0);
    }
    __syncthreads();
  }

  float* out = z ? p1 : p0;
  #pragma unroll
  for (int i = 0; i < 2; i++)
    #pragma unroll
    for (int j = 0; j < 4; j++)
      #pragma unroll
      for (int r = 0; r < 4; r++) {
        int m = m0 + wm + i * 16 + lq * 4 + r;
        int n = n0 + wn + j * 16 + lr;
        out[(size_t)m * N + n] = acc[i][j][r];
      }
}

// ---------------------------------------------------------------------------
// out_proj reduce + residual + FULL ln2, one block per row:
//   x2f = p0 + p1 + resB;  hln = LN(x2f)*w+b (bf16)
// ---------------------------------------------------------------------------
__global__ __launch_bounds__(256)
void reduce_out_ln2_kernel(const float* __restrict__ p0, const float* __restrict__ p1,
                           const bf16* __restrict__ resB, float* __restrict__ x2f,
                           const bf16* __restrict__ w, const bf16* __restrict__ b,
                           bf16* __restrict__ hln)
{
  int row = blockIdx.x, t = threadIdx.x;
  int i = row * 256 + t;
  __shared__ float rs[4], rq[4];
  f32x4 a = ((const f32x4*)p0)[i];
  f32x4 bb = ((const f32x4*)p1)[i];
  u16x4 r = ((const u16x4*)resB)[i];
  f32x4 o;
  float s = 0.f, ss = 0.f;
  #pragma unroll
  for (int j = 0; j < 4; j++) {
    o[j] = a[j] + bb[j] + __uint_as_float(((unsigned)r[j]) << 16);
    s += o[j]; ss += o[j] * o[j];
  }
  ((f32x4*)x2f)[i] = o;
  #pragma unroll
  for (int off = 32; off; off >>= 1) { s += __shfl_down(s, off); ss += __shfl_down(ss, off); }
  if ((t & 63) == 0) { rs[t >> 6] = s; rq[t >> 6] = ss; }
  __syncthreads();
  float S = rs[0] + rs[1] + rs[2] + rs[3];
  float Q = rq[0] + rq[1] + rq[2] + rq[3];
  float mean = S * (1.f / D_MODEL);
  float rstd = rsqrtf(Q * (1.f / D_MODEL) - mean * mean + 1e-5f);
  u16x4 wv = ((const u16x4*)w)[t];
  u16x4 bv = ((const u16x4*)b)[t];
  #pragma unroll
  for (int j = 0; j < 4; j++) {
    float wj = __uint_as_float(((unsigned)wv[j]) << 16);
    float bj = __uint_as_float(((unsigned)bv[j]) << 16);
    hln[(size_t)row * D_MODEL + t * 4 + j] =
        __float2bfloat16((o[j] - mean) * rstd * wj + bj);
  }
}

// ---------------------------------------------------------------------------
// ffn2 reduce: d_out = p0+p1 + bias + resF (dtype per flag)
// ---------------------------------------------------------------------------
__global__ __launch_bounds__(256)
void reduce_ffn_kernel(const float* __restrict__ p0, const float* __restrict__ p1,
                       const bf16* __restrict__ bias, const float* __restrict__ resF,
                       void* __restrict__ outp, const int* __restrict__ flagp)
{
  int i = blockIdx.x * 256 + threadIdx.x;
  int n4 = i & (D_MODEL / 4 - 1);
  f32x4 v0 = ((const f32x4*)p0)[i];
  f32x4 v1 = ((const f32x4*)p1)[i];
  f32x4 rf = ((const f32x4*)resF)[i];
  u16x4 bb = ((const u16x4*)bias)[n4];
  f32x4 o;
  #pragma unroll
  for (int j = 0; j < 4; j++)
    o[j] = v0[j] + v1[j] + rf[j] + __uint_as_float(((unsigned)bb[j]) << 16);
  if (*flagp) {
    ((f32x4*)outp)[i] = o;
  } else {
    bf16* ob = (bf16*)outp;
    #pragma unroll
    for (int j = 0; j < 4; j++) ob[i * 4 + j] = __float2bfloat16(o[j]);
  }
}

// ---------------------------------------------------------------------------
// Fused ln0 + ln1; reads x directly from d_in (fp32 or bf16 per flag).
// ---------------------------------------------------------------------------
__global__ __launch_bounds__(256)
void ln01_kernel(const void* __restrict__ xin, const int* __restrict__ flagp,
                 const bf16* __restrict__ w0, const bf16* __restrict__ b0,
                 const bf16* __restrict__ w1, const bf16* __restrict__ b1,
                 bf16* __restrict__ x0o, bf16* __restrict__ x1o)
{
  int row = blockIdx.x, t = threadIdx.x;
  __shared__ float rs[4], rq[4];
  float v[4], s = 0.f, ss = 0.f;
  if (*flagp) {
    const float* xr = (const float*)xin + (size_t)row * D_MODEL;
    #pragma unroll
    for (int i = 0; i < 4; i++) v[i] = xr[t + 256 * i];
  } else {
    const bf16* xr = (const bf16*)xin + (size_t)row * D_MODEL;
    #pragma unroll
    for (int i = 0; i < 4; i++) v[i] = __bfloat162float(xr[t + 256 * i]);
  }
  #pragma unroll
  for (int i = 0; i < 4; i++) { s += v[i]; ss += v[i] * v[i]; }
  #pragma unroll
  for (int o = 32; o; o >>= 1) { s += __shfl_down(s, o); ss += __shfl_down(ss, o); }
  if ((t & 63) == 0) { rs[t >> 6] = s; rq[t >> 6] = ss; }
  __syncthreads();
  float S = rs[0] + rs[1] + rs[2] + rs[3];
  float Q = rq[0] + rq[1] + rq[2] + rq[3];
  float mean = S * (1.f / D_MODEL);
  float rstd = rsqrtf(Q * (1.f / D_MODEL) - mean * mean + 1e-5f);
  float u[4]; s = 0.f; ss = 0.f;
  #pragma unroll
  for (int i = 0; i < 4; i++) {
    int c = t + 256 * i;
    u[i] = (v[i] - mean) * rstd * __bfloat162float(w0[c]) + __bfloat162float(b0[c]);
    s += u[i]; ss += u[i] * u[i];
    x0o[(size_t)row * D_MODEL + c] = __float2bfloat16(u[i]);
  }
  __syncthreads();
  #pragma unroll
  for (int o = 32; o; o >>= 1) { s += __shfl_down(s, o); ss += __shfl_down(ss, o); }
  if ((t & 63) == 0) { rs[t >> 6] = s; rq[t >> 6] = ss; }
  __syncthreads();
  S = rs[0] + rs[1] + rs[2] + rs[3];
  Q = rq[0] + rq[1] + rq[2] + rq[3];
  mean = S * (1.f / D_MODEL);
  rstd = rsqrtf(Q * (1.f / D_MODEL) - mean * mean + 1e-5f);
  #pragma unroll
  for (int i = 0; i < 4; i++) {
    int c = t + 256 * i;
    x1o[(size_t)row * D_MODEL + c] =
        __float2bfloat16((u[i] - mean) * rstd * __bfloat162float(w1[c]) + __bfloat162float(b1[c]));
  }
}

// ---------------------------------------------------------------------------
// Causal depthwise conv (k=4) + SiLU -> bf16 xact; tail channels do dt/lda.
// ---------------------------------------------------------------------------
__global__ __launch_bounds__(256)
void conv_silu_dt_kernel(const bf16* __restrict__ zxb, const bf16* __restrict__ cw,
                         const bf16* __restrict__ cb, bf16* __restrict__ xact,
                         const bf16* __restrict__ dtb, const bf16* __restrict__ alog,
                         float* __restrict__ dts, float* __restrict__ ldab)
{
  int c = blockIdx.x * 256 + threadIdx.x;
  int row = blockIdx.y;
  if (c < CONV_DIM) {
    int l = row & (SEQ - 1);
    float acc = __bfloat162float(cb[c]);
    #pragma unroll
    for (int k = 0; k < 4; k++) {
      int lt = l - 3 + k;
      if (lt >= 0)
        acc += __bfloat162float(zxb[(size_t)(row - 3 + k) * D_IN_PROJ + D_INNER + c]) *
               __bfloat162float(cw[c * 4 + k]);
    }
    xact[(size_t)row * CONV_DIM + c] = __float2bfloat16(acc / (1.f + expf(-acc)));
  } else if (c < CONV_DIM + NHEADS) {
    int h = c - CONV_DIM;
    float v = __bfloat162float(zxb[(size_t)row * D_IN_PROJ + (D_INNER + CONV_DIM) + h]) +
              __bfloat162float(dtb[h]);
    float sp = (v > 20.f) ? v : log1pf(expf(v));
    dts[row * NHEADS + h] = sp;
    ldab[row * NHEADS + h] = -sp * expf(__bfloat162float(alog[h]));
  }
}

// ---------------------------------------------------------------------------
// MFMA chunk scan, pass 1 (chunk states).
// ---------------------------------------------------------------------------
__global__ __launch_bounds__(256)
void scan_state_kernel(const bf16* __restrict__ xact, const float* __restrict__ dts,
                       const float* __restrict__ ldab, bf16* __restrict__ Sbuf,
                       float* __restrict__ acb)
{
  __shared__ __align__(16) bf16 wBT[64][72];
  __shared__ __align__(16) bf16 XT[64][72];
  __shared__ float lsS[64], dtS[64];
  const int bid = blockIdx.x;
  const int bh = bid & 63, c = bid >> 6;
  const int b = bh >> 5, h = bh & 31;
  const int t0 = c * TC;
  const int tid = threadIdx.x;
  const int w = tid >> 6, lane = tid & 63;
  const int lr = lane & 15, lq = lane >> 4;

  if (w == 0) {
    float v = ldab[(size_t)(b * SEQ + t0 + lane) * NHEADS + h];
    #pragma unroll
    for (int o = 1; o < 64; o <<= 1) {
      float up = __shfl_up(v, o);
      if (lane >= o) v += up;
    }
    lsS[lane] = v;
    dtS[lane] = dts[(size_t)(b * SEQ + t0 + lane) * NHEADS + h];
  }
  __syncthreads();
  const float lsT = lsS[63];
  {
    int nn = tid & 63, u0 = (tid >> 6) * 16;
    for (int i = 0; i < 16; i++) {
      int u = u0 + i;
      const bf16* rowp = xact + (size_t)(b * SEQ + t0 + u) * CONV_DIM;
      float wgt = dtS[u] * __expf(lsT - lsS[u]);
      wBT[nn][u] = __float2bfloat16(__bfloat162float(rowp[D_INNER + nn]) * wgt);
      XT[nn][u]  = rowp[h * 64 + nn];
    }
  }
  __syncthreads();

  bhalf8 af0 = *(const bhalf8*)&wBT[16 * w + lr][lq * 8];
  bhalf8 af1 = *(const bhalf8*)&wBT[16 * w + lr][32 + lq * 8];
  bf16* sb = Sbuf + ((size_t)bh * NCH + c) * 4096;
  #pragma unroll
  for (int jt = 0; jt < 4; jt++) {
    bhalf8 xf0 = *(const bhalf8*)&XT[16 * jt + lr][lq * 8];
    bhalf8 xf1 = *(const bhalf8*)&XT[16 * jt + lr][32 + lq * 8];
    f32x4 acc = (f32x4){0.f, 0.f, 0.f, 0.f};
    acc = __builtin_amdgcn_mfma_f32_16x16x32_bf16(af0, xf0, acc, 0, 0, 0);
    acc = __builtin_amdgcn_mfma_f32_16x16x32_bf16(af1, xf1, acc, 0, 0, 0);
    #pragma unroll
    for (int r = 0; r < 4; r++) {
      int n = 16 * w + lq * 4 + r;
      int p = 16 * jt + lr;
      sb[p * 64 + n] = __float2bfloat16(acc[r]);
    }
  }
  if (tid == 0) acb[bh * NCH + c] = __expf(lsT);
}

// ---------------------------------------------------------------------------
// Pass 2: serial inter-chunk propagation (in-place).
// ---------------------------------------------------------------------------
__global__ __launch_bounds__(256)
void state_prop_kernel(bf16* __restrict__ Sbuf, const float* __restrict__ acb)
{
  const int bh = blockIdx.x >> 2, q = blockIdx.x & 3;
  const int t = threadIdx.x;
  bf16* sp = Sbuf + (size_t)bh * NCH * 4096 + q * 1024 + t;
  const float* ap = acb + bh * NCH;
  float h0 = 0.f, h1 = 0.f, h2 = 0.f, h3 = 0.f;
  for (int c = 0; c < NCH; c++) {
    bf16* pc = sp + (size_t)c * 4096;
    float s0 = __bfloat162float(pc[0]);
    float s1 = __bfloat162float(pc[256]);
    float s2 = __bfloat162float(pc[512]);
    float s3 = __bfloat162float(pc[768]);
    float a = ap[c];
    pc[0]   = __float2bfloat16(h0);
    pc[256] = __float2bfloat16(h1);
    pc[512] = __float2bfloat16(h2);
    pc[768] = __float2bfloat16(h3);
    h0 = fmaf(h0, a, s0); h1 = fmaf(h1, a, s1);
    h2 = fmaf(h2, a, s2); h3 = fmaf(h3, a, s3);
  }
}

// ---------------------------------------------------------------------------
// MFMA chunk scan, pass 3.
// ---------------------------------------------------------------------------
__global__ __launch_bounds__(256)
void scan_y_kernel(const bf16* __restrict__ xact, const float* __restrict__ dts,
                   const float* __restrict__ ldab, const bf16* __restrict__ Sbuf,
                   bf16* __restrict__ yfull)
{
  __shared__ __align__(16) bf16 Cs[64][72];
  __shared__ __align__(16) bf16 Bs[64][72];
  __shared__ __align__(16) bf16 XT[64][72];
  __shared__ __align__(16) bf16 HT[64][72];
  __shared__ __align__(16) bf16 Ms[64][72];
  __shared__ float lsS[64], dtS[64];
  const int bid = blockIdx.x;
  const int bh = bid & 63, c = bid >> 6;
  const int b = bh >> 5, h = bh & 31;
  const int t0 = c * TC;
  const int tid = threadIdx.x;
  const int w = tid >> 6, lane = tid & 63;
  const int lr = lane & 15, lq = lane >> 4;

  if (w == 0) {
    float v = ldab[(size_t)(b * SEQ + t0 + lane) * NHEADS + h];
    #pragma unroll
    for (int o = 1; o < 64; o <<= 1) {
      float up = __shfl_up(v, o);
      if (lane >= o) v += up;
    }
    lsS[lane] = v;
    dtS[lane] = dts[(size_t)(b * SEQ + t0 + lane) * NHEADS + h];
  }
  {
    int nn = tid & 63, u0 = (tid >> 6) * 16;
    for (int i = 0; i < 16; i++) {
      int u = u0 + i;
      const bf16* rowp = xact + (size_t)(b * SEQ + t0 + u) * CONV_DIM;
      Bs[u][nn] = rowp[D_INNER + nn];
      Cs[u][nn] = rowp[D_INNER + 64 + nn];
      XT[nn][u] = rowp[h * 64 + nn];
    }
    const bf16* sb = Sbuf + ((size_t)bh * NCH + c) * 4096;
    for (int i = 0; i < 16; i++) {
      int e = tid + 256 * i;
      HT[e >> 6][e & 63] = sb[e];
    }
  }
  __syncthreads();

  bhalf8 cf0 = *(const bhalf8*)&Cs[16 * w + lr][lq * 8];
  bhalf8 cf1 = *(const bhalf8*)&Cs[16 * w + lr][32 + lq * 8];
  f32x4 accH[4];
  #pragma unroll
  for (int jt = 0; jt < 4; jt++) {
    bhalf8 bf0 = *(const bhalf8*)&Bs[16 * jt + lr][lq * 8];
    bhalf8 bf1 = *(const bhalf8*)&Bs[16 * jt + lr][32 + lq * 8];
    f32x4 g = (f32x4){0.f, 0.f, 0.f, 0.f};
    g = __builtin_amdgcn_mfma_f32_16x16x32_bf16(cf0, bf0, g, 0, 0, 0);
    g = __builtin_amdgcn_mfma_f32_16x16x32_bf16(cf1, bf1, g, 0, 0, 0);
    bhalf8 hf0 = *(const bhalf8*)&HT[16 * jt + lr][lq * 8];
    bhalf8 hf1 = *(const bhalf8*)&HT[16 * jt + lr][32 + lq * 8];
    f32x4 ah = (f32x4){0.f, 0.f, 0.f, 0.f};
    ah = __builtin_amdgcn_mfma_f32_16x16x32_bf16(cf0, hf0, ah, 0, 0, 0);
    ah = __builtin_amdgcn_mfma_f32_16x16x32_bf16(cf1, hf1, ah, 0, 0, 0);
    accH[jt] = ah;
    #pragma unroll
    for (int r = 0; r < 4; r++) {
      int t = 16 * w + lq * 4 + r;
      int u = 16 * jt + lr;
      float m = 0.f;
      if (u <= t) m = g[r] * __expf(lsS[t] - lsS[u]) * dtS[u];
      Ms[t][u] = __float2bfloat16(m);
    }
  }
  __syncthreads();

  bhalf8 mf0 = *(const bhalf8*)&Ms[16 * w + lr][lq * 8];
  bhalf8 mf1 = *(const bhalf8*)&Ms[16 * w + lr][32 + lq * 8];
  #pragma unroll
  for (int jt = 0; jt < 4; jt++) {
    bhalf8 xf0 = *(const bhalf8*)&XT[16 * jt + lr][lq * 8];
    bhalf8 xf1 = *(const bhalf8*)&XT[16 * jt + lr][32 + lq * 8];
    f32x4 acc = (f32x4){0.f, 0.f, 0.f, 0.f};
    acc = __builtin_amdgcn_mfma_f32_16x16x32_bf16(mf0, xf0, acc, 0, 0, 0);
    acc = __builtin_amdgcn_mfma_f32_16x16x32_bf16(mf1, xf1, acc, 0, 0, 0);
    #pragma unroll
    for (int r = 0; r < 4; r++) {
      int t = 16 * w + lq * 4 + r;
      int p = 16 * jt + lr;
      float y = acc[r] + __expf(lsS[t]) * accH[jt][r];
      yfull[(size_t)(b * SEQ + t0 + t) * D_INNER + h * 64 + p] = __float2bfloat16(y);
    }
  }
}

// ---------------------------------------------------------------------------
// y = yfull + D*x;  y *= silu(z);  RMSNorm * norm_w -> bf16.
// ---------------------------------------------------------------------------
__global__ __launch_bounds__(256)
void gate_rms_kernel(const bf16* __restrict__ yfull, const bf16* __restrict__ xact,
                     const bf16* __restrict__ zxb, const bf16* __restrict__ Dp,
                     const bf16* __restrict__ nw, bf16* __restrict__ yn)
{
  int row = blockIdx.x, t = threadIdx.x;
  __shared__ float rq[4];
  float yv[8]; float ss = 0.f;
  #pragma unroll
  for (int i = 0; i < 8; i++) {
    int c = t + 256 * i;
    float y = __bfloat162float(yfull[(size_t)row * D_INNER + c]) +
              __bfloat162float(Dp[c >> 6]) *
              __bfloat162float(xact[(size_t)row * CONV_DIM + c]);
    float z = __bfloat162float(zxb[(size_t)row * D_IN_PROJ + c]);
    yv[i] = y * (z / (1.f + expf(-z)));
    ss += yv[i] * yv[i];
  }
  #pragma unroll
  for (int o = 32; o; o >>= 1) ss += __shfl_down(ss, o);
  if ((t & 63) == 0) rq[t >> 6] = ss;
  __syncthreads();
  float tot = rq[0] + rq[1] + rq[2] + rq[3];
  float rr = rsqrtf(tot * (1.f / D_INNER) + 1e-5f);
  #pragma unroll
  for (int i = 0; i < 8; i++) {
    int c = t + 256 * i;
    yn[(size_t)row * D_INNER + c] =
        __float2bfloat16(yv[i] * rr * __bfloat162float(nw[c]));
  }
}

// ---------------------------------------------------------------------------
extern "C" void kernel_launch(void* const* d_in, const int* in_sizes, int n_in,
                              void* d_out, int out_size, void* d_ws, size_t ws_size,
                              hipStream_t stream)
{
  char* ws = (char*)d_ws;
  bf16*  x1b   = (bf16*) (ws + 0);           //  [3->4]
  bf16*  Sbuf  = (bf16*) (ws + 0);           //  [7->9]   alias x1b (dead @4)
  bf16*  ynb   = (bf16*) (ws + 0);           //  [10->11] alias Sbuf
  float* pf0   = (float*)(ws + 0);           //  [14->14b] alias ynb
  bf16*  wproj = (bf16*) (ws + 16777216);    //  [2->4]
  float* acb   = (float*)(ws + 16777216);    //  [7->8]   alias wproj
  float* dtsb  = (float*)(ws + 16785408);    //  [5->9]   alias wproj
  float* ldab  = (float*)(ws + 17309696);    //  [5->9]   alias wproj
  float* pf1   = (float*)(ws + 16777216);    //  [14->14b] alias wproj region
  bf16*  wout  = (bf16*) (ws + 25493504);    //  [2->11]
  bf16*  w1c   = (bf16*) (ws + 29687808);    //  [2->13]
  bf16*  w2c   = (bf16*) (ws + 38076416);    //  [2->14]
  bf16*  ln0w  = (bf16*) (ws + 46465024);
  bf16*  ln0b  = (bf16*) (ws + 46467072);
  bf16*  ln1w  = (bf16*) (ws + 46469120);
  bf16*  ln1b  = (bf16*) (ws + 46471168);
  bf16*  ln2w  = (bf16*) (ws + 46473216);
  bf16*  ln2b  = (bf16*) (ws + 46475264);
  bf16*  convw = (bf16*) (ws + 46477312);
  bf16*  convb = (bf16*) (ws + 46494720);
  bf16*  dtb   = (bf16*) (ws + 46499072);
  bf16*  alog  = (bf16*) (ws + 46499136);
  bf16*  Dp    = (bf16*) (ws + 46499200);
  bf16*  normw = (bf16*) (ws + 46499264);
  bf16*  b1c   = (bf16*) (ws + 46503360);
  bf16*  b2c   = (bf16*) (ws + 46511552);
  int*   flag  = (int*)  (ws + 46513600);
  bf16*  x0b   = (bf16*) (ws + 46514176);    //  [3->11b]
  bf16*  zxb   = (bf16*) (ws + 54902784);    //  [4->10]
  float* x2f   = (float*)(ws + 54902784);    //  [11b->14b] alias zxb
  bf16*  xact  = (bf16*) (ws + 89767936);    //  [5->10]
  float* pout0 = (float*)(ws + 89767936);    //  [11->11b] alias xact
  float* pout1 = (float*)(ws + 106545152);   //  [11->11b]
  bf16*  gbuf  = (bf16*) (ws + 89767936);    //  [13->14] alias xact region
  bf16*  yfull = (bf16*) (ws + 125419520);   //  [9->10]
  bf16*  hln   = (bf16*) (ws + 125419520);   //  [11b->13] alias yfull

  detect_kernel<<<1, 64, 0, stream>>>((const unsigned short*)d_in[0], flag);

  CvtArgs ca;
  void* dsts[NT] = { ln0w, ln0b, ln1w, ln1b, ln2w, ln2b, wproj, convw, convb,
                     dtb, alog, Dp, normw, wout, w1c, b1c, w2c, b2c };
  int cc = 0;
  ca.ccum[0] = 0;
  for (int i = 0; i < NT; i++) {
    ca.src[i] = d_in[i + 1];
    ca.dst[i] = dsts[i];
    ca.nel[i] = in_sizes[i + 1];
    cc += (in_sizes[i + 1] + 2047) / 2048;
    ca.ccum[i + 1] = cc;
  }
  cvt_kernel<<<cc, 256, 0, stream>>>(ca, flag);

  ln01_kernel<<<NROWS, 256, 0, stream>>>(d_in[0], flag, ln0w, ln0b, ln1w, ln1b,
                                         x0b, x1b);

  gemm_bt<0><<<dim3(34, 32), 256, 0, stream>>>(x1b, wproj, NROWS, D_IN_PROJ, D_MODEL,
                                               zxb, nullptr);

  conv_silu_dt_kernel<<<dim3(9, NROWS), 256, 0, stream>>>(zxb, convw, convb, xact,
                                                          dtb, alog, dtsb, ldab);

  scan_state_kernel<<<NCH * 64, 256, 0, stream>>>(xact, dtsb, ldab, Sbuf, acb);
  state_prop_kernel<<<64 * 4, 256, 0, stream>>>(Sbuf, acb);
  scan_y_kernel<<<NCH * 64, 256, 0, stream>>>(xact, dtsb, ldab, Sbuf, yfull);

  gate_rms_kernel<<<NROWS, 256, 0, stream>>>(yfull, xact, zxb, Dp, normw, ynb);

  // out_proj: 64x128 split-K=2 -> partials, then fused reduce+residual+ln2
  gemm_skinny_sk<<<1024, 256, 0, stream>>>(ynb, wout, NROWS, D_MODEL, D_INNER,
                                           pout0, pout1);
  reduce_out_ln2_kernel<<<NROWS, 256, 0, stream>>>(pout0, pout1, x0b, x2f,
                                                   ln2w, ln2b, hln);

  gemm_bt<2><<<dim3(32, 32), 256, 0, stream>>>(hln, w1c, NROWS, FFN_DIM, D_MODEL,
                                               gbuf, b1c);

  // ffn2: 64x128 split-K=2 -> partials, then fused reduce(+bias+residual)
  gemm_skinny_sk<<<1024, 256, 0, stream>>>(gbuf, w2c, NROWS, D_MODEL, FFN_DIM,
                                           pf0, pf1);
  reduce_ffn_kernel<<<(NROWS * D_MODEL) / 1024, 256, 0, stream>>>(pf0, pf1,
                                                                  b2c, x2f, d_out, flag);
}

// Round 11
// 415.229 us; speedup vs baseline: 4.6156x; 1.0853x over previous
//
#include <hip/hip_runtime.h>
#include <hip/hip_bf16.h>
#include <math.h>

typedef __hip_bfloat16 bf16;
typedef __bf16 bhalf;
typedef bhalf bhalf8 __attribute__((ext_vector_type(8)));
typedef float f32x4 __attribute__((ext_vector_type(4)));
typedef unsigned short u16;
typedef u16 u16x4 __attribute__((ext_vector_type(4)));
typedef u16 u16x8 __attribute__((ext_vector_type(8)));

#define D_MODEL   1024
#define D_STATE   64
#define HEADDIM   64
#define D_INNER   2048
#define NHEADS    32
#define CONV_DIM  2176
#define D_IN_PROJ 4256
#define FFN_DIM   4096
#define BSZ       2
#define SEQ       2048
#define NROWS     (BSZ*SEQ)
#define TC        64
#define NCH       (SEQ/TC)

#define AS1 __attribute__((address_space(1)))
#define AS3 __attribute__((address_space(3)))
__device__ __forceinline__ void load_lds16(const void* g, void* l) {
  __builtin_amdgcn_global_load_lds((AS1 void*)g, (AS3 void*)l, 16, 0, 0);
}

__device__ __forceinline__ float bf2f(u16 u) {
  return __uint_as_float(((unsigned)u) << 16);
}
__device__ __forceinline__ u16 f2bbits(float f) {
  bf16 h = __float2bfloat16(f);
  return *(u16*)&h;
}

// ---------------------------------------------------------------------------
// Input dtype detection (inputs proven fp32 => flag=1; kept for robustness).
// ---------------------------------------------------------------------------
__global__ __launch_bounds__(64)
void detect_kernel(const unsigned short* __restrict__ x, int* __restrict__ flagp)
{
  int bad = 0;
  for (int i = threadIdx.x; i < 4096; i += 64) {
    unsigned u = ((unsigned)x[i]) << 16;
    float v = __uint_as_float(u);
    if (!(fabsf(v) <= 1e6f)) bad = 1;
  }
  unsigned long long any = __ballot(bad);
  if (threadIdx.x == 0) *flagp = (any != 0ULL) ? 1 : 0;
}

// ---------------------------------------------------------------------------
// Normalize weight inputs to bf16 copies; vectorized (8 elems/thread, 1 pass).
// All tensor sizes are divisible by 8; all dst offsets 16B-aligned.
// ---------------------------------------------------------------------------
#define NT 18
struct CvtArgs {
  const void* src[NT];
  void*       dst[NT];
  int ccum[NT + 1];
  int nel[NT];
};

__global__ __launch_bounds__(256)
void cvt_kernel(CvtArgs a, const int* __restrict__ flagp)
{
  int c = blockIdx.x;
  int ti = 0;
  while (c >= a.ccum[ti + 1]) ti++;
  int j = (c - a.ccum[ti]) * 2048 + threadIdx.x * 8;
  if (j >= a.nel[ti]) return;
  if (*flagp) {
    const float* s = (const float*)a.src[ti];
    f32x4 v0 = *(const f32x4*)(s + j);
    f32x4 v1 = *(const f32x4*)(s + j + 4);
    u16x8 o;
    #pragma unroll
    for (int k = 0; k < 4; k++) { o[k] = f2bbits(v0[k]); o[k + 4] = f2bbits(v1[k]); }
    *(u16x8*)((u16*)a.dst[ti] + j) = o;
  } else {
    *(u16x8*)((u16*)a.dst[ti] + j) = *(const u16x8*)((const u16*)a.src[ti] + j);
  }
}

// ---------------------------------------------------------------------------
// GEMM 128x128, BK=64, XOR-swizzled LDS. 2D grid dim3(nb, M/128) — the
// round-7/10-proven dispatch order (n fastest).
// EPI 0: store bf16   EPI 2: store bf16(gelu(acc+bias))
// ---------------------------------------------------------------------------
template<int EPI>
__global__ __launch_bounds__(256, 2)
void gemm_bt(const bf16* __restrict__ A, const bf16* __restrict__ W,
             int M, int N, int K,
             bf16* __restrict__ outB,
             const bf16* __restrict__ bias)
{
  __shared__ __align__(16) bhalf sA[128 * 64];
  __shared__ __align__(16) bhalf sW[128 * 64];
  const int n0   = blockIdx.x * 128;
  const int m0   = blockIdx.y * 128;
  const int t    = threadIdx.x;
  const int w    = t >> 6;
  const int lane = t & 63;
  const int wm   = (w >> 1) * 64;
  const int wn   = (w & 1) * 64;
  const int lr   = lane & 15;
  const int lq   = lane >> 4;

  f32x4 acc[4][4];
  #pragma unroll
  for (int i = 0; i < 4; i++)
    #pragma unroll
    for (int j = 0; j < 4; j++)
      acc[i][j] = (f32x4){0.f, 0.f, 0.f, 0.f};

  for (int k0 = 0; k0 < K; k0 += 64) {
    #pragma unroll
    for (int j = 0; j < 4; j++) {
      int s  = t + 256 * j;
      int r  = s >> 3;
      int cs = (s & 7) ^ (r & 7);
      load_lds16(A + (size_t)(m0 + r) * K + k0 + cs * 8, sA + s * 8);
      int wr = n0 + r; wr = wr < N ? wr : N - 1;
      load_lds16(W + (size_t)wr * K + k0 + cs * 8, sW + s * 8);
    }
    __syncthreads();
    #pragma unroll
    for (int kk = 0; kk < 2; kk++) {
      bhalf8 af[4], bfr[4];
      #pragma unroll
      for (int i = 0; i < 4; i++) {
        int r = wm + i * 16 + lr;
        int c = (kk * 4 + lq) ^ (r & 7);
        af[i] = *(const bhalf8*)(sA + r * 64 + c * 8);
      }
      #pragma unroll
      for (int j = 0; j < 4; j++) {
        int r = wn + j * 16 + lr;
        int c = (kk * 4 + lq) ^ (r & 7);
        bfr[j] = *(const bhalf8*)(sW + r * 64 + c * 8);
      }
      #pragma unroll
      for (int i = 0; i < 4; i++)
        #pragma unroll
        for (int j = 0; j < 4; j++)
          acc[i][j] = __builtin_amdgcn_mfma_f32_16x16x32_bf16(af[i], bfr[j], acc[i][j], 0, 0, 0);
    }
    __syncthreads();
  }

  #pragma unroll
  for (int i = 0; i < 4; i++) {
    #pragma unroll
    for (int j = 0; j < 4; j++) {
      #pragma unroll
      for (int r = 0; r < 4; r++) {
        int m = m0 + wm + i * 16 + lq * 4 + r;
        int n = n0 + wn + j * 16 + lr;
        if (n < N) {
          float v = acc[i][j][r];
          size_t idx = (size_t)m * N + n;
          if (EPI == 0) {
            outB[idx] = __float2bfloat16(v);
          } else {
            v += __bfloat162float(bias[n]);
            outB[idx] = __float2bfloat16(0.5f * v * (1.0f + erff(v * 0.70710678118654752f)));
          }
        }
      }
    }
  }
}

// ---------------------------------------------------------------------------
// Skinny GEMM 64x128 tile, split-K=2 (N=1024): 1024 blocks (4/CU),
// fp32 partials; epilogues live in the reduce kernels.
// ---------------------------------------------------------------------------
__global__ __launch_bounds__(256, 4)
void gemm_skinny_sk(const bf16* __restrict__ A, const bf16* __restrict__ W,
                    int M, int N, int K,
                    float* __restrict__ p0, float* __restrict__ p1)
{
  __shared__ __align__(16) bhalf sA[64 * 64];
  __shared__ __align__(16) bhalf sW[128 * 64];
  const int id   = blockIdx.x;
  const int z    = id >> 9;
  const int id9  = id & 511;
  const int hi   = id9 >> 6;
  const int rem  = id9 & 63;
  const int jn   = rem >> 3;
  const int mi   = hi * 8 + (rem & 7);
  const int m0   = mi * 64;
  const int n0   = jn * 128;
  const int t    = threadIdx.x;
  const int w    = t >> 6;
  const int lane = t & 63;
  const int wm   = (w >> 1) * 32;
  const int wn   = (w & 1) * 64;
  const int lr   = lane & 15;
  const int lq   = lane >> 4;

  f32x4 acc[2][4];
  #pragma unroll
  for (int i = 0; i < 2; i++)
    #pragma unroll
    for (int j = 0; j < 4; j++)
      acc[i][j] = (f32x4){0.f, 0.f, 0.f, 0.f};

  const int kh = K >> 1;
  const int kend = z * kh + kh;
  for (int k0 = z * kh; k0 < kend; k0 += 64) {
    #pragma unroll
    for (int j = 0; j < 2; j++) {
      int s  = t + 256 * j;
      int r  = s >> 3;
      int cs = (s & 7) ^ (r & 7);
      load_lds16(A + (size_t)(m0 + r) * K + k0 + cs * 8, sA + s * 8);
    }
    #pragma unroll
    for (int j = 0; j < 4; j++) {
      int s  = t + 256 * j;
      int r  = s >> 3;
      int cs = (s & 7) ^ (r & 7);
      load_lds16(W + (size_t)(n0 + r) * K + k0 + cs * 8, sW + s * 8);
    }
    __syncthreads();
    #pragma unroll
    for (int kk = 0; kk < 2; kk++) {
      bhalf8 af[2], bfr[4];
      #pragma unroll
      for (int i = 0; i < 2; i++) {
        int r = wm + i * 16 + lr;
        int c = (kk * 4 + lq) ^ (r & 7);
        af[i] = *(const bhalf8*)(sA + r * 64 + c * 8);
      }
      #pragma unroll
      for (int j = 0; j < 4; j++) {
        int r = wn + j * 16 + lr;
        int c = (kk * 4 + lq) ^ (r & 7);
        bfr[j] = *(const bhalf8*)(sW + r * 64 + c * 8);
      }
      #pragma unroll
      for (int i = 0; i < 2; i++)
        #pragma unroll
        for (int j = 0; j < 4; j++)
          acc[i][j] = __builtin_amdgcn_mfma_f32_16x16x32_bf16(af[i], bfr[j], acc[i][j], 0, 0, 0);
    }
    __syncthreads();
  }

  float* out = z ? p1 : p0;
  #pragma unroll
  for (int i = 0; i < 2; i++)
    #pragma unroll
    for (int j = 0; j < 4; j++)
      #pragma unroll
      for (int r = 0; r < 4; r++) {
        int m = m0 + wm + i * 16 + lq * 4 + r;
        int n = n0 + wn + j * 16 + lr;
        out[(size_t)m * N + n] = acc[i][j][r];
      }
}

// ---------------------------------------------------------------------------
// out_proj reduce + residual + FULL ln2, one block per row:
//   x2f = p0 + p1 + resB;  hln = LN(x2f)*w+b (bf16)
// ---------------------------------------------------------------------------
__global__ __launch_bounds__(256)
void reduce_out_ln2_kernel(const float* __restrict__ p0, const float* __restrict__ p1,
                           const bf16* __restrict__ resB, float* __restrict__ x2f,
                           const bf16* __restrict__ w, const bf16* __restrict__ b,
                           bf16* __restrict__ hln)
{
  int row = blockIdx.x, t = threadIdx.x;
  int i = row * 256 + t;
  __shared__ float rs[4], rq[4];
  f32x4 a = ((const f32x4*)p0)[i];
  f32x4 bb = ((const f32x4*)p1)[i];
  u16x4 r = ((const u16x4*)resB)[i];
  f32x4 o;
  float s = 0.f, ss = 0.f;
  #pragma unroll
  for (int j = 0; j < 4; j++) {
    o[j] = a[j] + bb[j] + bf2f(r[j]);
    s += o[j]; ss += o[j] * o[j];
  }
  ((f32x4*)x2f)[i] = o;
  #pragma unroll
  for (int off = 32; off; off >>= 1) { s += __shfl_down(s, off); ss += __shfl_down(ss, off); }
  if ((t & 63) == 0) { rs[t >> 6] = s; rq[t >> 6] = ss; }
  __syncthreads();
  float S = rs[0] + rs[1] + rs[2] + rs[3];
  float Q = rq[0] + rq[1] + rq[2] + rq[3];
  float mean = S * (1.f / D_MODEL);
  float rstd = rsqrtf(Q * (1.f / D_MODEL) - mean * mean + 1e-5f);
  u16x4 wv = ((const u16x4*)w)[t];
  u16x4 bv = ((const u16x4*)b)[t];
  u16x4 ov;
  #pragma unroll
  for (int j = 0; j < 4; j++)
    ov[j] = f2bbits((o[j] - mean) * rstd * bf2f(wv[j]) + bf2f(bv[j]));
  ((u16x4*)hln)[i] = ov;
}

// ---------------------------------------------------------------------------
// ffn2 reduce: d_out = p0+p1 + bias + resF (dtype per flag)
// ---------------------------------------------------------------------------
__global__ __launch_bounds__(256)
void reduce_ffn_kernel(const float* __restrict__ p0, const float* __restrict__ p1,
                       const bf16* __restrict__ bias, const float* __restrict__ resF,
                       void* __restrict__ outp, const int* __restrict__ flagp)
{
  int i = blockIdx.x * 256 + threadIdx.x;
  int n4 = i & (D_MODEL / 4 - 1);
  f32x4 v0 = ((const f32x4*)p0)[i];
  f32x4 v1 = ((const f32x4*)p1)[i];
  f32x4 rf = ((const f32x4*)resF)[i];
  u16x4 bb = ((const u16x4*)bias)[n4];
  f32x4 o;
  #pragma unroll
  for (int j = 0; j < 4; j++)
    o[j] = v0[j] + v1[j] + rf[j] + bf2f(bb[j]);
  if (*flagp) {
    ((f32x4*)outp)[i] = o;
  } else {
    u16x4 ov;
    #pragma unroll
    for (int j = 0; j < 4; j++) ov[j] = f2bbits(o[j]);
    ((u16x4*)outp)[i] = ov;
  }
}

// ---------------------------------------------------------------------------
// Fused ln0 + ln1; reads x directly from d_in (fp32/bf16 per flag); float4.
// ---------------------------------------------------------------------------
__global__ __launch_bounds__(256)
void ln01_kernel(const void* __restrict__ xin, const int* __restrict__ flagp,
                 const bf16* __restrict__ w0, const bf16* __restrict__ b0,
                 const bf16* __restrict__ w1, const bf16* __restrict__ b1,
                 bf16* __restrict__ x0o, bf16* __restrict__ x1o)
{
  int row = blockIdx.x, t = threadIdx.x;
  int i = row * 256 + t;
  __shared__ float rs[4], rq[4];
  float v[4], s = 0.f, ss = 0.f;
  if (*flagp) {
    f32x4 xv = ((const f32x4*)xin)[i];
    #pragma unroll
    for (int j = 0; j < 4; j++) v[j] = xv[j];
  } else {
    u16x4 xv = ((const u16x4*)xin)[i];
    #pragma unroll
    for (int j = 0; j < 4; j++) v[j] = bf2f(xv[j]);
  }
  #pragma unroll
  for (int j = 0; j < 4; j++) { s += v[j]; ss += v[j] * v[j]; }
  #pragma unroll
  for (int o = 32; o; o >>= 1) { s += __shfl_down(s, o); ss += __shfl_down(ss, o); }
  if ((t & 63) == 0) { rs[t >> 6] = s; rq[t >> 6] = ss; }
  __syncthreads();
  float S = rs[0] + rs[1] + rs[2] + rs[3];
  float Q = rq[0] + rq[1] + rq[2] + rq[3];
  float mean = S * (1.f / D_MODEL);
  float rstd = rsqrtf(Q * (1.f / D_MODEL) - mean * mean + 1e-5f);
  u16x4 w0v = ((const u16x4*)w0)[t], b0v = ((const u16x4*)b0)[t];
  float u[4]; s = 0.f; ss = 0.f;
  u16x4 o0;
  #pragma unroll
  for (int j = 0; j < 4; j++) {
    u[j] = (v[j] - mean) * rstd * bf2f(w0v[j]) + bf2f(b0v[j]);
    s += u[j]; ss += u[j] * u[j];
    o0[j] = f2bbits(u[j]);
  }
  ((u16x4*)x0o)[i] = o0;
  __syncthreads();
  #pragma unroll
  for (int o = 32; o; o >>= 1) { s += __shfl_down(s, o); ss += __shfl_down(ss, o); }
  if ((t & 63) == 0) { rs[t >> 6] = s; rq[t >> 6] = ss; }
  __syncthreads();
  S = rs[0] + rs[1] + rs[2] + rs[3];
  Q = rq[0] + rq[1] + rq[2] + rq[3];
  mean = S * (1.f / D_MODEL);
  rstd = rsqrtf(Q * (1.f / D_MODEL) - mean * mean + 1e-5f);
  u16x4 w1v = ((const u16x4*)w1)[t], b1v = ((const u16x4*)b1)[t];
  u16x4 o1;
  #pragma unroll
  for (int j = 0; j < 4; j++)
    o1[j] = f2bbits((u[j] - mean) * rstd * bf2f(w1v[j]) + bf2f(b1v[j]));
  ((u16x4*)x1o)[i] = o1;
}

// ---------------------------------------------------------------------------
// Causal depthwise conv (k=4) + SiLU -> bf16 xact, vectorized 8 ch/thread.
// Grid dim3(2, NROWS): block.x=0 -> ch 0..2047; block.x=1 t<16 -> ch
// 2048..2175, t in [16,48) -> dt/lda for head t-16.
// ---------------------------------------------------------------------------
__device__ __forceinline__ void conv8(const bf16* __restrict__ zxb,
                                      const bf16* __restrict__ cw,
                                      const bf16* __restrict__ cb,
                                      bf16* __restrict__ xact, int row, int c0)
{
  int l = row & (SEQ - 1);
  float acc[8];
  {
    bhalf8 cbv = *(const bhalf8*)(cb + c0);
    #pragma unroll
    for (int j = 0; j < 8; j++) acc[j] = (float)cbv[j];
  }
  bhalf wts[32];
  #pragma unroll
  for (int q = 0; q < 4; q++)
    *(bhalf8*)(wts + q * 8) = *(const bhalf8*)(cw + c0 * 4 + q * 8);
  #pragma unroll
  for (int k = 0; k < 4; k++) {
    int lt = l - 3 + k;
    if (lt >= 0) {
      bhalf8 xv = *(const bhalf8*)(zxb + (size_t)(row - 3 + k) * D_IN_PROJ + D_INNER + c0);
      #pragma unroll
      for (int j = 0; j < 8; j++)
        acc[j] = fmaf((float)xv[j], (float)wts[j * 4 + k], acc[j]);
    }
  }
  bhalf8 o;
  #pragma unroll
  for (int j = 0; j < 8; j++) {
    float a = acc[j];
    o[j] = (bhalf)(a / (1.f + expf(-a)));
  }
  *(bhalf8*)(xact + (size_t)row * CONV_DIM + c0) = o;
}

__global__ __launch_bounds__(256)
void conv_silu_dt_kernel(const bf16* __restrict__ zxb, const bf16* __restrict__ cw,
                         const bf16* __restrict__ cb, bf16* __restrict__ xact,
                         const bf16* __restrict__ dtb, const bf16* __restrict__ alog,
                         float* __restrict__ dts, float* __restrict__ ldab)
{
  const int row = blockIdx.y;
  const int t = threadIdx.x;
  if (blockIdx.x == 0) {
    conv8(zxb, cw, cb, xact, row, t * 8);
  } else {
    if (t < 16) {
      conv8(zxb, cw, cb, xact, row, 2048 + t * 8);
    } else if (t < 48) {
      int h = t - 16;
      float v = __bfloat162float(zxb[(size_t)row * D_IN_PROJ + (D_INNER + CONV_DIM) + h]) +
                __bfloat162float(dtb[h]);
      float sp = (v > 20.f) ? v : log1pf(expf(v));
      dts[row * NHEADS + h] = sp;
      ldab[row * NHEADS + h] = -sp * expf(__bfloat162float(alog[h]));
    }
  }
}

// ---------------------------------------------------------------------------
// MFMA chunk scan, pass 1 (chunk states).
// ---------------------------------------------------------------------------
__global__ __launch_bounds__(256)
void scan_state_kernel(const bf16* __restrict__ xact, const float* __restrict__ dts,
                       const float* __restrict__ ldab, bf16* __restrict__ Sbuf,
                       float* __restrict__ acb)
{
  __shared__ __align__(16) bf16 wBT[64][72];
  __shared__ __align__(16) bf16 XT[64][72];
  __shared__ float lsS[64], dtS[64];
  const int bid = blockIdx.x;
  const int bh = bid & 63, c = bid >> 6;
  const int b = bh >> 5, h = bh & 31;
  const int t0 = c * TC;
  const int tid = threadIdx.x;
  const int w = tid >> 6, lane = tid & 63;
  const int lr = lane & 15, lq = lane >> 4;

  if (w == 0) {
    float v = ldab[(size_t)(b * SEQ + t0 + lane) * NHEADS + h];
    #pragma unroll
    for (int o = 1; o < 64; o <<= 1) {
      float up = __shfl_up(v, o);
      if (lane >= o) v += up;
    }
    lsS[lane] = v;
    dtS[lane] = dts[(size_t)(b * SEQ + t0 + lane) * NHEADS + h];
  }
  __syncthreads();
  const float lsT = lsS[63];
  {
    int nn = tid & 63, u0 = (tid >> 6) * 16;
    for (int i = 0; i < 16; i++) {
      int u = u0 + i;
      const bf16* rowp = xact + (size_t)(b * SEQ + t0 + u) * CONV_DIM;
      float wgt = dtS[u] * __expf(lsT - lsS[u]);
      wBT[nn][u] = __float2bfloat16(__bfloat162float(rowp[D_INNER + nn]) * wgt);
      XT[nn][u]  = rowp[h * 64 + nn];
    }
  }
  __syncthreads();

  bhalf8 af0 = *(const bhalf8*)&wBT[16 * w + lr][lq * 8];
  bhalf8 af1 = *(const bhalf8*)&wBT[16 * w + lr][32 + lq * 8];
  bf16* sb = Sbuf + ((size_t)bh * NCH + c) * 4096;
  #pragma unroll
  for (int jt = 0; jt < 4; jt++) {
    bhalf8 xf0 = *(const bhalf8*)&XT[16 * jt + lr][lq * 8];
    bhalf8 xf1 = *(const bhalf8*)&XT[16 * jt + lr][32 + lq * 8];
    f32x4 acc = (f32x4){0.f, 0.f, 0.f, 0.f};
    acc = __builtin_amdgcn_mfma_f32_16x16x32_bf16(af0, xf0, acc, 0, 0, 0);
    acc = __builtin_amdgcn_mfma_f32_16x16x32_bf16(af1, xf1, acc, 0, 0, 0);
    #pragma unroll
    for (int r = 0; r < 4; r++) {
      int n = 16 * w + lq * 4 + r;
      int p = 16 * jt + lr;
      sb[p * 64 + n] = __float2bfloat16(acc[r]);
    }
  }
  if (tid == 0) acb[bh * NCH + c] = __expf(lsT);
}

// ---------------------------------------------------------------------------
// Pass 2: serial inter-chunk propagation (in-place).
// ---------------------------------------------------------------------------
__global__ __launch_bounds__(256)
void state_prop_kernel(bf16* __restrict__ Sbuf, const float* __restrict__ acb)
{
  const int bh = blockIdx.x >> 2, q = blockIdx.x & 3;
  const int t = threadIdx.x;
  bf16* sp = Sbuf + (size_t)bh * NCH * 4096 + q * 1024 + t;
  const float* ap = acb + bh * NCH;
  float h0 = 0.f, h1 = 0.f, h2 = 0.f, h3 = 0.f;
  for (int c = 0; c < NCH; c++) {
    bf16* pc = sp + (size_t)c * 4096;
    float s0 = __bfloat162float(pc[0]);
    float s1 = __bfloat162float(pc[256]);
    float s2 = __bfloat162float(pc[512]);
    float s3 = __bfloat162float(pc[768]);
    float a = ap[c];
    pc[0]   = __float2bfloat16(h0);
    pc[256] = __float2bfloat16(h1);
    pc[512] = __float2bfloat16(h2);
    pc[768] = __float2bfloat16(h3);
    h0 = fmaf(h0, a, s0); h1 = fmaf(h1, a, s1);
    h2 = fmaf(h2, a, s2); h3 = fmaf(h3, a, s3);
  }
}

// ---------------------------------------------------------------------------
// MFMA chunk scan, pass 3.
// ---------------------------------------------------------------------------
__global__ __launch_bounds__(256)
void scan_y_kernel(const bf16* __restrict__ xact, const float* __restrict__ dts,
                   const float* __restrict__ ldab, const bf16* __restrict__ Sbuf,
                   bf16* __restrict__ yfull)
{
  __shared__ __align__(16) bf16 Cs[64][72];
  __shared__ __align__(16) bf16 Bs[64][72];
  __shared__ __align__(16) bf16 XT[64][72];
  __shared__ __align__(16) bf16 HT[64][72];
  __shared__ __align__(16) bf16 Ms[64][72];
  __shared__ float lsS[64], dtS[64];
  const int bid = blockIdx.x;
  const int bh = bid & 63, c = bid >> 6;
  const int b = bh >> 5, h = bh & 31;
  const int t0 = c * TC;
  const int tid = threadIdx.x;
  const int w = tid >> 6, lane = tid & 63;
  const int lr = lane & 15, lq = lane >> 4;

  if (w == 0) {
    float v = ldab[(size_t)(b * SEQ + t0 + lane) * NHEADS + h];
    #pragma unroll
    for (int o = 1; o < 64; o <<= 1) {
      float up = __shfl_up(v, o);
      if (lane >= o) v += up;
    }
    lsS[lane] = v;
    dtS[lane] = dts[(size_t)(b * SEQ + t0 + lane) * NHEADS + h];
  }
  {
    int nn = tid & 63, u0 = (tid >> 6) * 16;
    for (int i = 0; i < 16; i++) {
      int u = u0 + i;
      const bf16* rowp = xact + (size_t)(b * SEQ + t0 + u) * CONV_DIM;
      Bs[u][nn] = rowp[D_INNER + nn];
      Cs[u][nn] = rowp[D_INNER + 64 + nn];
      XT[nn][u] = rowp[h * 64 + nn];
    }
    const bf16* sb = Sbuf + ((size_t)bh * NCH + c) * 4096;
    for (int i = 0; i < 16; i++) {
      int e = tid + 256 * i;
      HT[e >> 6][e & 63] = sb[e];
    }
  }
  __syncthreads();

  bhalf8 cf0 = *(const bhalf8*)&Cs[16 * w + lr][lq * 8];
  bhalf8 cf1 = *(const bhalf8*)&Cs[16 * w + lr][32 + lq * 8];
  f32x4 accH[4];
  #pragma unroll
  for (int jt = 0; jt < 4; jt++) {
    bhalf8 bf0 = *(const bhalf8*)&Bs[16 * jt + lr][lq * 8];
    bhalf8 bf1 = *(const bhalf8*)&Bs[16 * jt + lr][32 + lq * 8];
    f32x4 g = (f32x4){0.f, 0.f, 0.f, 0.f};
    g = __builtin_amdgcn_mfma_f32_16x16x32_bf16(cf0, bf0, g, 0, 0, 0);
    g = __builtin_amdgcn_mfma_f32_16x16x32_bf16(cf1, bf1, g, 0, 0, 0);
    bhalf8 hf0 = *(const bhalf8*)&HT[16 * jt + lr][lq * 8];
    bhalf8 hf1 = *(const bhalf8*)&HT[16 * jt + lr][32 + lq * 8];
    f32x4 ah = (f32x4){0.f, 0.f, 0.f, 0.f};
    ah = __builtin_amdgcn_mfma_f32_16x16x32_bf16(cf0, hf0, ah, 0, 0, 0);
    ah = __builtin_amdgcn_mfma_f32_16x16x32_bf16(cf1, hf1, ah, 0, 0, 0);
    accH[jt] = ah;
    #pragma unroll
    for (int r = 0; r < 4; r++) {
      int t = 16 * w + lq * 4 + r;
      int u = 16 * jt + lr;
      float m = 0.f;
      if (u <= t) m = g[r] * __expf(lsS[t] - lsS[u]) * dtS[u];
      Ms[t][u] = __float2bfloat16(m);
    }
  }
  __syncthreads();

  bhalf8 mf0 = *(const bhalf8*)&Ms[16 * w + lr][lq * 8];
  bhalf8 mf1 = *(const bhalf8*)&Ms[16 * w + lr][32 + lq * 8];
  #pragma unroll
  for (int jt = 0; jt < 4; jt++) {
    bhalf8 xf0 = *(const bhalf8*)&XT[16 * jt + lr][lq * 8];
    bhalf8 xf1 = *(const bhalf8*)&XT[16 * jt + lr][32 + lq * 8];
    f32x4 acc = (f32x4){0.f, 0.f, 0.f, 0.f};
    acc = __builtin_amdgcn_mfma_f32_16x16x32_bf16(mf0, xf0, acc, 0, 0, 0);
    acc = __builtin_amdgcn_mfma_f32_16x16x32_bf16(mf1, xf1, acc, 0, 0, 0);
    #pragma unroll
    for (int r = 0; r < 4; r++) {
      int t = 16 * w + lq * 4 + r;
      int p = 16 * jt + lr;
      float y = acc[r] + __expf(lsS[t]) * accH[jt][r];
      yfull[(size_t)(b * SEQ + t0 + t) * D_INNER + h * 64 + p] = __float2bfloat16(y);
    }
  }
}

// ---------------------------------------------------------------------------
// y = yfull + D*x;  y *= silu(z);  RMSNorm * norm_w -> bf16. Vectorized:
// thread t owns contiguous channels c0 = t*8 (8|64 so one head per group).
// ---------------------------------------------------------------------------
__global__ __launch_bounds__(256)
void gate_rms_kernel(const bf16* __restrict__ yfull, const bf16* __restrict__ xact,
                     const bf16* __restrict__ zxb, const bf16* __restrict__ Dp,
                     const bf16* __restrict__ nw, bf16* __restrict__ yn)
{
  int row = blockIdx.x, t = threadIdx.x;
  int c0 = t * 8;
  __shared__ float rq[4];
  bhalf8 yv8 = *(const bhalf8*)(yfull + (size_t)row * D_INNER + c0);
  bhalf8 xv8 = *(const bhalf8*)(xact + (size_t)row * CONV_DIM + c0);
  bhalf8 zv8 = *(const bhalf8*)(zxb + (size_t)row * D_IN_PROJ + c0);
  float Dv = __bfloat162float(Dp[c0 >> 6]);
  float yv[8]; float ss = 0.f;
  #pragma unroll
  for (int j = 0; j < 8; j++) {
    float y = (float)yv8[j] + Dv * (float)xv8[j];
    float z = (float)zv8[j];
    yv[j] = y * (z / (1.f + expf(-z)));
    ss += yv[j] * yv[j];
  }
  #pragma unroll
  for (int o = 32; o; o >>= 1) ss += __shfl_down(ss, o);
  if ((t & 63) == 0) rq[t >> 6] = ss;
  __syncthreads();
  float tot = rq[0] + rq[1] + rq[2] + rq[3];
  float rr = rsqrtf(tot * (1.f / D_INNER) + 1e-5f);
  bhalf8 nv8 = *(const bhalf8*)(nw + c0);
  bhalf8 o;
  #pragma unroll
  for (int j = 0; j < 8; j++)
    o[j] = (bhalf)(yv[j] * rr * (float)nv8[j]);
  *(bhalf8*)(yn + (size_t)row * D_INNER + c0) = o;
}

// ---------------------------------------------------------------------------
extern "C" void kernel_launch(void* const* d_in, const int* in_sizes, int n_in,
                              void* d_out, int out_size, void* d_ws, size_t ws_size,
                              hipStream_t stream)
{
  char* ws = (char*)d_ws;
  bf16*  x1b   = (bf16*) (ws + 0);           //  [3->4]
  bf16*  Sbuf  = (bf16*) (ws + 0);           //  [7->9]   alias x1b (dead @4)
  bf16*  ynb   = (bf16*) (ws + 0);           //  [10->11] alias Sbuf
  float* pf0   = (float*)(ws + 0);           //  [14->14b] alias ynb
  bf16*  wproj = (bf16*) (ws + 16777216);    //  [2->4]
  float* acb   = (float*)(ws + 16777216);    //  [7->8]   alias wproj
  float* dtsb  = (float*)(ws + 16785408);    //  [5->9]   alias wproj
  float* ldab  = (float*)(ws + 17309696);    //  [5->9]   alias wproj
  float* pf1   = (float*)(ws + 16777216);    //  [14->14b] alias wproj region
  bf16*  wout  = (bf16*) (ws + 25493504);    //  [2->11]
  bf16*  w1c   = (bf16*) (ws + 29687808);    //  [2->13]
  bf16*  w2c   = (bf16*) (ws + 38076416);    //  [2->14]
  bf16*  ln0w  = (bf16*) (ws + 46465024);
  bf16*  ln0b  = (bf16*) (ws + 46467072);
  bf16*  ln1w  = (bf16*) (ws + 46469120);
  bf16*  ln1b  = (bf16*) (ws + 46471168);
  bf16*  ln2w  = (bf16*) (ws + 46473216);
  bf16*  ln2b  = (bf16*) (ws + 46475264);
  bf16*  convw = (bf16*) (ws + 46477312);
  bf16*  convb = (bf16*) (ws + 46494720);
  bf16*  dtb   = (bf16*) (ws + 46499072);
  bf16*  alog  = (bf16*) (ws + 46499136);
  bf16*  Dp    = (bf16*) (ws + 46499200);
  bf16*  normw = (bf16*) (ws + 46499264);
  bf16*  b1c   = (bf16*) (ws + 46503360);
  bf16*  b2c   = (bf16*) (ws + 46511552);
  int*   flag  = (int*)  (ws + 46513600);
  bf16*  x0b   = (bf16*) (ws + 46514176);    //  [3->11b]
  bf16*  zxb   = (bf16*) (ws + 54902784);    //  [4->10]
  float* x2f   = (float*)(ws + 54902784);    //  [11b->14b] alias zxb
  bf16*  xact  = (bf16*) (ws + 89767936);    //  [5->10]
  float* pout0 = (float*)(ws + 89767936);    //  [11->11b] alias xact
  float* pout1 = (float*)(ws + 106545152);   //  [11->11b]
  bf16*  gbuf  = (bf16*) (ws + 89767936);    //  [13->14] alias xact region
  bf16*  yfull = (bf16*) (ws + 125419520);   //  [9->10]
  bf16*  hln   = (bf16*) (ws + 125419520);   //  [11b->13] alias yfull

  detect_kernel<<<1, 64, 0, stream>>>((const unsigned short*)d_in[0], flag);

  CvtArgs ca;
  void* dsts[NT] = { ln0w, ln0b, ln1w, ln1b, ln2w, ln2b, wproj, convw, convb,
                     dtb, alog, Dp, normw, wout, w1c, b1c, w2c, b2c };
  int cc = 0;
  ca.ccum[0] = 0;
  for (int i = 0; i < NT; i++) {
    ca.src[i] = d_in[i + 1];
    ca.dst[i] = dsts[i];
    ca.nel[i] = in_sizes[i + 1];
    cc += (in_sizes[i + 1] + 2047) / 2048;
    ca.ccum[i + 1] = cc;
  }
  cvt_kernel<<<cc, 256, 0, stream>>>(ca, flag);

  ln01_kernel<<<NROWS, 256, 0, stream>>>(d_in[0], flag, ln0w, ln0b, ln1w, ln1b,
                                         x0b, x1b);

  gemm_bt<0><<<dim3(34, 32), 256, 0, stream>>>(x1b, wproj, NROWS, D_IN_PROJ, D_MODEL,
                                               zxb, nullptr);

  conv_silu_dt_kernel<<<dim3(2, NROWS), 256, 0, stream>>>(zxb, convw, convb, xact,
                                                          dtb, alog, dtsb, ldab);

  scan_state_kernel<<<NCH * 64, 256, 0, stream>>>(xact, dtsb, ldab, Sbuf, acb);
  state_prop_kernel<<<64 * 4, 256, 0, stream>>>(Sbuf, acb);
  scan_y_kernel<<<NCH * 64, 256, 0, stream>>>(xact, dtsb, ldab, Sbuf, yfull);

  gate_rms_kernel<<<NROWS, 256, 0, stream>>>(yfull, xact, zxb, Dp, normw, ynb);

  // out_proj: 64x128 split-K=2 -> partials, then fused reduce+residual+ln2
  gemm_skinny_sk<<<1024, 256, 0, stream>>>(ynb, wout, NROWS, D_MODEL, D_INNER,
                                           pout0, pout1);
  reduce_out_ln2_kernel<<<NROWS, 256, 0, stream>>>(pout0, pout1, x0b, x2f,
                                                   ln2w, ln2b, hln);

  gemm_bt<2><<<dim3(32, 32), 256, 0, stream>>>(hln, w1c, NROWS, FFN_DIM, D_MODEL,
                                               gbuf, b1c);

  // ffn2: 64x128 split-K=2 -> partials, then fused reduce(+bias+residual)
  gemm_skinny_sk<<<1024, 256, 0, stream>>>(gbuf, w2c, NROWS, D_MODEL, FFN_DIM,
                                           pf0, pf1);
  reduce_ffn_kernel<<<(NROWS * D_MODEL) / 1024, 256, 0, stream>>>(pf0, pf1,
                                                                  b2c, x2f, d_out, flag);
}

// Round 12
// 411.582 us; speedup vs baseline: 4.6565x; 1.0089x over previous
//
#include <hip/hip_runtime.h>
#include <hip/hip_bf16.h>
#include <math.h>

typedef __hip_bfloat16 bf16;
typedef __bf16 bhalf;
typedef bhalf bhalf8 __attribute__((ext_vector_type(8)));
typedef float f32x4 __attribute__((ext_vector_type(4)));
typedef unsigned short u16;
typedef u16 u16x4 __attribute__((ext_vector_type(4)));
typedef u16 u16x8 __attribute__((ext_vector_type(8)));

#define D_MODEL   1024
#define D_STATE   64
#define HEADDIM   64
#define D_INNER   2048
#define NHEADS    32
#define CONV_DIM  2176
#define D_IN_PROJ 4256
#define FFN_DIM   4096
#define BSZ       2
#define SEQ       2048
#define NROWS     (BSZ*SEQ)
#define TC        64
#define NCH       (SEQ/TC)

#define AS1 __attribute__((address_space(1)))
#define AS3 __attribute__((address_space(3)))
__device__ __forceinline__ void load_lds16(const void* g, void* l) {
  __builtin_amdgcn_global_load_lds((AS1 void*)g, (AS3 void*)l, 16, 0, 0);
}

__device__ __forceinline__ float bf2f(u16 u) {
  return __uint_as_float(((unsigned)u) << 16);
}
__device__ __forceinline__ u16 f2bbits(float f) {
  bf16 h = __float2bfloat16(f);
  return *(u16*)&h;
}

// ---------------------------------------------------------------------------
// Normalize weight inputs to bf16 copies; vectorized. Each block self-detects
// the input dtype (256 probes of x's first halfwords: fp32-as-bf16 yields
// |v|>1e6 or NaN with P(miss) ~ 0.6^256). Block 0 publishes the flag for
// downstream consumers (ln01, reduce_ffn). Replaces the detect dispatch.
// ---------------------------------------------------------------------------
#define NT 18
struct CvtArgs {
  const void* src[NT];
  void*       dst[NT];
  int ccum[NT + 1];
  int nel[NT];
};

__global__ __launch_bounds__(256)
void cvt_kernel(CvtArgs a, const unsigned short* __restrict__ x0,
                int* __restrict__ flagp)
{
  __shared__ int sbad;
  if (threadIdx.x == 0) sbad = 0;
  __syncthreads();
  {
    float v = bf2f(x0[threadIdx.x]);
    if (!(fabsf(v) <= 1e6f)) sbad = 1;   // benign race, same value
  }
  __syncthreads();
  const int isf32 = sbad;
  if (blockIdx.x == 0 && threadIdx.x == 0) *flagp = isf32;

  int c = blockIdx.x;
  int ti = 0;
  while (c >= a.ccum[ti + 1]) ti++;
  int j = (c - a.ccum[ti]) * 2048 + threadIdx.x * 8;
  if (j >= a.nel[ti]) return;
  if (isf32) {
    const float* s = (const float*)a.src[ti];
    f32x4 v0 = *(const f32x4*)(s + j);
    f32x4 v1 = *(const f32x4*)(s + j + 4);
    u16x8 o;
    #pragma unroll
    for (int k = 0; k < 4; k++) { o[k] = f2bbits(v0[k]); o[k + 4] = f2bbits(v1[k]); }
    *(u16x8*)((u16*)a.dst[ti] + j) = o;
  } else {
    *(u16x8*)((u16*)a.dst[ti] + j) = *(const u16x8*)((const u16*)a.src[ti] + j);
  }
}

// ---------------------------------------------------------------------------
// GEMM 128x128, BK=64, XOR-swizzled LDS. 2D grid dim3(nb, M/128) — the
// round-7/10-proven dispatch order (n fastest).
// EPI 0: store bf16   EPI 2: store bf16(gelu(acc+bias))
// ---------------------------------------------------------------------------
template<int EPI>
__global__ __launch_bounds__(256, 2)
void gemm_bt(const bf16* __restrict__ A, const bf16* __restrict__ W,
             int M, int N, int K,
             bf16* __restrict__ outB,
             const bf16* __restrict__ bias)
{
  __shared__ __align__(16) bhalf sA[128 * 64];
  __shared__ __align__(16) bhalf sW[128 * 64];
  const int n0   = blockIdx.x * 128;
  const int m0   = blockIdx.y * 128;
  const int t    = threadIdx.x;
  const int w    = t >> 6;
  const int lane = t & 63;
  const int wm   = (w >> 1) * 64;
  const int wn   = (w & 1) * 64;
  const int lr   = lane & 15;
  const int lq   = lane >> 4;

  f32x4 acc[4][4];
  #pragma unroll
  for (int i = 0; i < 4; i++)
    #pragma unroll
    for (int j = 0; j < 4; j++)
      acc[i][j] = (f32x4){0.f, 0.f, 0.f, 0.f};

  for (int k0 = 0; k0 < K; k0 += 64) {
    #pragma unroll
    for (int j = 0; j < 4; j++) {
      int s  = t + 256 * j;
      int r  = s >> 3;
      int cs = (s & 7) ^ (r & 7);
      load_lds16(A + (size_t)(m0 + r) * K + k0 + cs * 8, sA + s * 8);
      int wr = n0 + r; wr = wr < N ? wr : N - 1;
      load_lds16(W + (size_t)wr * K + k0 + cs * 8, sW + s * 8);
    }
    __syncthreads();
    #pragma unroll
    for (int kk = 0; kk < 2; kk++) {
      bhalf8 af[4], bfr[4];
      #pragma unroll
      for (int i = 0; i < 4; i++) {
        int r = wm + i * 16 + lr;
        int c = (kk * 4 + lq) ^ (r & 7);
        af[i] = *(const bhalf8*)(sA + r * 64 + c * 8);
      }
      #pragma unroll
      for (int j = 0; j < 4; j++) {
        int r = wn + j * 16 + lr;
        int c = (kk * 4 + lq) ^ (r & 7);
        bfr[j] = *(const bhalf8*)(sW + r * 64 + c * 8);
      }
      #pragma unroll
      for (int i = 0; i < 4; i++)
        #pragma unroll
        for (int j = 0; j < 4; j++)
          acc[i][j] = __builtin_amdgcn_mfma_f32_16x16x32_bf16(af[i], bfr[j], acc[i][j], 0, 0, 0);
    }
    __syncthreads();
  }

  #pragma unroll
  for (int i = 0; i < 4; i++) {
    #pragma unroll
    for (int j = 0; j < 4; j++) {
      #pragma unroll
      for (int r = 0; r < 4; r++) {
        int m = m0 + wm + i * 16 + lq * 4 + r;
        int n = n0 + wn + j * 16 + lr;
        if (n < N) {
          float v = acc[i][j][r];
          size_t idx = (size_t)m * N + n;
          if (EPI == 0) {
            outB[idx] = __float2bfloat16(v);
          } else {
            v += __bfloat162float(bias[n]);
            outB[idx] = __float2bfloat16(0.5f * v * (1.0f + erff(v * 0.70710678118654752f)));
          }
        }
      }
    }
  }
}

// ---------------------------------------------------------------------------
// Skinny GEMM 64x128 tile, split-K=SK (N=1024): grid = 512*SK blocks,
// fp32 partials; epilogues live in the reduce kernels.
// ---------------------------------------------------------------------------
struct SkParts4 { float* p[4]; };

template<int SK>
__global__ __launch_bounds__(256, 4)
void gemm_skinny_sk(const bf16* __restrict__ A, const bf16* __restrict__ W,
                    int M, int N, int K, SkParts4 parts)
{
  __shared__ __align__(16) bhalf sA[64 * 64];
  __shared__ __align__(16) bhalf sW[128 * 64];
  const int id   = blockIdx.x;
  const int z    = id >> 9;            // split index (grid = 512*SK)
  const int id9  = id & 511;
  const int hi   = id9 >> 6;
  const int rem  = id9 & 63;
  const int jn   = rem >> 3;
  const int mi   = hi * 8 + (rem & 7);
  const int m0   = mi * 64;
  const int n0   = jn * 128;
  const int t    = threadIdx.x;
  const int w    = t >> 6;
  const int lane = t & 63;
  const int wm   = (w >> 1) * 32;
  const int wn   = (w & 1) * 64;
  const int lr   = lane & 15;
  const int lq   = lane >> 4;

  f32x4 acc[2][4];
  #pragma unroll
  for (int i = 0; i < 2; i++)
    #pragma unroll
    for (int j = 0; j < 4; j++)
      acc[i][j] = (f32x4){0.f, 0.f, 0.f, 0.f};

  const int kh = K / SK;
  const int kend = z * kh + kh;
  for (int k0 = z * kh; k0 < kend; k0 += 64) {
    #pragma unroll
    for (int j = 0; j < 2; j++) {
      int s  = t + 256 * j;
      int r  = s >> 3;
      int cs = (s & 7) ^ (r & 7);
      load_lds16(A + (size_t)(m0 + r) * K + k0 + cs * 8, sA + s * 8);
    }
    #pragma unroll
    for (int j = 0; j < 4; j++) {
      int s  = t + 256 * j;
      int r  = s >> 3;
      int cs = (s & 7) ^ (r & 7);
      load_lds16(W + (size_t)(n0 + r) * K + k0 + cs * 8, sW + s * 8);
    }
    __syncthreads();
    #pragma unroll
    for (int kk = 0; kk < 2; kk++) {
      bhalf8 af[2], bfr[4];
      #pragma unroll
      for (int i = 0; i < 2; i++) {
        int r = wm + i * 16 + lr;
        int c = (kk * 4 + lq) ^ (r & 7);
        af[i] = *(const bhalf8*)(sA + r * 64 + c * 8);
      }
      #pragma unroll
      for (int j = 0; j < 4; j++) {
        int r = wn + j * 16 + lr;
        int c = (kk * 4 + lq) ^ (r & 7);
        bfr[j] = *(const bhalf8*)(sW + r * 64 + c * 8);
      }
      #pragma unroll
      for (int i = 0; i < 2; i++)
        #pragma unroll
        for (int j = 0; j < 4; j++)
          acc[i][j] = __builtin_amdgcn_mfma_f32_16x16x32_bf16(af[i], bfr[j], acc[i][j], 0, 0, 0);
    }
    __syncthreads();
  }

  float* out = parts.p[z];
  #pragma unroll
  for (int i = 0; i < 2; i++)
    #pragma unroll
    for (int j = 0; j < 4; j++)
      #pragma unroll
      for (int r = 0; r < 4; r++) {
        int m = m0 + wm + i * 16 + lq * 4 + r;
        int n = n0 + wn + j * 16 + lr;
        out[(size_t)m * N + n] = acc[i][j][r];
      }
}

// ---------------------------------------------------------------------------
// out_proj reduce + residual + FULL ln2, one block per row:
//   x2f = p0 + p1 + resB;  hln = LN(x2f)*w+b (bf16)
// ---------------------------------------------------------------------------
__global__ __launch_bounds__(256)
void reduce_out_ln2_kernel(const float* __restrict__ p0, const float* __restrict__ p1,
                           const bf16* __restrict__ resB, float* __restrict__ x2f,
                           const bf16* __restrict__ w, const bf16* __restrict__ b,
                           bf16* __restrict__ hln)
{
  int row = blockIdx.x, t = threadIdx.x;
  int i = row * 256 + t;
  __shared__ float rs[4], rq[4];
  f32x4 a = ((const f32x4*)p0)[i];
  f32x4 bb = ((const f32x4*)p1)[i];
  u16x4 r = ((const u16x4*)resB)[i];
  f32x4 o;
  float s = 0.f, ss = 0.f;
  #pragma unroll
  for (int j = 0; j < 4; j++) {
    o[j] = a[j] + bb[j] + bf2f(r[j]);
    s += o[j]; ss += o[j] * o[j];
  }
  ((f32x4*)x2f)[i] = o;
  #pragma unroll
  for (int off = 32; off; off >>= 1) { s += __shfl_down(s, off); ss += __shfl_down(ss, off); }
  if ((t & 63) == 0) { rs[t >> 6] = s; rq[t >> 6] = ss; }
  __syncthreads();
  float S = rs[0] + rs[1] + rs[2] + rs[3];
  float Q = rq[0] + rq[1] + rq[2] + rq[3];
  float mean = S * (1.f / D_MODEL);
  float rstd = rsqrtf(Q * (1.f / D_MODEL) - mean * mean + 1e-5f);
  u16x4 wv = ((const u16x4*)w)[t];
  u16x4 bv = ((const u16x4*)b)[t];
  u16x4 ov;
  #pragma unroll
  for (int j = 0; j < 4; j++)
    ov[j] = f2bbits((o[j] - mean) * rstd * bf2f(wv[j]) + bf2f(bv[j]));
  ((u16x4*)hln)[i] = ov;
}

// ---------------------------------------------------------------------------
// ffn2 reduce: d_out = p0+p1+p2+p3 + bias + resF (dtype per flag)
// ---------------------------------------------------------------------------
__global__ __launch_bounds__(256)
void reduce_ffn_kernel(const float* __restrict__ p0, const float* __restrict__ p1,
                       const float* __restrict__ p2, const float* __restrict__ p3,
                       const bf16* __restrict__ bias, const float* __restrict__ resF,
                       void* __restrict__ outp, const int* __restrict__ flagp)
{
  int i = blockIdx.x * 256 + threadIdx.x;
  int n4 = i & (D_MODEL / 4 - 1);
  f32x4 v0 = ((const f32x4*)p0)[i];
  f32x4 v1 = ((const f32x4*)p1)[i];
  f32x4 v2 = ((const f32x4*)p2)[i];
  f32x4 v3 = ((const f32x4*)p3)[i];
  f32x4 rf = ((const f32x4*)resF)[i];
  u16x4 bb = ((const u16x4*)bias)[n4];
  f32x4 o;
  #pragma unroll
  for (int j = 0; j < 4; j++)
    o[j] = ((v0[j] + v1[j]) + (v2[j] + v3[j])) + rf[j] + bf2f(bb[j]);
  if (*flagp) {
    ((f32x4*)outp)[i] = o;
  } else {
    u16x4 ov;
    #pragma unroll
    for (int j = 0; j < 4; j++) ov[j] = f2bbits(o[j]);
    ((u16x4*)outp)[i] = ov;
  }
}

// ---------------------------------------------------------------------------
// Fused ln0 + ln1; reads x directly from d_in (fp32/bf16 per flag); float4.
// ---------------------------------------------------------------------------
__global__ __launch_bounds__(256)
void ln01_kernel(const void* __restrict__ xin, const int* __restrict__ flagp,
                 const bf16* __restrict__ w0, const bf16* __restrict__ b0,
                 const bf16* __restrict__ w1, const bf16* __restrict__ b1,
                 bf16* __restrict__ x0o, bf16* __restrict__ x1o)
{
  int row = blockIdx.x, t = threadIdx.x;
  int i = row * 256 + t;
  __shared__ float rs[4], rq[4];
  float v[4], s = 0.f, ss = 0.f;
  if (*flagp) {
    f32x4 xv = ((const f32x4*)xin)[i];
    #pragma unroll
    for (int j = 0; j < 4; j++) v[j] = xv[j];
  } else {
    u16x4 xv = ((const u16x4*)xin)[i];
    #pragma unroll
    for (int j = 0; j < 4; j++) v[j] = bf2f(xv[j]);
  }
  #pragma unroll
  for (int j = 0; j < 4; j++) { s += v[j]; ss += v[j] * v[j]; }
  #pragma unroll
  for (int o = 32; o; o >>= 1) { s += __shfl_down(s, o); ss += __shfl_down(ss, o); }
  if ((t & 63) == 0) { rs[t >> 6] = s; rq[t >> 6] = ss; }
  __syncthreads();
  float S = rs[0] + rs[1] + rs[2] + rs[3];
  float Q = rq[0] + rq[1] + rq[2] + rq[3];
  float mean = S * (1.f / D_MODEL);
  float rstd = rsqrtf(Q * (1.f / D_MODEL) - mean * mean + 1e-5f);
  u16x4 w0v = ((const u16x4*)w0)[t], b0v = ((const u16x4*)b0)[t];
  float u[4]; s = 0.f; ss = 0.f;
  u16x4 o0;
  #pragma unroll
  for (int j = 0; j < 4; j++) {
    u[j] = (v[j] - mean) * rstd * bf2f(w0v[j]) + bf2f(b0v[j]);
    s += u[j]; ss += u[j] * u[j];
    o0[j] = f2bbits(u[j]);
  }
  ((u16x4*)x0o)[i] = o0;
  __syncthreads();
  #pragma unroll
  for (int o = 32; o; o >>= 1) { s += __shfl_down(s, o); ss += __shfl_down(ss, o); }
  if ((t & 63) == 0) { rs[t >> 6] = s; rq[t >> 6] = ss; }
  __syncthreads();
  S = rs[0] + rs[1] + rs[2] + rs[3];
  Q = rq[0] + rq[1] + rq[2] + rq[3];
  mean = S * (1.f / D_MODEL);
  rstd = rsqrtf(Q * (1.f / D_MODEL) - mean * mean + 1e-5f);
  u16x4 w1v = ((const u16x4*)w1)[t], b1v = ((const u16x4*)b1)[t];
  u16x4 o1;
  #pragma unroll
  for (int j = 0; j < 4; j++)
    o1[j] = f2bbits((u[j] - mean) * rstd * bf2f(w1v[j]) + bf2f(b1v[j]));
  ((u16x4*)x1o)[i] = o1;
}

// ---------------------------------------------------------------------------
// Causal depthwise conv (k=4) + SiLU -> bf16 xact, vectorized 8 ch/thread.
// Grid dim3(2, NROWS); block.x=1 tail threads compute dt/lda.
// ---------------------------------------------------------------------------
__device__ __forceinline__ void conv8(const bf16* __restrict__ zxb,
                                      const bf16* __restrict__ cw,
                                      const bf16* __restrict__ cb,
                                      bf16* __restrict__ xact, int row, int c0)
{
  int l = row & (SEQ - 1);
  float acc[8];
  {
    bhalf8 cbv = *(const bhalf8*)(cb + c0);
    #pragma unroll
    for (int j = 0; j < 8; j++) acc[j] = (float)cbv[j];
  }
  bhalf wts[32];
  #pragma unroll
  for (int q = 0; q < 4; q++)
    *(bhalf8*)(wts + q * 8) = *(const bhalf8*)(cw + c0 * 4 + q * 8);
  #pragma unroll
  for (int k = 0; k < 4; k++) {
    int lt = l - 3 + k;
    if (lt >= 0) {
      bhalf8 xv = *(const bhalf8*)(zxb + (size_t)(row - 3 + k) * D_IN_PROJ + D_INNER + c0);
      #pragma unroll
      for (int j = 0; j < 8; j++)
        acc[j] = fmaf((float)xv[j], (float)wts[j * 4 + k], acc[j]);
    }
  }
  bhalf8 o;
  #pragma unroll
  for (int j = 0; j < 8; j++) {
    float a = acc[j];
    o[j] = (bhalf)(a / (1.f + expf(-a)));
  }
  *(bhalf8*)(xact + (size_t)row * CONV_DIM + c0) = o;
}

__global__ __launch_bounds__(256)
void conv_silu_dt_kernel(const bf16* __restrict__ zxb, const bf16* __restrict__ cw,
                         const bf16* __restrict__ cb, bf16* __restrict__ xact,
                         const bf16* __restrict__ dtb, const bf16* __restrict__ alog,
                         float* __restrict__ dts, float* __restrict__ ldab)
{
  const int row = blockIdx.y;
  const int t = threadIdx.x;
  if (blockIdx.x == 0) {
    conv8(zxb, cw, cb, xact, row, t * 8);
  } else {
    if (t < 16) {
      conv8(zxb, cw, cb, xact, row, 2048 + t * 8);
    } else if (t < 48) {
      int h = t - 16;
      float v = __bfloat162float(zxb[(size_t)row * D_IN_PROJ + (D_INNER + CONV_DIM) + h]) +
                __bfloat162float(dtb[h]);
      float sp = (v > 20.f) ? v : log1pf(expf(v));
      dts[row * NHEADS + h] = sp;
      ldab[row * NHEADS + h] = -sp * expf(__bfloat162float(alog[h]));
    }
  }
}

// ---------------------------------------------------------------------------
// MFMA chunk scan, pass 1 (chunk states).
// ---------------------------------------------------------------------------
__global__ __launch_bounds__(256)
void scan_state_kernel(const bf16* __restrict__ xact, const float* __restrict__ dts,
                       const float* __restrict__ ldab, bf16* __restrict__ Sbuf,
                       float* __restrict__ acb)
{
  __shared__ __align__(16) bf16 wBT[64][72];
  __shared__ __align__(16) bf16 XT[64][72];
  __shared__ float lsS[64], dtS[64];
  const int bid = blockIdx.x;
  const int bh = bid & 63, c = bid >> 6;
  const int b = bh >> 5, h = bh & 31;
  const int t0 = c * TC;
  const int tid = threadIdx.x;
  const int w = tid >> 6, lane = tid & 63;
  const int lr = lane & 15, lq = lane >> 4;

  if (w == 0) {
    float v = ldab[(size_t)(b * SEQ + t0 + lane) * NHEADS + h];
    #pragma unroll
    for (int o = 1; o < 64; o <<= 1) {
      float up = __shfl_up(v, o);
      if (lane >= o) v += up;
    }
    lsS[lane] = v;
    dtS[lane] = dts[(size_t)(b * SEQ + t0 + lane) * NHEADS + h];
  }
  __syncthreads();
  const float lsT = lsS[63];
  {
    int nn = tid & 63, u0 = (tid >> 6) * 16;
    for (int i = 0; i < 16; i++) {
      int u = u0 + i;
      const bf16* rowp = xact + (size_t)(b * SEQ + t0 + u) * CONV_DIM;
      float wgt = dtS[u] * __expf(lsT - lsS[u]);
      wBT[nn][u] = __float2bfloat16(__bfloat162float(rowp[D_INNER + nn]) * wgt);
      XT[nn][u]  = rowp[h * 64 + nn];
    }
  }
  __syncthreads();

  bhalf8 af0 = *(const bhalf8*)&wBT[16 * w + lr][lq * 8];
  bhalf8 af1 = *(const bhalf8*)&wBT[16 * w + lr][32 + lq * 8];
  bf16* sb = Sbuf + ((size_t)bh * NCH + c) * 4096;
  #pragma unroll
  for (int jt = 0; jt < 4; jt++) {
    bhalf8 xf0 = *(const bhalf8*)&XT[16 * jt + lr][lq * 8];
    bhalf8 xf1 = *(const bhalf8*)&XT[16 * jt + lr][32 + lq * 8];
    f32x4 acc = (f32x4){0.f, 0.f, 0.f, 0.f};
    acc = __builtin_amdgcn_mfma_f32_16x16x32_bf16(af0, xf0, acc, 0, 0, 0);
    acc = __builtin_amdgcn_mfma_f32_16x16x32_bf16(af1, xf1, acc, 0, 0, 0);
    #pragma unroll
    for (int r = 0; r < 4; r++) {
      int n = 16 * w + lq * 4 + r;
      int p = 16 * jt + lr;
      sb[p * 64 + n] = __float2bfloat16(acc[r]);
    }
  }
  if (tid == 0) acb[bh * NCH + c] = __expf(lsT);
}

// ---------------------------------------------------------------------------
// Pass 2: serial inter-chunk propagation (in-place).
// ---------------------------------------------------------------------------
__global__ __launch_bounds__(256)
void state_prop_kernel(bf16* __restrict__ Sbuf, const float* __restrict__ acb)
{
  const int bh = blockIdx.x >> 2, q = blockIdx.x & 3;
  const int t = threadIdx.x;
  bf16* sp = Sbuf + (size_t)bh * NCH * 4096 + q * 1024 + t;
  const float* ap = acb + bh * NCH;
  float h0 = 0.f, h1 = 0.f, h2 = 0.f, h3 = 0.f;
  for (int c = 0; c < NCH; c++) {
    bf16* pc = sp + (size_t)c * 4096;
    float s0 = __bfloat162float(pc[0]);
    float s1 = __bfloat162float(pc[256]);
    float s2 = __bfloat162float(pc[512]);
    float s3 = __bfloat162float(pc[768]);
    float a = ap[c];
    pc[0]   = __float2bfloat16(h0);
    pc[256] = __float2bfloat16(h1);
    pc[512] = __float2bfloat16(h2);
    pc[768] = __float2bfloat16(h3);
    h0 = fmaf(h0, a, s0); h1 = fmaf(h1, a, s1);
    h2 = fmaf(h2, a, s2); h3 = fmaf(h3, a, s3);
  }
}

// ---------------------------------------------------------------------------
// MFMA chunk scan, pass 3. LDS reduced to 4 tiles (37.4 KB -> 4 blocks/CU):
// M is held in registers across the G loop, then written into Bs's storage
// (Bs dead after the loop) behind a barrier.
// ---------------------------------------------------------------------------
__global__ __launch_bounds__(256)
void scan_y_kernel(const bf16* __restrict__ xact, const float* __restrict__ dts,
                   const float* __restrict__ ldab, const bf16* __restrict__ Sbuf,
                   bf16* __restrict__ yfull)
{
  __shared__ __align__(16) bf16 Cs[64][72];
  __shared__ __align__(16) bf16 Bs[64][72];    // reused for M after G loop
  __shared__ __align__(16) bf16 XT[64][72];
  __shared__ __align__(16) bf16 HT[64][72];
  __shared__ float lsS[64], dtS[64];
  const int bid = blockIdx.x;
  const int bh = bid & 63, c = bid >> 6;
  const int b = bh >> 5, h = bh & 31;
  const int t0 = c * TC;
  const int tid = threadIdx.x;
  const int w = tid >> 6, lane = tid & 63;
  const int lr = lane & 15, lq = lane >> 4;

  if (w == 0) {
    float v = ldab[(size_t)(b * SEQ + t0 + lane) * NHEADS + h];
    #pragma unroll
    for (int o = 1; o < 64; o <<= 1) {
      float up = __shfl_up(v, o);
      if (lane >= o) v += up;
    }
    lsS[lane] = v;
    dtS[lane] = dts[(size_t)(b * SEQ + t0 + lane) * NHEADS + h];
  }
  {
    int nn = tid & 63, u0 = (tid >> 6) * 16;
    for (int i = 0; i < 16; i++) {
      int u = u0 + i;
      const bf16* rowp = xact + (size_t)(b * SEQ + t0 + u) * CONV_DIM;
      Bs[u][nn] = rowp[D_INNER + nn];
      Cs[u][nn] = rowp[D_INNER + 64 + nn];
      XT[nn][u] = rowp[h * 64 + nn];
    }
    const bf16* sb = Sbuf + ((size_t)bh * NCH + c) * 4096;
    for (int i = 0; i < 16; i++) {
      int e = tid + 256 * i;
      HT[e >> 6][e & 63] = sb[e];
    }
  }
  __syncthreads();

  bhalf8 cf0 = *(const bhalf8*)&Cs[16 * w + lr][lq * 8];
  bhalf8 cf1 = *(const bhalf8*)&Cs[16 * w + lr][32 + lq * 8];
  f32x4 accH[4];
  float mreg[4][4];
  #pragma unroll
  for (int jt = 0; jt < 4; jt++) {
    bhalf8 bf0 = *(const bhalf8*)&Bs[16 * jt + lr][lq * 8];
    bhalf8 bf1 = *(const bhalf8*)&Bs[16 * jt + lr][32 + lq * 8];
    f32x4 g = (f32x4){0.f, 0.f, 0.f, 0.f};
    g = __builtin_amdgcn_mfma_f32_16x16x32_bf16(cf0, bf0, g, 0, 0, 0);
    g = __builtin_amdgcn_mfma_f32_16x16x32_bf16(cf1, bf1, g, 0, 0, 0);
    bhalf8 hf0 = *(const bhalf8*)&HT[16 * jt + lr][lq * 8];
    bhalf8 hf1 = *(const bhalf8*)&HT[16 * jt + lr][32 + lq * 8];
    f32x4 ah = (f32x4){0.f, 0.f, 0.f, 0.f};
    ah = __builtin_amdgcn_mfma_f32_16x16x32_bf16(cf0, hf0, ah, 0, 0, 0);
    ah = __builtin_amdgcn_mfma_f32_16x16x32_bf16(cf1, hf1, ah, 0, 0, 0);
    accH[jt] = ah;
    #pragma unroll
    for (int r = 0; r < 4; r++) {
      int t = 16 * w + lq * 4 + r;
      int u = 16 * jt + lr;
      float m = 0.f;
      if (u <= t) m = g[r] * __expf(lsS[t] - lsS[u]) * dtS[u];
      mreg[jt][r] = m;
    }
  }
  __syncthreads();               // all Bs reads complete
  #pragma unroll
  for (int jt = 0; jt < 4; jt++)
    #pragma unroll
    for (int r = 0; r < 4; r++)
      Bs[16 * w + lq * 4 + r][16 * jt + lr] = __float2bfloat16(mreg[jt][r]);
  __syncthreads();

  bhalf8 mf0 = *(const bhalf8*)&Bs[16 * w + lr][lq * 8];
  bhalf8 mf1 = *(const bhalf8*)&Bs[16 * w + lr][32 + lq * 8];
  #pragma unroll
  for (int jt = 0; jt < 4; jt++) {
    bhalf8 xf0 = *(const bhalf8*)&XT[16 * jt + lr][lq * 8];
    bhalf8 xf1 = *(const bhalf8*)&XT[16 * jt + lr][32 + lq * 8];
    f32x4 acc = (f32x4){0.f, 0.f, 0.f, 0.f};
    acc = __builtin_amdgcn_mfma_f32_16x16x32_bf16(mf0, xf0, acc, 0, 0, 0);
    acc = __builtin_amdgcn_mfma_f32_16x16x32_bf16(mf1, xf1, acc, 0, 0, 0);
    #pragma unroll
    for (int r = 0; r < 4; r++) {
      int t = 16 * w + lq * 4 + r;
      int p = 16 * jt + lr;
      float y = acc[r] + __expf(lsS[t]) * accH[jt][r];
      yfull[(size_t)(b * SEQ + t0 + t) * D_INNER + h * 64 + p] = __float2bfloat16(y);
    }
  }
}

// ---------------------------------------------------------------------------
// y = yfull + D*x;  y *= silu(z);  RMSNorm * norm_w -> bf16.
// ---------------------------------------------------------------------------
__global__ __launch_bounds__(256)
void gate_rms_kernel(const bf16* __restrict__ yfull, const bf16* __restrict__ xact,
                     const bf16* __restrict__ zxb, const bf16* __restrict__ Dp,
                     const bf16* __restrict__ nw, bf16* __restrict__ yn)
{
  int row = blockIdx.x, t = threadIdx.x;
  int c0 = t * 8;
  __shared__ float rq[4];
  bhalf8 yv8 = *(const bhalf8*)(yfull + (size_t)row * D_INNER + c0);
  bhalf8 xv8 = *(const bhalf8*)(xact + (size_t)row * CONV_DIM + c0);
  bhalf8 zv8 = *(const bhalf8*)(zxb + (size_t)row * D_IN_PROJ + c0);
  float Dv = __bfloat162float(Dp[c0 >> 6]);
  float yv[8]; float ss = 0.f;
  #pragma unroll
  for (int j = 0; j < 8; j++) {
    float y = (float)yv8[j] + Dv * (float)xv8[j];
    float z = (float)zv8[j];
    yv[j] = y * (z / (1.f + expf(-z)));
    ss += yv[j] * yv[j];
  }
  #pragma unroll
  for (int o = 32; o; o >>= 1) ss += __shfl_down(ss, o);
  if ((t & 63) == 0) rq[t >> 6] = ss;
  __syncthreads();
  float tot = rq[0] + rq[1] + rq[2] + rq[3];
  float rr = rsqrtf(tot * (1.f / D_INNER) + 1e-5f);
  bhalf8 nv8 = *(const bhalf8*)(nw + c0);
  bhalf8 o;
  #pragma unroll
  for (int j = 0; j < 8; j++)
    o[j] = (bhalf)(yv[j] * rr * (float)nv8[j]);
  *(bhalf8*)(yn + (size_t)row * D_INNER + c0) = o;
}

// ---------------------------------------------------------------------------
extern "C" void kernel_launch(void* const* d_in, const int* in_sizes, int n_in,
                              void* d_out, int out_size, void* d_ws, size_t ws_size,
                              hipStream_t stream)
{
  char* ws = (char*)d_ws;
  bf16*  x1b   = (bf16*) (ws + 0);           //  [3->4]
  bf16*  Sbuf  = (bf16*) (ws + 0);           //  [7->9]   alias x1b (dead @4)
  bf16*  ynb   = (bf16*) (ws + 0);           //  [10->11] alias Sbuf
  float* pf0   = (float*)(ws + 0);           //  [14->14b] alias ynb
  bf16*  wproj = (bf16*) (ws + 16777216);    //  [2->4]
  float* acb   = (float*)(ws + 16777216);    //  [7->8]   alias wproj
  float* dtsb  = (float*)(ws + 16785408);    //  [5->9]   alias wproj
  float* ldab  = (float*)(ws + 17309696);    //  [5->9]   alias wproj
  float* pf1   = (float*)(ws + 16777216);    //  [14->14b] alias wproj region
  bf16*  wout  = (bf16*) (ws + 25493504);    //  [2->11]
  bf16*  w1c   = (bf16*) (ws + 29687808);    //  [2->13]
  bf16*  w2c   = (bf16*) (ws + 38076416);    //  [2->14]
  bf16*  ln0w  = (bf16*) (ws + 46465024);
  bf16*  ln0b  = (bf16*) (ws + 46467072);
  bf16*  ln1w  = (bf16*) (ws + 46469120);
  bf16*  ln1b  = (bf16*) (ws + 46471168);
  bf16*  ln2w  = (bf16*) (ws + 46473216);
  bf16*  ln2b  = (bf16*) (ws + 46475264);
  bf16*  convw = (bf16*) (ws + 46477312);
  bf16*  convb = (bf16*) (ws + 46494720);
  bf16*  dtb   = (bf16*) (ws + 46499072);
  bf16*  alog  = (bf16*) (ws + 46499136);
  bf16*  Dp    = (bf16*) (ws + 46499200);
  bf16*  normw = (bf16*) (ws + 46499264);
  bf16*  b1c   = (bf16*) (ws + 46503360);
  bf16*  b2c   = (bf16*) (ws + 46511552);
  int*   flag  = (int*)  (ws + 46513600);
  bf16*  x0b   = (bf16*) (ws + 46514176);    //  [3->11b]
  bf16*  zxb   = (bf16*) (ws + 54902784);    //  [4->10]
  float* x2f   = (float*)(ws + 54902784);    //  [11b->14b] alias zxb (ends 71.68M)
  float* pf3   = (float*)(ws + 71680000);    //  [14->14b] zxb tail (dead @10), ends 88.46M
  bf16*  xact  = (bf16*) (ws + 89767936);    //  [5->10]
  float* pout0 = (float*)(ws + 89767936);    //  [11->11b] alias xact
  float* pout1 = (float*)(ws + 106545152);   //  [11->11b]
  bf16*  gbuf  = (bf16*) (ws + 89767936);    //  [13->14] alias xact region
  bf16*  yfull = (bf16*) (ws + 125419520);   //  [9->10]
  bf16*  hln   = (bf16*) (ws + 125419520);   //  [11b->13] alias yfull
  float* pf2   = (float*)(ws + 125419520);   //  [14->14b] alias hln (dead @13)

  CvtArgs ca;
  void* dsts[NT] = { ln0w, ln0b, ln1w, ln1b, ln2w, ln2b, wproj, convw, convb,
                     dtb, alog, Dp, normw, wout, w1c, b1c, w2c, b2c };
  int cc = 0;
  ca.ccum[0] = 0;
  for (int i = 0; i < NT; i++) {
    ca.src[i] = d_in[i + 1];
    ca.dst[i] = dsts[i];
    ca.nel[i] = in_sizes[i + 1];
    cc += (in_sizes[i + 1] + 2047) / 2048;
    ca.ccum[i + 1] = cc;
  }
  cvt_kernel<<<cc, 256, 0, stream>>>(ca, (const unsigned short*)d_in[0], flag);

  ln01_kernel<<<NROWS, 256, 0, stream>>>(d_in[0], flag, ln0w, ln0b, ln1w, ln1b,
                                         x0b, x1b);

  gemm_bt<0><<<dim3(34, 32), 256, 0, stream>>>(x1b, wproj, NROWS, D_IN_PROJ, D_MODEL,
                                               zxb, nullptr);

  conv_silu_dt_kernel<<<dim3(2, NROWS), 256, 0, stream>>>(zxb, convw, convb, xact,
                                                          dtb, alog, dtsb, ldab);

  scan_state_kernel<<<NCH * 64, 256, 0, stream>>>(xact, dtsb, ldab, Sbuf, acb);
  state_prop_kernel<<<64 * 4, 256, 0, stream>>>(Sbuf, acb);
  scan_y_kernel<<<NCH * 64, 256, 0, stream>>>(xact, dtsb, ldab, Sbuf, yfull);

  gate_rms_kernel<<<NROWS, 256, 0, stream>>>(yfull, xact, zxb, Dp, normw, ynb);

  // out_proj: 64x128 split-K=2 -> partials, then fused reduce+residual+ln2
  SkParts4 po = { { pout0, pout1, pout0, pout0 } };
  gemm_skinny_sk<2><<<1024, 256, 0, stream>>>(ynb, wout, NROWS, D_MODEL, D_INNER, po);
  reduce_out_ln2_kernel<<<NROWS, 256, 0, stream>>>(pout0, pout1, x0b, x2f,
                                                   ln2w, ln2b, hln);

  gemm_bt<2><<<dim3(32, 32), 256, 0, stream>>>(hln, w1c, NROWS, FFN_DIM, D_MODEL,
                                               gbuf, b1c);

  // ffn2: 64x128 split-K=4 (2048 blocks, 8/CU) -> partials, then fused reduce
  SkParts4 pfp = { { pf0, pf1, pf2, pf3 } };
  gemm_skinny_sk<4><<<2048, 256, 0, stream>>>(gbuf, w2c, NROWS, D_MODEL, FFN_DIM, pfp);
  reduce_ffn_kernel<<<(NROWS * D_MODEL) / 1024, 256, 0, stream>>>(pf0, pf1, pf2, pf3,
                                                                  b2c, x2f, d_out, flag);
}